// Round 1
// 1639.400 us; speedup vs baseline: 1.0799x; 1.0799x over previous
//
#include <hip/hip_runtime.h>
#include <hip/hip_bf16.h>
#include <math.h>

// ---------------- constants ----------------
#define D_MODEL   768
#define N_LAYER   8
#define D_INNER   1536
#define D_STATE   128
#define HEADDIM   64
#define NHEADS    24
#define CONV_DIM  1792
#define D_IN_PROJ 3352
#define AH        8
#define AD        64
#define AINNER    512
#define BSZ       2
#define SEQ       512
#define LC        64
#define ROWS      (BSZ*SEQ)          // 1024
#define NCHUNK    8
#define CT        64                 // chunk length
#define NP1       3456               // 3352 padded to 27*128
#define AFF       4608

typedef __attribute__((ext_vector_type(8))) short bf16x8;
typedef __attribute__((ext_vector_type(4))) float f32x4;

__device__ __forceinline__ float siluf(float x) { return x / (1.f + expf(-x)); }

__device__ __forceinline__ unsigned short f2b(float x) {
    __hip_bfloat16 h = __float2bfloat16(x);
    return __builtin_bit_cast(unsigned short, h);
}
__device__ __forceinline__ float b2f(unsigned short u) {
    unsigned v = ((unsigned)u) << 16;
    return __builtin_bit_cast(float, v);
}

// async global->LDS 16B copy (wave-uniform base + lane*16 contiguity honored by callers)
__device__ __forceinline__ void gload16(const void* g, void* l) {
    __builtin_amdgcn_global_load_lds(
        (const __attribute__((address_space(1))) unsigned int*)g,
        (__attribute__((address_space(3))) unsigned int*)l,
        16, 0, 0);
}

// block-wide sum, 256 threads (4 waves)
__device__ __forceinline__ float block_sum_256(float v, float* s4) {
    #pragma unroll
    for (int o = 32; o > 0; o >>= 1) v += __shfl_down(v, o, 64);
    __syncthreads();
    if ((threadIdx.x & 63) == 0) s4[threadIdx.x >> 6] = v;
    __syncthreads();
    return s4[0] + s4[1] + s4[2] + s4[3];
}

// ---------------- fused preamble: ref f2b + silumean + aff bias init ----------------
__global__ void k_pre(const float* __restrict__ ref_emb, unsigned short* __restrict__ ref_bf,
                      float* __restrict__ smc, const float* __restrict__ adab,
                      float* __restrict__ aff_all) {
    int blk = blockIdx.x;
    if (blk < 384) {                              // f2b, exact 98304
        int i = blk * 256 + threadIdx.x;
        ref_bf[i] = f2b(ref_emb[i]);
    } else if (blk < 390) {                       // silu(mean(cond,1))
        int i = (blk - 384) * 256 + threadIdx.x;
        if (i < BSZ * D_MODEL) {
            int b = i / D_MODEL, d = i % D_MODEL;
            const float* p = ref_emb + (size_t)b * LC * D_MODEL + d;
            float s = 0.f;
            #pragma unroll 4
            for (int l = 0; l < LC; l++) s += p[l * D_MODEL];
            smc[i] = siluf(s * (1.f / (float)LC));
        }
    } else {                                      // aff init with bias, exact 73728
        int i = (blk - 390) * 256 + threadIdx.x;
        int j = i % AFF; int l = (i / AFF) >> 1;
        aff_all[i] = adab[l * AFF + j];
    }
}

// ---------------- batched padded transpose: src fp32 [L][K][N] -> dst bf16 [L][Npad][K] ----
__global__ void k_transpose_pb(const float* __restrict__ src, unsigned short* __restrict__ dst,
                               int K, int N, int Npad) {
    int z = blockIdx.z;
    src += (size_t)z * K * N;
    dst += (size_t)z * Npad * K;
    __shared__ float tile[32][33];
    int n0 = blockIdx.x * 32, k0 = blockIdx.y * 32;
    int t = threadIdx.x;
    int nl = t & 31, kl = t >> 5;
    #pragma unroll
    for (int p = 0; p < 4; p++) {
        int k = kl + p * 8;
        int n = n0 + nl;
        tile[k][nl] = (n < N) ? src[(size_t)(k0 + k) * N + n] : 0.f;
    }
    __syncthreads();
    int kl2 = t & 31, nl2 = t >> 5;
    #pragma unroll
    for (int p = 0; p < 4; p++) {
        int n = nl2 + p * 8;
        dst[(size_t)(n0 + n) * K + k0 + kl2] = f2b(tile[kl2][n]);
    }
}

// q/k/v transposes share geometry (K=768, N=Npad=512): one batched launch
__global__ void k_transpose_qkv(const float* __restrict__ qw, const float* __restrict__ kw,
                                const float* __restrict__ vw, unsigned short* __restrict__ qd,
                                unsigned short* __restrict__ kd, unsigned short* __restrict__ vd) {
    int z = blockIdx.z;                 // 0..23
    int which = z >> 3, layer = z & 7;
    const float* src = (which == 0 ? qw : which == 1 ? kw : vw) + (size_t)layer * D_MODEL * AINNER;
    unsigned short* dst = (which == 0 ? qd : which == 1 ? kd : vd) + (size_t)layer * AINNER * D_MODEL;
    __shared__ float tile[32][33];
    int n0 = blockIdx.x * 32, k0 = blockIdx.y * 32;
    int t = threadIdx.x;
    int nl = t & 31, kl = t >> 5;
    #pragma unroll
    for (int p = 0; p < 4; p++) {
        int k = kl + p * 8;
        tile[k][nl] = src[(size_t)(k0 + k) * AINNER + n0 + nl];
    }
    __syncthreads();
    int kl2 = t & 31, nl2 = t >> 5;
    #pragma unroll
    for (int p = 0; p < 4; p++) {
        int n = nl2 + p * 8;
        dst[(size_t)(n0 + n) * D_MODEL + k0 + kl2] = f2b(tile[kl2][n]);
    }
}

// ---------------- bf16 MFMA GEMM with async LDS staging ----------------
// C[M,N] = A[M,K] @ Bt[N,K]^T ; A,Bt bf16 row-major; C fp32
__global__ __launch_bounds__(256)
void k_gemm(const unsigned short* __restrict__ A, const unsigned short* __restrict__ Bt,
            float* __restrict__ C, int M, int N, int K) {
    __shared__ __align__(16) unsigned short As[128][32];
    __shared__ __align__(16) unsigned short Bs[128][32];
    int m0 = blockIdx.y * 128, n0 = blockIdx.x * 128;
    int tid = threadIdx.x;
    int lane = tid & 63, wave = tid >> 6;
    int wm = (wave >> 1) * 64, wn = (wave & 1) * 64;
    int l15 = lane & 15, quad = lane >> 4;
    f32x4 acc[4][4];
    #pragma unroll
    for (int i = 0; i < 4; i++)
        #pragma unroll
        for (int j = 0; j < 4; j++) acc[i][j] = (f32x4){0.f, 0.f, 0.f, 0.f};

    int srow = tid >> 2;
    int schunk = (tid & 3) * 8;

    for (int k0 = 0; k0 < K; k0 += 32) {
        #pragma unroll
        for (int ps = 0; ps < 2; ps++) {
            int r = srow + ps * 64;
            gload16(&A[(size_t)(m0 + r) * K + k0 + schunk], &As[r][schunk]);
            gload16(&Bt[(size_t)(n0 + r) * K + k0 + schunk], &Bs[r][schunk]);
        }
        __syncthreads();
        bf16x8 af[4], bfr[4];
        #pragma unroll
        for (int i = 0; i < 4; i++) af[i]  = *(const bf16x8*)&As[wm + i * 16 + l15][quad * 8];
        #pragma unroll
        for (int j = 0; j < 4; j++) bfr[j] = *(const bf16x8*)&Bs[wn + j * 16 + l15][quad * 8];
        #pragma unroll
        for (int i = 0; i < 4; i++)
            #pragma unroll
            for (int j = 0; j < 4; j++)
                acc[i][j] = __builtin_amdgcn_mfma_f32_16x16x32_bf16(af[i], bfr[j], acc[i][j], 0, 0, 0);
        __syncthreads();
    }
    #pragma unroll
    for (int i = 0; i < 4; i++) {
        #pragma unroll
        for (int j = 0; j < 4; j++) {
            int col = n0 + wn + j * 16 + l15;
            if (col < N) {
                #pragma unroll
                for (int r = 0; r < 4; r++) {
                    int row = m0 + wm + i * 16 + quad * 4 + r;
                    C[(size_t)row * N + col] = acc[i][j][r];
                }
            }
        }
    }
}

// split-K variant: grid.z = number of K-slices of width Kc; partial written to C + z*M*N
__global__ __launch_bounds__(256)
void k_gemm_sk(const unsigned short* __restrict__ A, const unsigned short* __restrict__ Bt,
               float* __restrict__ C, int M, int N, int K, int Kc) {
    int z = blockIdx.z;
    C += (size_t)z * M * N;
    int kbeg = z * Kc;
    int kend = kbeg + Kc; if (kend > K) kend = K;
    __shared__ __align__(16) unsigned short As[128][32];
    __shared__ __align__(16) unsigned short Bs[128][32];
    int m0 = blockIdx.y * 128, n0 = blockIdx.x * 128;
    int tid = threadIdx.x;
    int lane = tid & 63, wave = tid >> 6;
    int wm = (wave >> 1) * 64, wn = (wave & 1) * 64;
    int l15 = lane & 15, quad = lane >> 4;
    f32x4 acc[4][4];
    #pragma unroll
    for (int i = 0; i < 4; i++)
        #pragma unroll
        for (int j = 0; j < 4; j++) acc[i][j] = (f32x4){0.f, 0.f, 0.f, 0.f};

    int srow = tid >> 2;
    int schunk = (tid & 3) * 8;

    for (int k0 = kbeg; k0 < kend; k0 += 32) {
        #pragma unroll
        for (int ps = 0; ps < 2; ps++) {
            int r = srow + ps * 64;
            gload16(&A[(size_t)(m0 + r) * K + k0 + schunk], &As[r][schunk]);
            gload16(&Bt[(size_t)(n0 + r) * K + k0 + schunk], &Bs[r][schunk]);
        }
        __syncthreads();
        bf16x8 af[4], bfr[4];
        #pragma unroll
        for (int i = 0; i < 4; i++) af[i]  = *(const bf16x8*)&As[wm + i * 16 + l15][quad * 8];
        #pragma unroll
        for (int j = 0; j < 4; j++) bfr[j] = *(const bf16x8*)&Bs[wn + j * 16 + l15][quad * 8];
        #pragma unroll
        for (int i = 0; i < 4; i++)
            #pragma unroll
            for (int j = 0; j < 4; j++)
                acc[i][j] = __builtin_amdgcn_mfma_f32_16x16x32_bf16(af[i], bfr[j], acc[i][j], 0, 0, 0);
        __syncthreads();
    }
    #pragma unroll
    for (int i = 0; i < 4; i++) {
        #pragma unroll
        for (int j = 0; j < 4; j++) {
            int col = n0 + wn + j * 16 + l15;
            if (col < N) {
                #pragma unroll
                for (int r = 0; r < 4; r++) {
                    int row = m0 + wm + i * 16 + quad * 4 + r;
                    C[(size_t)row * N + col] = acc[i][j][r];
                }
            }
        }
    }
}

// batched K/V projection -> bf16 out
__global__ __launch_bounds__(256)
void k_gemm_kv(const unsigned short* __restrict__ A, const unsigned short* __restrict__ Kwt,
               const unsigned short* __restrict__ Vwt, unsigned short* __restrict__ Kb,
               unsigned short* __restrict__ Vb) {
    int z = blockIdx.z; int layer = z >> 1; int which = z & 1;
    const unsigned short* Bt = (which ? Vwt : Kwt) + (size_t)layer * AINNER * D_MODEL;
    unsigned short* C = (which ? Vb : Kb) + (size_t)layer * (BSZ * LC) * AINNER;
    __shared__ __align__(16) unsigned short As[128][32];
    __shared__ __align__(16) unsigned short Bs[128][32];
    int n0 = blockIdx.x * 128;
    int tid = threadIdx.x;
    int lane = tid & 63, wave = tid >> 6;
    int wm = (wave >> 1) * 64, wn = (wave & 1) * 64;
    int l15 = lane & 15, quad = lane >> 4;
    f32x4 acc[4][4];
    #pragma unroll
    for (int i = 0; i < 4; i++)
        #pragma unroll
        for (int j = 0; j < 4; j++) acc[i][j] = (f32x4){0.f, 0.f, 0.f, 0.f};
    int srow = tid >> 2, schunk = (tid & 3) * 8;
    for (int k0 = 0; k0 < D_MODEL; k0 += 32) {
        #pragma unroll
        for (int ps = 0; ps < 2; ps++) {
            int r = srow + ps * 64;
            gload16(&A[(size_t)r * D_MODEL + k0 + schunk], &As[r][schunk]);
            gload16(&Bt[(size_t)(n0 + r) * D_MODEL + k0 + schunk], &Bs[r][schunk]);
        }
        __syncthreads();
        bf16x8 af[4], bfr[4];
        #pragma unroll
        for (int i = 0; i < 4; i++) af[i]  = *(const bf16x8*)&As[wm + i * 16 + l15][quad * 8];
        #pragma unroll
        for (int j = 0; j < 4; j++) bfr[j] = *(const bf16x8*)&Bs[wn + j * 16 + l15][quad * 8];
        #pragma unroll
        for (int i = 0; i < 4; i++)
            #pragma unroll
            for (int j = 0; j < 4; j++)
                acc[i][j] = __builtin_amdgcn_mfma_f32_16x16x32_bf16(af[i], bfr[j], acc[i][j], 0, 0, 0);
        __syncthreads();
    }
    #pragma unroll
    for (int i = 0; i < 4; i++) {
        #pragma unroll
        for (int j = 0; j < 4; j++) {
            int col = n0 + wn + j * 16 + l15;
            #pragma unroll
            for (int r = 0; r < 4; r++) {
                int row = wm + i * 16 + quad * 4 + r;
                C[(size_t)row * AINNER + col] = f2b(acc[i][j][r]);
            }
        }
    }
}

// ---------------- split-K ada ----------------
__global__ void k_ada_split(const float* __restrict__ smc, const float* __restrict__ adaw,
                            float* __restrict__ aff_all) {
    int l = blockIdx.z;
    int kc = blockIdx.y;
    int j = blockIdx.x * 256 + threadIdx.x;
    const float* w = adaw + (size_t)l * D_MODEL * AFF + j;
    const float* x0 = smc;
    const float* x1 = smc + D_MODEL;
    float s0 = 0.f, s1 = 0.f;
    int d0 = kc * 96;
    #pragma unroll 8
    for (int d = d0; d < d0 + 96; d++) {
        float wv = w[(size_t)d * AFF];
        s0 += x0[d] * wv; s1 += x1[d] * wv;
    }
    atomicAdd(&aff_all[(size_t)l * BSZ * AFF + j], s0);
    atomicAdd(&aff_all[(size_t)l * BSZ * AFF + AFF + j], s1);
}

// ---------------- [fused prev-attn out (2 split-K partials)] + residual + rmsnorm + mod ----
__global__ void k_addrmsmod(const float* __restrict__ hin, const float* __restrict__ raw,
                            const float* __restrict__ bias, const float* __restrict__ affprev,
                            float* __restrict__ residual, const float* __restrict__ normw,
                            const float* __restrict__ affcur,
                            float* __restrict__ hidden_n, unsigned short* __restrict__ u,
                            int has_raw) {
    __shared__ float s4[4];
    const size_t PSTR = (size_t)ROWS * D_MODEL;
    int row = blockIdx.x;
    int b = row >> 9;
    const float* hp = hin + (size_t)row * D_MODEL;
    float* rp = residual + (size_t)row * D_MODEL;
    float v[3]; float ss = 0.f;
    #pragma unroll
    for (int j = 0; j < 3; j++) {
        int d = threadIdx.x + j * 256;
        float x = hp[d];
        if (has_raw) {
            float g = affprev[b * AFF + 3840 + d];
            float rawv = raw[(size_t)row * D_MODEL + d] + raw[PSTR + (size_t)row * D_MODEL + d];
            x += g * (rawv + bias[d]);
        }
        x += rp[d];
        rp[d] = x; v[j] = x; ss += x * x;
    }
    ss = block_sum_256(ss, s4);
    float inv = rsqrtf(ss / (float)D_MODEL + 1e-5f);
    const float* sh = affcur + b * AFF;
    const float* sc = affcur + b * AFF + 768;
    #pragma unroll
    for (int j = 0; j < 3; j++) {
        int d = threadIdx.x + j * 256;
        float hn = v[j] * inv * normw[d];
        hidden_n[(size_t)row * D_MODEL + d] = hn;
        u[(size_t)row * D_MODEL + d] = f2b(hn * (1.f + sc[d]) + sh[d]);
    }
}

// ---------------- depthwise causal conv + silu, fused softplus(dt) ----------------
__global__ void k_convdt(const float* __restrict__ zx, const float* __restrict__ convw,
                         const float* __restrict__ convb, const float* __restrict__ dtbias,
                         float* __restrict__ xBC, float* __restrict__ dtb) {
    int i = blockIdx.x * 256 + threadIdx.x;
    if (i < ROWS * NHEADS) {
        int h = i % NHEADS; int row = i / NHEADS;
        float x = zx[(size_t)row * D_IN_PROJ + D_INNER + CONV_DIM + h] + dtbias[h];
        dtb[i] = (x > 20.f) ? x : log1pf(expf(x));
    }
    if (i >= ROWS * CONV_DIM) return;
    int c = i % CONV_DIM; int row = i / CONV_DIM;
    int l = row & 511; int b = row >> 9;
    float acc = convb[c];
    #pragma unroll
    for (int k = 0; k < 4; k++) {
        int t = l - 3 + k;
        if (t >= 0)
            acc += convw[c * 4 + k] * zx[(size_t)(b * SEQ + t) * D_IN_PROJ + D_INNER + c];
    }
    xBC[i] = siluf(acc);
}

// ---------------- fused SSM: per-(b,h) block, 8 chunks sequential, h in registers ------
// Per chunk c: out-pass uses pre-update h (written bf16 to sHB), then state MFMA + h update.
__global__ __launch_bounds__(256)
void k_ssm_fused(const float* __restrict__ xBC, const float* __restrict__ dtb,
                 const float* __restrict__ Alog, const float* __restrict__ Dssm,
                 float* __restrict__ y) {
    __shared__ unsigned short sB[64][136];    // [t][n] B matrix
    __shared__ unsigned short sC[64][136];    // [t][n] C matrix; scaled by exp(L_t) mid-chunk
    __shared__ unsigned short sXT[64][72];    // [p][t]
    __shared__ unsigned short sG[64][72];     // G[i][s]; reused as XwT [p][t] for state pass
    __shared__ unsigned short sBT[128][72];   // [n][t]
    __shared__ unsigned short sHB[64][136];   // h_start bf16 [p][n]
    __shared__ float sL[64], sDt[64];
    int bh = blockIdx.x;
    int h = bh % NHEADS, b = bh / NHEADS;
    int tid = threadIdx.x;
    int lane = tid & 63, wave = tid >> 6;
    int l15 = lane & 15, quad = lane >> 4;
    int r = tid >> 2, q4 = tid & 3;
    float a_h = expf(Alog[h]);
    float Dh = Dssm[h];
    f32x4 hreg[8];
    #pragma unroll
    for (int nt = 0; nt < 8; nt++) hreg[nt] = (f32x4){0.f, 0.f, 0.f, 0.f};

    for (int c = 0; c < NCHUNK; c++) {
        __syncthreads();      // previous chunk's LDS reads done before restaging
        int base = b * SEQ + c * CT;
        if (tid < 64) {
            float dt = dtb[(base + tid) * NHEADS + h];
            float v = -a_h * dt;
            #pragma unroll
            for (int off = 1; off < 64; off <<= 1) {
                float u2 = __shfl_up(v, off, 64);
                if (tid >= off) v += u2;
            }
            sL[tid] = v; sDt[tid] = dt;
        }
        // h_start -> LDS bf16 at this thread's accumulator coords
        #pragma unroll
        for (int nt = 0; nt < 8; nt++) {
            int n = nt * 16 + l15;
            #pragma unroll
            for (int rr = 0; rr < 4; rr++) {
                int pp = wave * 16 + quad * 4 + rr;
                sHB[pp][n] = f2b(hreg[nt][rr]);
            }
        }
        const float* xrow = xBC + (size_t)(base + r) * CONV_DIM;
        #pragma unroll
        for (int j = 0; j < 8; j++) {
            float4 v = *(const float4*)&xrow[D_INNER + q4 * 32 + j * 4];
            int n0 = q4 * 32 + j * 4;
            ushort4 pk; pk.x = f2b(v.x); pk.y = f2b(v.y); pk.z = f2b(v.z); pk.w = f2b(v.w);
            *(ushort4*)&sB[r][n0] = pk;
            sBT[n0 + 0][r] = pk.x; sBT[n0 + 1][r] = pk.y;
            sBT[n0 + 2][r] = pk.z; sBT[n0 + 3][r] = pk.w;
            float4 w = *(const float4*)&xrow[D_INNER + D_STATE + q4 * 32 + j * 4];
            ushort4 pk2; pk2.x = f2b(w.x); pk2.y = f2b(w.y); pk2.z = f2b(w.z); pk2.w = f2b(w.w);
            *(ushort4*)&sC[r][n0] = pk2;
        }
        #pragma unroll
        for (int j = 0; j < 4; j++) {
            float4 v = *(const float4*)&xrow[h * HEADDIM + q4 * 16 + j * 4];
            int p0 = q4 * 16 + j * 4;
            sXT[p0 + 0][r] = f2b(v.x); sXT[p0 + 1][r] = f2b(v.y);
            sXT[p0 + 2][r] = f2b(v.z); sXT[p0 + 3][r] = f2b(v.w);
        }
        __syncthreads();
        float Pc = expf(sL[63]);

        // acc1 = C·B^T  (CB[t][s])
        f32x4 acc1[4];
        #pragma unroll
        for (int j = 0; j < 4; j++) acc1[j] = (f32x4){0.f, 0.f, 0.f, 0.f};
        #pragma unroll
        for (int k0 = 0; k0 < 4; k0++) {
            bf16x8 a = *(const bf16x8*)&sC[wave * 16 + l15][k0 * 32 + quad * 8];
            #pragma unroll
            for (int nt = 0; nt < 4; nt++) {
                bf16x8 bv = *(const bf16x8*)&sB[nt * 16 + l15][k0 * 32 + quad * 8];
                acc1[nt] = __builtin_amdgcn_mfma_f32_16x16x32_bf16(a, bv, acc1[nt], 0, 0, 0);
            }
        }
        // G[i][s] = causal mask * CB * exp(L_i - L_s) * dt_s
        #pragma unroll
        for (int nt = 0; nt < 4; nt++) {
            int s = nt * 16 + l15;
            float Ls = sL[s], dts = sDt[s];
            #pragma unroll
            for (int rr = 0; rr < 4; rr++) {
                int i = wave * 16 + quad * 4 + rr;
                float g = (s <= i) ? acc1[nt][rr] * expf(sL[i] - Ls) * dts : 0.f;
                sG[i][s] = f2b(g);
            }
        }
        // scale C rows by exp(L_t) (each wave touches only its own 16-row stripe)
        {
            int row2 = wave * 16 + l15;
            float el = expf(sL[row2]);
            #pragma unroll
            for (int j = 0; j < 32; j++) {
                int n = quad * 32 + j;
                sC[row2][n] = f2b(b2f(sC[row2][n]) * el);
            }
        }
        __syncthreads();

        // acc2 = G·X^T + C̃·h0^T
        f32x4 acc2[4];
        #pragma unroll
        for (int j = 0; j < 4; j++) acc2[j] = (f32x4){0.f, 0.f, 0.f, 0.f};
        #pragma unroll
        for (int k0 = 0; k0 < 2; k0++) {
            bf16x8 a = *(const bf16x8*)&sG[wave * 16 + l15][k0 * 32 + quad * 8];
            #pragma unroll
            for (int nt = 0; nt < 4; nt++) {
                bf16x8 bv = *(const bf16x8*)&sXT[nt * 16 + l15][k0 * 32 + quad * 8];
                acc2[nt] = __builtin_amdgcn_mfma_f32_16x16x32_bf16(a, bv, acc2[nt], 0, 0, 0);
            }
        }
        #pragma unroll
        for (int k0 = 0; k0 < 4; k0++) {
            bf16x8 a = *(const bf16x8*)&sC[wave * 16 + l15][k0 * 32 + quad * 8];
            #pragma unroll
            for (int nt = 0; nt < 4; nt++) {
                bf16x8 bv = *(const bf16x8*)&sHB[nt * 16 + l15][k0 * 32 + quad * 8];
                acc2[nt] = __builtin_amdgcn_mfma_f32_16x16x32_bf16(a, bv, acc2[nt], 0, 0, 0);
            }
        }
        #pragma unroll
        for (int nt = 0; nt < 4; nt++) {
            int p = nt * 16 + l15;
            #pragma unroll
            for (int rr = 0; rr < 4; rr++) {
                int i = wave * 16 + quad * 4 + rr;
                float xv = b2f(sXT[p][i]);
                y[(size_t)(base + i) * D_INNER + h * HEADDIM + p] = acc2[nt][rr] + Dh * xv;
            }
        }
        __syncthreads();
        // XwT[p][t] = X[t][p] * exp(Lend - L_t) * dt_t  (reuse sG)
        {
            float wr2 = expf(sL[63] - sL[r]) * sDt[r];
            #pragma unroll
            for (int j = 0; j < 16; j++) {
                int pp = q4 * 16 + j;
                sG[pp][r] = f2b(b2f(sXT[pp][r]) * wr2);
            }
        }
        __syncthreads();
        // state S[p][n] = Xw·B ; h = h*Pc + S
        f32x4 accS[8];
        #pragma unroll
        for (int j = 0; j < 8; j++) accS[j] = (f32x4){0.f, 0.f, 0.f, 0.f};
        #pragma unroll
        for (int k0 = 0; k0 < 2; k0++) {
            bf16x8 a = *(const bf16x8*)&sG[wave * 16 + l15][k0 * 32 + quad * 8];
            #pragma unroll
            for (int nt = 0; nt < 8; nt++) {
                bf16x8 bv = *(const bf16x8*)&sBT[nt * 16 + l15][k0 * 32 + quad * 8];
                accS[nt] = __builtin_amdgcn_mfma_f32_16x16x32_bf16(a, bv, accS[nt], 0, 0, 0);
            }
        }
        #pragma unroll
        for (int nt = 0; nt < 8; nt++)
            #pragma unroll
            for (int rr = 0; rr < 4; rr++)
                hreg[nt][rr] = hreg[nt][rr] * Pc + accS[nt][rr];
    }
}

// ---------------- gated rmsnorm -> bf16 ----------------
__global__ void k_gatednorm(const float* __restrict__ yscan, const float* __restrict__ zx,
                            const float* __restrict__ nw, unsigned short* __restrict__ out) {
    __shared__ float s4[4];
    int row = blockIdx.x;
    const float* yp = yscan + (size_t)row * D_INNER;
    const float* zp = zx + (size_t)row * D_IN_PROJ;
    float v[6]; float ss = 0.f;
    #pragma unroll
    for (int j = 0; j < 6; j++) {
        int d = threadIdx.x + j * 256;
        float val = yp[d] * siluf(zp[d]);
        v[j] = val; ss += val * val;
    }
    ss = block_sum_256(ss, s4);
    float inv = rsqrtf(ss / (float)D_INNER + 1e-5f);
    #pragma unroll
    for (int j = 0; j < 6; j++) {
        int d = threadIdx.x + j * 256;
        out[(size_t)row * D_INNER + d] = f2b(v[j] * inv * nw[d]);
    }
}

// ---------------- hidden2 = hidden_n + g_mba*(Σ tmp partials + out_b); ln + msa mod ----
__global__ void k_fuse_ln(const float* __restrict__ hidden_n, const float* __restrict__ tmp,
                          const float* __restrict__ outb, const float* __restrict__ aff,
                          float* __restrict__ hidden2, unsigned short* __restrict__ attnx) {
    __shared__ float s4[4];
    const size_t PSTR = (size_t)ROWS * D_MODEL;
    int row = blockIdx.x;
    int b = row >> 9;
    const float* gm = aff + b * AFF + 1536;
    float v[3]; float s = 0.f;
    #pragma unroll
    for (int j = 0; j < 3; j++) {
        int d = threadIdx.x + j * 256;
        size_t idx = (size_t)row * D_MODEL + d;
        float t = tmp[idx] + tmp[idx + PSTR] + tmp[idx + 2 * PSTR] + tmp[idx + 3 * PSTR];
        float x = hidden_n[idx] + gm[d] * (t + outb[d]);
        hidden2[idx] = x;
        v[j] = x; s += x;
    }
    float mean = block_sum_256(s, s4) / (float)D_MODEL;
    float ss = 0.f;
    #pragma unroll
    for (int j = 0; j < 3; j++) { float c = v[j] - mean; ss += c * c; }
    float var = block_sum_256(ss, s4) / (float)D_MODEL;
    float inv = rsqrtf(var + 1e-6f);
    const float* sh = aff + b * AFF + 2304;
    const float* sc = aff + b * AFF + 3072;
    #pragma unroll
    for (int j = 0; j < 3; j++) {
        int d = threadIdx.x + j * 256;
        float xh = (v[j] - mean) * inv;
        attnx[(size_t)row * D_MODEL + d] = f2b(xh * (1.f + sc[d]) + sh[d]);
    }
}

// ---------------- cross-attention with fused Q-projection (MFMA) ----------------
// block per (b,h,32-query tile): Q = attnx[32,768] @ Wq_h[768,64], then softmax/PV.
__global__ __launch_bounds__(256)
void k_attn(const unsigned short* __restrict__ attnx, const unsigned short* __restrict__ qwt,
            const unsigned short* __restrict__ kb, const unsigned short* __restrict__ vb,
            unsigned short* __restrict__ ob) {
    int blk = blockIdx.x;
    int lt = blk & 15; int h = (blk >> 4) & 7; int b = blk >> 7;
    __shared__ unsigned short sK[64][66];
    __shared__ unsigned short sV[64][66];
    __shared__ unsigned short sA[32][136];
    __shared__ unsigned short sW[64][136];
    __shared__ float sQf[32][68];
    int tid = threadIdx.x;
    // stage K/V first (loads issue early, hide under Q-GEMM)
    {
        int r = tid >> 2, c0 = (tid & 3) * 16;
        const unsigned short* kp = kb + (size_t)(b * LC + r) * AINNER + h * AD + c0;
        const unsigned short* vp = vb + (size_t)(b * LC + r) * AINNER + h * AD + c0;
        #pragma unroll
        for (int j = 0; j < 4; j++) {
            *(ushort4*)&sK[r][c0 + j * 4] = *(const ushort4*)&kp[j * 4];
            *(ushort4*)&sV[r][c0 + j * 4] = *(const ushort4*)&vp[j * 4];
        }
    }
    int lane = tid & 63, wave = tid >> 6;
    int l15 = lane & 15, quad = lane >> 4;
    int rt = wave >> 1, cp = (wave & 1) * 2;
    f32x4 accq[2];
    accq[0] = (f32x4){0.f, 0.f, 0.f, 0.f};
    accq[1] = (f32x4){0.f, 0.f, 0.f, 0.f};
    const size_t arow_base = (size_t)(b * SEQ + lt * 32) * D_MODEL;
    for (int k0 = 0; k0 < D_MODEL; k0 += 128) {
        __syncthreads();
        #pragma unroll
        for (int j = 0; j < 2; j++) {
            int s = tid + j * 256; int row = s >> 4, c8 = (s & 15) * 8;
            *(uint4*)&sA[row][c8] =
                *(const uint4*)&attnx[arow_base + (size_t)row * D_MODEL + k0 + c8];
        }
        #pragma unroll
        for (int j = 0; j < 4; j++) {
            int s = tid + j * 256; int row = s >> 4, c8 = (s & 15) * 8;
            *(uint4*)&sW[row][c8] =
                *(const uint4*)&qwt[(size_t)(h * AD + row) * D_MODEL + k0 + c8];
        }
        __syncthreads();
        #pragma unroll
        for (int ks = 0; ks < 4; ks++) {
            bf16x8 af = *(const bf16x8*)&sA[rt * 16 + l15][ks * 32 + quad * 8];
            #pragma unroll
            for (int j = 0; j < 2; j++) {
                bf16x8 bf = *(const bf16x8*)&sW[(cp + j) * 16 + l15][ks * 32 + quad * 8];
                accq[j] = __builtin_amdgcn_mfma_f32_16x16x32_bf16(af, bf, accq[j], 0, 0, 0);
            }
        }
    }
    #pragma unroll
    for (int j = 0; j < 2; j++)
        #pragma unroll
        for (int rr = 0; rr < 4; rr++)
            sQf[rt * 16 + quad * 4 + rr][(cp + j) * 16 + l15] = accq[j][rr] * 0.125f;
    __syncthreads();
    int m = lane;
    #pragma unroll
    for (int qq = 0; qq < 8; qq++) {
        int q = wave * 8 + qq;
        float s = 0.f;
        #pragma unroll 8
        for (int d = 0; d < AD; d++) s += sQf[q][d] * b2f(sK[m][d]);
        float mx = s;
        #pragma unroll
        for (int off = 32; off > 0; off >>= 1) mx = fmaxf(mx, __shfl_xor(mx, off, 64));
        float e = expf(s - mx);
        float sum = e;
        #pragma unroll
        for (int off = 32; off > 0; off >>= 1) sum += __shfl_xor(sum, off, 64);
        float a = e / sum;
        float acc = 0.f;
        #pragma unroll 8
        for (int mm = 0; mm < LC; mm++) {
            float am = __shfl(a, mm, 64);
            acc += am * b2f(sV[mm][m]);
        }
        ob[(size_t)(b * SEQ + lt * 32 + q) * AINNER + h * AD + m] = f2b(acc);
    }
}

// ---------------- final: h = hidden2 + g*(Σ raw partials + bias); rmsnorm(h + r) --------
__global__ void k_final(const float* __restrict__ hidden2, const float* __restrict__ raw,
                        const float* __restrict__ bias, const float* __restrict__ aff,
                        const float* __restrict__ residual, const float* __restrict__ w,
                        float* __restrict__ out) {
    __shared__ float s4[4];
    const size_t PSTR = (size_t)ROWS * D_MODEL;
    int row = blockIdx.x;
    int b = row >> 9;
    const float* gm = aff + b * AFF + 3840;
    float v[3]; float ss = 0.f;
    #pragma unroll
    for (int j = 0; j < 3; j++) {
        int d = threadIdx.x + j * 256;
        size_t idx = (size_t)row * D_MODEL + d;
        float rawv = raw[idx] + raw[idx + PSTR];
        float x = hidden2[idx] + gm[d] * (rawv + bias[d]) + residual[idx];
        v[j] = x; ss += x * x;
    }
    ss = block_sum_256(ss, s4);
    float inv = rsqrtf(ss / (float)D_MODEL + 1e-5f);
    #pragma unroll
    for (int j = 0; j < 3; j++) {
        int d = threadIdx.x + j * 256;
        out[(size_t)row * D_MODEL + d] = v[j] * inv * w[d];
    }
}

// ---------------- host launch ----------------
extern "C" void kernel_launch(void* const* d_in, const int* in_sizes, int n_in,
                              void* d_out, int out_size, void* d_ws, size_t ws_size,
                              hipStream_t stream) {
    const float* hidden_states = (const float*)d_in[0];
    const float* ref_emb  = (const float*)d_in[1];
    const float* norm_w   = (const float*)d_in[2];
    const float* ada_w    = (const float*)d_in[3];
    const float* ada_b    = (const float*)d_in[4];
    const float* in_w     = (const float*)d_in[5];
    const float* conv_w   = (const float*)d_in[6];
    const float* conv_b   = (const float*)d_in[7];
    const float* dt_bias  = (const float*)d_in[8];
    const float* A_log    = (const float*)d_in[9];
    const float* D_ssm    = (const float*)d_in[10];
    const float* ssm_nw   = (const float*)d_in[11];
    const float* out_w    = (const float*)d_in[12];
    const float* out_b    = (const float*)d_in[13];
    const float* q_w      = (const float*)d_in[14];
    const float* k_w      = (const float*)d_in[15];
    const float* v_w      = (const float*)d_in[16];
    const float* o_w      = (const float*)d_in[17];
    const float* o_b      = (const float*)d_in[18];
    const float* norm_f_w = (const float*)d_in[19];
    float* out = (float*)d_out;

    char* p = (char*)d_ws;
    auto alloc = [&](size_t bytes) -> char* {
        char* r = p; p += (bytes + 255) & ~(size_t)255; return r;
    };
    float* residual = (float*)alloc((size_t)ROWS * D_MODEL * 4);
    float* hidden2  = (float*)alloc((size_t)ROWS * D_MODEL * 4);
    float* hidden_n = (float*)alloc((size_t)ROWS * D_MODEL * 4);
    float* tmpM     = (float*)alloc((size_t)4 * ROWS * D_MODEL * 4);  // out-proj partials
    float* tmpO     = (float*)alloc((size_t)2 * ROWS * D_MODEL * 4);  // o-proj partials
    float* zx       = (float*)alloc((size_t)ROWS * D_IN_PROJ * 4);
    float* xBC      = (float*)alloc((size_t)ROWS * CONV_DIM * 4);
    float* dtb      = (float*)alloc((size_t)ROWS * NHEADS * 4);
    float* yscan    = (float*)alloc((size_t)ROWS * D_INNER * 4);
    float* aff_all  = (float*)alloc((size_t)N_LAYER * BSZ * AFF * 4);
    float* smc      = (float*)alloc((size_t)BSZ * D_MODEL * 4);
    unsigned short* u_bf   = (unsigned short*)alloc((size_t)ROWS * D_MODEL * 2);
    unsigned short* ynorm  = (unsigned short*)alloc((size_t)ROWS * D_INNER * 2);
    unsigned short* attnx  = (unsigned short*)alloc((size_t)ROWS * D_MODEL * 2);
    unsigned short* ob     = (unsigned short*)alloc((size_t)ROWS * AINNER * 2);
    unsigned short* ref_bf = (unsigned short*)alloc((size_t)BSZ * LC * D_MODEL * 2);
    unsigned short* kb_all  = (unsigned short*)alloc((size_t)N_LAYER * BSZ * LC * AINNER * 2);
    unsigned short* vb_all  = (unsigned short*)alloc((size_t)N_LAYER * BSZ * LC * AINNER * 2);
    unsigned short* in_wt_all  = (unsigned short*)alloc((size_t)N_LAYER * NP1 * D_MODEL * 2);
    unsigned short* out_wt_all = (unsigned short*)alloc((size_t)N_LAYER * D_MODEL * D_INNER * 2);
    unsigned short* q_wt_all   = (unsigned short*)alloc((size_t)N_LAYER * AINNER * D_MODEL * 2);
    unsigned short* o_wt_all   = (unsigned short*)alloc((size_t)N_LAYER * D_MODEL * AINNER * 2);
    unsigned short* kwt_all = (unsigned short*)alloc((size_t)N_LAYER * AINNER * D_MODEL * 2);
    unsigned short* vwt_all = (unsigned short*)alloc((size_t)N_LAYER * AINNER * D_MODEL * 2);

    hipMemsetAsync(residual, 0, (size_t)ROWS * D_MODEL * sizeof(float), stream);
    k_pre<<<678, 256, 0, stream>>>(ref_emb, ref_bf, smc, ada_b, aff_all);
    k_ada_split<<<dim3(AFF / 256, 8, N_LAYER), 256, 0, stream>>>(smc, ada_w, aff_all);

    // weight transposes (batched over layers; q/k/v share one launch)
    k_transpose_pb<<<dim3(NP1 / 32, D_MODEL / 32, N_LAYER), 256, 0, stream>>>(in_w, in_wt_all, D_MODEL, D_IN_PROJ, NP1);
    k_transpose_pb<<<dim3(D_MODEL / 32, D_INNER / 32, N_LAYER), 256, 0, stream>>>(out_w, out_wt_all, D_INNER, D_MODEL, D_MODEL);
    k_transpose_qkv<<<dim3(AINNER / 32, D_MODEL / 32, 3 * N_LAYER), 256, 0, stream>>>(q_w, k_w, v_w, q_wt_all, kwt_all, vwt_all);
    k_transpose_pb<<<dim3(D_MODEL / 32, AINNER / 32, N_LAYER), 256, 0, stream>>>(o_w, o_wt_all, AINNER, D_MODEL, D_MODEL);
    k_gemm_kv<<<dim3(AINNER / 128, 1, N_LAYER * 2), 256, 0, stream>>>(ref_bf, kwt_all, vwt_all, kb_all, vb_all);

    for (int layer = 0; layer < N_LAYER; layer++) {
        const float* L_norm_w  = norm_w  + layer * D_MODEL;
        const float* L_conv_w  = conv_w  + layer * CONV_DIM * 4;
        const float* L_conv_b  = conv_b  + layer * CONV_DIM;
        const float* L_dt_bias = dt_bias + layer * NHEADS;
        const float* L_A_log   = A_log   + layer * NHEADS;
        const float* L_D_ssm   = D_ssm   + layer * NHEADS;
        const float* L_ssm_nw  = ssm_nw  + layer * D_INNER;
        const float* L_out_b   = out_b   + layer * D_MODEL;
        const float* L_o_b_prev= o_b     + (layer - 1) * D_MODEL;
        const float* L_aff     = aff_all + (size_t)layer * BSZ * AFF;
        const float* L_aff_prev= aff_all + (size_t)(layer - 1) * BSZ * AFF;
        const unsigned short* in_wt  = in_wt_all  + (size_t)layer * NP1 * D_MODEL;
        const unsigned short* out_wt = out_wt_all + (size_t)layer * D_MODEL * D_INNER;
        const unsigned short* q_wt   = q_wt_all   + (size_t)layer * AINNER * D_MODEL;
        const unsigned short* o_wt   = o_wt_all   + (size_t)layer * D_MODEL * AINNER;

        k_addrmsmod<<<ROWS, 256, 0, stream>>>(
            layer == 0 ? hidden_states : hidden2, tmpO,
            layer == 0 ? o_b : L_o_b_prev,
            layer == 0 ? aff_all : L_aff_prev,
            residual, L_norm_w, L_aff, hidden_n, u_bf, layer == 0 ? 0 : 1);
        k_gemm<<<dim3(NP1 / 128, ROWS / 128), 256, 0, stream>>>(u_bf, in_wt, zx, ROWS, D_IN_PROJ, D_MODEL);
        k_convdt<<<(ROWS * CONV_DIM + 255) / 256, 256, 0, stream>>>(zx, L_conv_w, L_conv_b, L_dt_bias, xBC, dtb);
        k_ssm_fused<<<BSZ * NHEADS, 256, 0, stream>>>(xBC, dtb, L_A_log, L_D_ssm, yscan);
        k_gatednorm<<<ROWS, 256, 0, stream>>>(yscan, zx, L_ssm_nw, ynorm);
        k_gemm_sk<<<dim3(D_MODEL / 128, ROWS / 128, 4), 256, 0, stream>>>(ynorm, out_wt, tmpM, ROWS, D_MODEL, D_INNER, 384);
        k_fuse_ln<<<ROWS, 256, 0, stream>>>(hidden_n, tmpM, L_out_b, L_aff, hidden2, attnx);
        k_attn<<<BSZ * AH * 16, 256, 0, stream>>>(
            attnx, q_wt,
            kb_all + (size_t)layer * BSZ * LC * AINNER,
            vb_all + (size_t)layer * BSZ * LC * AINNER, ob);
        k_gemm_sk<<<dim3(D_MODEL / 128, ROWS / 128, 2), 256, 0, stream>>>(ob, o_wt, tmpO, ROWS, D_MODEL, AINNER, 256);
    }
    k_final<<<ROWS, 256, 0, stream>>>(hidden2, tmpO, o_b + (N_LAYER - 1) * D_MODEL,
                                      aff_all + (size_t)(N_LAYER - 1) * BSZ * AFF,
                                      residual, norm_f_w, out);
}

// Round 2
// 1369.235 us; speedup vs baseline: 1.2930x; 1.1973x over previous
//
#include <hip/hip_runtime.h>
#include <hip/hip_bf16.h>
#include <math.h>

// ---------------- constants ----------------
#define D_MODEL   768
#define N_LAYER   8
#define D_INNER   1536
#define D_STATE   128
#define HEADDIM   64
#define NHEADS    24
#define CONV_DIM  1792
#define D_IN_PROJ 3352
#define AH        8
#define AD        64
#define AINNER    512
#define BSZ       2
#define SEQ       512
#define LC        64
#define ROWS      (BSZ*SEQ)          // 1024
#define NCHUNK    8
#define CT        64                 // chunk length
#define NP1       3456               // 3352 padded to 27*128
#define AFF       4608

typedef __attribute__((ext_vector_type(8))) short bf16x8;
typedef __attribute__((ext_vector_type(4))) float f32x4;

__device__ __forceinline__ float siluf(float x) { return x / (1.f + expf(-x)); }

__device__ __forceinline__ unsigned short f2b(float x) {
    __hip_bfloat16 h = __float2bfloat16(x);
    return __builtin_bit_cast(unsigned short, h);
}
__device__ __forceinline__ float b2f(unsigned short u) {
    unsigned v = ((unsigned)u) << 16;
    return __builtin_bit_cast(float, v);
}

// async global->LDS 16B copy (wave-uniform base + lane*16 contiguity honored by callers)
__device__ __forceinline__ void gload16(const void* g, void* l) {
    __builtin_amdgcn_global_load_lds(
        (const __attribute__((address_space(1))) unsigned int*)g,
        (__attribute__((address_space(3))) unsigned int*)l,
        16, 0, 0);
}

// block-wide sum, 256 threads (4 waves)
__device__ __forceinline__ float block_sum_256(float v, float* s4) {
    #pragma unroll
    for (int o = 32; o > 0; o >>= 1) v += __shfl_down(v, o, 64);
    __syncthreads();
    if ((threadIdx.x & 63) == 0) s4[threadIdx.x >> 6] = v;
    __syncthreads();
    return s4[0] + s4[1] + s4[2] + s4[3];
}

// ---------------- fused preamble: ref f2b + silumean + aff bias init ----------------
__global__ void k_pre(const float* __restrict__ ref_emb, unsigned short* __restrict__ ref_bf,
                      float* __restrict__ smc, const float* __restrict__ adab,
                      float* __restrict__ aff_all) {
    int blk = blockIdx.x;
    if (blk < 384) {                              // f2b, exact 98304
        int i = blk * 256 + threadIdx.x;
        ref_bf[i] = f2b(ref_emb[i]);
    } else if (blk < 390) {                       // silu(mean(cond,1))
        int i = (blk - 384) * 256 + threadIdx.x;
        if (i < BSZ * D_MODEL) {
            int b = i / D_MODEL, d = i % D_MODEL;
            const float* p = ref_emb + (size_t)b * LC * D_MODEL + d;
            float s = 0.f;
            #pragma unroll 4
            for (int l = 0; l < LC; l++) s += p[l * D_MODEL];
            smc[i] = siluf(s * (1.f / (float)LC));
        }
    } else {                                      // aff init with bias, exact 73728
        int i = (blk - 390) * 256 + threadIdx.x;
        int j = i % AFF; int l = (i / AFF) >> 1;
        aff_all[i] = adab[l * AFF + j];
    }
}

// ---------------- batched padded transpose: src fp32 [L][K][N] -> dst bf16 [L][Npad][K] ----
__global__ void k_transpose_pb(const float* __restrict__ src, unsigned short* __restrict__ dst,
                               int K, int N, int Npad) {
    int z = blockIdx.z;
    src += (size_t)z * K * N;
    dst += (size_t)z * Npad * K;
    __shared__ float tile[32][33];
    int n0 = blockIdx.x * 32, k0 = blockIdx.y * 32;
    int t = threadIdx.x;
    int nl = t & 31, kl = t >> 5;
    #pragma unroll
    for (int p = 0; p < 4; p++) {
        int k = kl + p * 8;
        int n = n0 + nl;
        tile[k][nl] = (n < N) ? src[(size_t)(k0 + k) * N + n] : 0.f;
    }
    __syncthreads();
    int kl2 = t & 31, nl2 = t >> 5;
    #pragma unroll
    for (int p = 0; p < 4; p++) {
        int n = nl2 + p * 8;
        dst[(size_t)(n0 + n) * K + k0 + kl2] = f2b(tile[kl2][n]);
    }
}

// q/k/v transposes share geometry (K=768, N=Npad=512): one batched launch
__global__ void k_transpose_qkv(const float* __restrict__ qw, const float* __restrict__ kw,
                                const float* __restrict__ vw, unsigned short* __restrict__ qd,
                                unsigned short* __restrict__ kd, unsigned short* __restrict__ vd) {
    int z = blockIdx.z;                 // 0..23
    int which = z >> 3, layer = z & 7;
    const float* src = (which == 0 ? qw : which == 1 ? kw : vw) + (size_t)layer * D_MODEL * AINNER;
    unsigned short* dst = (which == 0 ? qd : which == 1 ? kd : vd) + (size_t)layer * AINNER * D_MODEL;
    __shared__ float tile[32][33];
    int n0 = blockIdx.x * 32, k0 = blockIdx.y * 32;
    int t = threadIdx.x;
    int nl = t & 31, kl = t >> 5;
    #pragma unroll
    for (int p = 0; p < 4; p++) {
        int k = kl + p * 8;
        tile[k][nl] = src[(size_t)(k0 + k) * AINNER + n0 + nl];
    }
    __syncthreads();
    int kl2 = t & 31, nl2 = t >> 5;
    #pragma unroll
    for (int p = 0; p < 4; p++) {
        int n = nl2 + p * 8;
        dst[(size_t)(n0 + n) * D_MODEL + k0 + kl2] = f2b(tile[kl2][n]);
    }
}

// ---------------- bf16 MFMA GEMM with async LDS staging ----------------
// C[M,N] = A[M,K] @ Bt[N,K]^T ; A,Bt bf16 row-major; C fp32
__global__ __launch_bounds__(256)
void k_gemm(const unsigned short* __restrict__ A, const unsigned short* __restrict__ Bt,
            float* __restrict__ C, int M, int N, int K) {
    __shared__ __align__(16) unsigned short As[128][32];
    __shared__ __align__(16) unsigned short Bs[128][32];
    int m0 = blockIdx.y * 128, n0 = blockIdx.x * 128;
    int tid = threadIdx.x;
    int lane = tid & 63, wave = tid >> 6;
    int wm = (wave >> 1) * 64, wn = (wave & 1) * 64;
    int l15 = lane & 15, quad = lane >> 4;
    f32x4 acc[4][4];
    #pragma unroll
    for (int i = 0; i < 4; i++)
        #pragma unroll
        for (int j = 0; j < 4; j++) acc[i][j] = (f32x4){0.f, 0.f, 0.f, 0.f};

    int srow = tid >> 2;
    int schunk = (tid & 3) * 8;

    for (int k0 = 0; k0 < K; k0 += 32) {
        #pragma unroll
        for (int ps = 0; ps < 2; ps++) {
            int r = srow + ps * 64;
            gload16(&A[(size_t)(m0 + r) * K + k0 + schunk], &As[r][schunk]);
            gload16(&Bt[(size_t)(n0 + r) * K + k0 + schunk], &Bs[r][schunk]);
        }
        __syncthreads();
        bf16x8 af[4], bfr[4];
        #pragma unroll
        for (int i = 0; i < 4; i++) af[i]  = *(const bf16x8*)&As[wm + i * 16 + l15][quad * 8];
        #pragma unroll
        for (int j = 0; j < 4; j++) bfr[j] = *(const bf16x8*)&Bs[wn + j * 16 + l15][quad * 8];
        #pragma unroll
        for (int i = 0; i < 4; i++)
            #pragma unroll
            for (int j = 0; j < 4; j++)
                acc[i][j] = __builtin_amdgcn_mfma_f32_16x16x32_bf16(af[i], bfr[j], acc[i][j], 0, 0, 0);
        __syncthreads();
    }
    #pragma unroll
    for (int i = 0; i < 4; i++) {
        #pragma unroll
        for (int j = 0; j < 4; j++) {
            int col = n0 + wn + j * 16 + l15;
            if (col < N) {
                #pragma unroll
                for (int r = 0; r < 4; r++) {
                    int row = m0 + wm + i * 16 + quad * 4 + r;
                    C[(size_t)row * N + col] = acc[i][j][r];
                }
            }
        }
    }
}

// split-K variant: grid.z = number of K-slices of width Kc; partial written to C + z*M*N
__global__ __launch_bounds__(256)
void k_gemm_sk(const unsigned short* __restrict__ A, const unsigned short* __restrict__ Bt,
               float* __restrict__ C, int M, int N, int K, int Kc) {
    int z = blockIdx.z;
    C += (size_t)z * M * N;
    int kbeg = z * Kc;
    int kend = kbeg + Kc; if (kend > K) kend = K;
    __shared__ __align__(16) unsigned short As[128][32];
    __shared__ __align__(16) unsigned short Bs[128][32];
    int m0 = blockIdx.y * 128, n0 = blockIdx.x * 128;
    int tid = threadIdx.x;
    int lane = tid & 63, wave = tid >> 6;
    int wm = (wave >> 1) * 64, wn = (wave & 1) * 64;
    int l15 = lane & 15, quad = lane >> 4;
    f32x4 acc[4][4];
    #pragma unroll
    for (int i = 0; i < 4; i++)
        #pragma unroll
        for (int j = 0; j < 4; j++) acc[i][j] = (f32x4){0.f, 0.f, 0.f, 0.f};

    int srow = tid >> 2;
    int schunk = (tid & 3) * 8;

    for (int k0 = kbeg; k0 < kend; k0 += 32) {
        #pragma unroll
        for (int ps = 0; ps < 2; ps++) {
            int r = srow + ps * 64;
            gload16(&A[(size_t)(m0 + r) * K + k0 + schunk], &As[r][schunk]);
            gload16(&Bt[(size_t)(n0 + r) * K + k0 + schunk], &Bs[r][schunk]);
        }
        __syncthreads();
        bf16x8 af[4], bfr[4];
        #pragma unroll
        for (int i = 0; i < 4; i++) af[i]  = *(const bf16x8*)&As[wm + i * 16 + l15][quad * 8];
        #pragma unroll
        for (int j = 0; j < 4; j++) bfr[j] = *(const bf16x8*)&Bs[wn + j * 16 + l15][quad * 8];
        #pragma unroll
        for (int i = 0; i < 4; i++)
            #pragma unroll
            for (int j = 0; j < 4; j++)
                acc[i][j] = __builtin_amdgcn_mfma_f32_16x16x32_bf16(af[i], bfr[j], acc[i][j], 0, 0, 0);
        __syncthreads();
    }
    #pragma unroll
    for (int i = 0; i < 4; i++) {
        #pragma unroll
        for (int j = 0; j < 4; j++) {
            int col = n0 + wn + j * 16 + l15;
            if (col < N) {
                #pragma unroll
                for (int r = 0; r < 4; r++) {
                    int row = m0 + wm + i * 16 + quad * 4 + r;
                    C[(size_t)row * N + col] = acc[i][j][r];
                }
            }
        }
    }
}

// batched K/V projection -> bf16 out
__global__ __launch_bounds__(256)
void k_gemm_kv(const unsigned short* __restrict__ A, const unsigned short* __restrict__ Kwt,
               const unsigned short* __restrict__ Vwt, unsigned short* __restrict__ Kb,
               unsigned short* __restrict__ Vb) {
    int z = blockIdx.z; int layer = z >> 1; int which = z & 1;
    const unsigned short* Bt = (which ? Vwt : Kwt) + (size_t)layer * AINNER * D_MODEL;
    unsigned short* C = (which ? Vb : Kb) + (size_t)layer * (BSZ * LC) * AINNER;
    __shared__ __align__(16) unsigned short As[128][32];
    __shared__ __align__(16) unsigned short Bs[128][32];
    int n0 = blockIdx.x * 128;
    int tid = threadIdx.x;
    int lane = tid & 63, wave = tid >> 6;
    int wm = (wave >> 1) * 64, wn = (wave & 1) * 64;
    int l15 = lane & 15, quad = lane >> 4;
    f32x4 acc[4][4];
    #pragma unroll
    for (int i = 0; i < 4; i++)
        #pragma unroll
        for (int j = 0; j < 4; j++) acc[i][j] = (f32x4){0.f, 0.f, 0.f, 0.f};
    int srow = tid >> 2, schunk = (tid & 3) * 8;
    for (int k0 = 0; k0 < D_MODEL; k0 += 32) {
        #pragma unroll
        for (int ps = 0; ps < 2; ps++) {
            int r = srow + ps * 64;
            gload16(&A[(size_t)r * D_MODEL + k0 + schunk], &As[r][schunk]);
            gload16(&Bt[(size_t)(n0 + r) * D_MODEL + k0 + schunk], &Bs[r][schunk]);
        }
        __syncthreads();
        bf16x8 af[4], bfr[4];
        #pragma unroll
        for (int i = 0; i < 4; i++) af[i]  = *(const bf16x8*)&As[wm + i * 16 + l15][quad * 8];
        #pragma unroll
        for (int j = 0; j < 4; j++) bfr[j] = *(const bf16x8*)&Bs[wn + j * 16 + l15][quad * 8];
        #pragma unroll
        for (int i = 0; i < 4; i++)
            #pragma unroll
            for (int j = 0; j < 4; j++)
                acc[i][j] = __builtin_amdgcn_mfma_f32_16x16x32_bf16(af[i], bfr[j], acc[i][j], 0, 0, 0);
        __syncthreads();
    }
    #pragma unroll
    for (int i = 0; i < 4; i++) {
        #pragma unroll
        for (int j = 0; j < 4; j++) {
            int col = n0 + wn + j * 16 + l15;
            #pragma unroll
            for (int r = 0; r < 4; r++) {
                int row = wm + i * 16 + quad * 4 + r;
                C[(size_t)row * AINNER + col] = f2b(acc[i][j][r]);
            }
        }
    }
}

// ---------------- split-K ada ----------------
__global__ void k_ada_split(const float* __restrict__ smc, const float* __restrict__ adaw,
                            float* __restrict__ aff_all) {
    int l = blockIdx.z;
    int kc = blockIdx.y;
    int j = blockIdx.x * 256 + threadIdx.x;
    const float* w = adaw + (size_t)l * D_MODEL * AFF + j;
    const float* x0 = smc;
    const float* x1 = smc + D_MODEL;
    float s0 = 0.f, s1 = 0.f;
    int d0 = kc * 96;
    #pragma unroll 8
    for (int d = d0; d < d0 + 96; d++) {
        float wv = w[(size_t)d * AFF];
        s0 += x0[d] * wv; s1 += x1[d] * wv;
    }
    atomicAdd(&aff_all[(size_t)l * BSZ * AFF + j], s0);
    atomicAdd(&aff_all[(size_t)l * BSZ * AFF + AFF + j], s1);
}

// ---------------- [fused prev-attn out (2 split-K partials)] + residual + rmsnorm + mod ----
__global__ void k_addrmsmod(const float* __restrict__ hin, const float* __restrict__ raw,
                            const float* __restrict__ bias, const float* __restrict__ affprev,
                            float* __restrict__ residual, const float* __restrict__ normw,
                            const float* __restrict__ affcur,
                            float* __restrict__ hidden_n, unsigned short* __restrict__ u,
                            int has_raw) {
    __shared__ float s4[4];
    const size_t PSTR = (size_t)ROWS * D_MODEL;
    int row = blockIdx.x;
    int b = row >> 9;
    const float* hp = hin + (size_t)row * D_MODEL;
    float* rp = residual + (size_t)row * D_MODEL;
    float v[3]; float ss = 0.f;
    #pragma unroll
    for (int j = 0; j < 3; j++) {
        int d = threadIdx.x + j * 256;
        float x = hp[d];
        if (has_raw) {
            float g = affprev[b * AFF + 3840 + d];
            float rawv = raw[(size_t)row * D_MODEL + d] + raw[PSTR + (size_t)row * D_MODEL + d];
            x += g * (rawv + bias[d]);
        }
        x += rp[d];
        rp[d] = x; v[j] = x; ss += x * x;
    }
    ss = block_sum_256(ss, s4);
    float inv = rsqrtf(ss / (float)D_MODEL + 1e-5f);
    const float* sh = affcur + b * AFF;
    const float* sc = affcur + b * AFF + 768;
    #pragma unroll
    for (int j = 0; j < 3; j++) {
        int d = threadIdx.x + j * 256;
        float hn = v[j] * inv * normw[d];
        hidden_n[(size_t)row * D_MODEL + d] = hn;
        u[(size_t)row * D_MODEL + d] = f2b(hn * (1.f + sc[d]) + sh[d]);
    }
}

// ---------------- depthwise causal conv + silu, fused softplus(dt) ----------------
__global__ void k_convdt(const float* __restrict__ zx, const float* __restrict__ convw,
                         const float* __restrict__ convb, const float* __restrict__ dtbias,
                         float* __restrict__ xBC, float* __restrict__ dtb) {
    int i = blockIdx.x * 256 + threadIdx.x;
    if (i < ROWS * NHEADS) {
        int h = i % NHEADS; int row = i / NHEADS;
        float x = zx[(size_t)row * D_IN_PROJ + D_INNER + CONV_DIM + h] + dtbias[h];
        dtb[i] = (x > 20.f) ? x : log1pf(expf(x));
    }
    if (i >= ROWS * CONV_DIM) return;
    int c = i % CONV_DIM; int row = i / CONV_DIM;
    int l = row & 511; int b = row >> 9;
    float acc = convb[c];
    #pragma unroll
    for (int k = 0; k < 4; k++) {
        int t = l - 3 + k;
        if (t >= 0)
            acc += convw[c * 4 + k] * zx[(size_t)(b * SEQ + t) * D_IN_PROJ + D_INNER + c];
    }
    xBC[i] = siluf(acc);
}

// ---------------- SSM K1: chunk-parallel (grid = NCHUNK x B*H) ----------------
// Computes y_partial = G·X^T + D·x, chunk state S_c = Xw·B (bf16), and P_c.
__global__ __launch_bounds__(256)
void k_ssm_par(const float* __restrict__ xBC, const float* __restrict__ dtb,
               const float* __restrict__ Alog, const float* __restrict__ Dssm,
               float* __restrict__ y, unsigned short* __restrict__ Sbuf,
               float* __restrict__ Pbuf) {
    __shared__ unsigned short sB[64][136];    // [t][n]
    __shared__ unsigned short sC[64][136];    // [t][n]
    __shared__ unsigned short sXT[64][72];    // [p][t]
    __shared__ unsigned short sG[64][72];     // G[i][s]; reused as XwT [p][t]
    __shared__ unsigned short sBT[128][72];   // [n][t]
    __shared__ float sL[64], sDt[64];
    int c = blockIdx.x, bh = blockIdx.y;
    int h = bh % NHEADS, b = bh / NHEADS;
    int tid = threadIdx.x;
    int lane = tid & 63, wave = tid >> 6;
    int l15 = lane & 15, quad = lane >> 4;
    int r = tid >> 2, q4 = tid & 3;
    int base = b * SEQ + c * CT;
    float a_h = expf(Alog[h]);
    float Dh = Dssm[h];
    if (tid < 64) {
        float dt = dtb[(base + tid) * NHEADS + h];
        float v = -a_h * dt;
        #pragma unroll
        for (int off = 1; off < 64; off <<= 1) {
            float u2 = __shfl_up(v, off, 64);
            if (tid >= off) v += u2;
        }
        sL[tid] = v; sDt[tid] = dt;
    }
    const float* xrow = xBC + (size_t)(base + r) * CONV_DIM;
    #pragma unroll
    for (int j = 0; j < 8; j++) {
        float4 v = *(const float4*)&xrow[D_INNER + q4 * 32 + j * 4];
        int n0 = q4 * 32 + j * 4;
        ushort4 pk; pk.x = f2b(v.x); pk.y = f2b(v.y); pk.z = f2b(v.z); pk.w = f2b(v.w);
        *(ushort4*)&sB[r][n0] = pk;
        sBT[n0 + 0][r] = pk.x; sBT[n0 + 1][r] = pk.y;
        sBT[n0 + 2][r] = pk.z; sBT[n0 + 3][r] = pk.w;
        float4 w = *(const float4*)&xrow[D_INNER + D_STATE + q4 * 32 + j * 4];
        ushort4 pk2; pk2.x = f2b(w.x); pk2.y = f2b(w.y); pk2.z = f2b(w.z); pk2.w = f2b(w.w);
        *(ushort4*)&sC[r][n0] = pk2;
    }
    #pragma unroll
    for (int j = 0; j < 4; j++) {
        float4 v = *(const float4*)&xrow[h * HEADDIM + q4 * 16 + j * 4];
        int p0 = q4 * 16 + j * 4;
        sXT[p0 + 0][r] = f2b(v.x); sXT[p0 + 1][r] = f2b(v.y);
        sXT[p0 + 2][r] = f2b(v.z); sXT[p0 + 3][r] = f2b(v.w);
    }
    __syncthreads();
    if (tid == 0) Pbuf[bh * NCHUNK + c] = expf(sL[63]);

    // acc1 = C·B^T  (CB[t][s])
    f32x4 acc1[4];
    #pragma unroll
    for (int j = 0; j < 4; j++) acc1[j] = (f32x4){0.f, 0.f, 0.f, 0.f};
    #pragma unroll
    for (int k0 = 0; k0 < 4; k0++) {
        bf16x8 a = *(const bf16x8*)&sC[wave * 16 + l15][k0 * 32 + quad * 8];
        #pragma unroll
        for (int nt = 0; nt < 4; nt++) {
            bf16x8 bv = *(const bf16x8*)&sB[nt * 16 + l15][k0 * 32 + quad * 8];
            acc1[nt] = __builtin_amdgcn_mfma_f32_16x16x32_bf16(a, bv, acc1[nt], 0, 0, 0);
        }
    }
    // G[i][s] = causal mask * CB * exp(L_i - L_s) * dt_s
    #pragma unroll
    for (int nt = 0; nt < 4; nt++) {
        int s = nt * 16 + l15;
        float Ls = sL[s], dts = sDt[s];
        #pragma unroll
        for (int rr = 0; rr < 4; rr++) {
            int i = wave * 16 + quad * 4 + rr;
            float g = (s <= i) ? acc1[nt][rr] * expf(sL[i] - Ls) * dts : 0.f;
            sG[i][s] = f2b(g);
        }
    }
    __syncthreads();

    // acc2 = G·X^T ; y_partial write (+ D·x)
    f32x4 acc2[4];
    #pragma unroll
    for (int j = 0; j < 4; j++) acc2[j] = (f32x4){0.f, 0.f, 0.f, 0.f};
    #pragma unroll
    for (int k0 = 0; k0 < 2; k0++) {
        bf16x8 a = *(const bf16x8*)&sG[wave * 16 + l15][k0 * 32 + quad * 8];
        #pragma unroll
        for (int nt = 0; nt < 4; nt++) {
            bf16x8 bv = *(const bf16x8*)&sXT[nt * 16 + l15][k0 * 32 + quad * 8];
            acc2[nt] = __builtin_amdgcn_mfma_f32_16x16x32_bf16(a, bv, acc2[nt], 0, 0, 0);
        }
    }
    #pragma unroll
    for (int nt = 0; nt < 4; nt++) {
        int p = nt * 16 + l15;
        #pragma unroll
        for (int rr = 0; rr < 4; rr++) {
            int i = wave * 16 + quad * 4 + rr;
            float xv = b2f(sXT[p][i]);
            y[(size_t)(base + i) * D_INNER + h * HEADDIM + p] = acc2[nt][rr] + Dh * xv;
        }
    }
    __syncthreads();
    // XwT[p][t] = X[t][p] * exp(Lend - L_t) * dt_t  (reuse sG)
    {
        float wr2 = expf(sL[63] - sL[r]) * sDt[r];
        #pragma unroll
        for (int j = 0; j < 16; j++) {
            int pp = q4 * 16 + j;
            sG[pp][r] = f2b(b2f(sXT[pp][r]) * wr2);
        }
    }
    __syncthreads();
    // S[p][n] = Xw·B -> Sbuf bf16
    f32x4 accS[8];
    #pragma unroll
    for (int j = 0; j < 8; j++) accS[j] = (f32x4){0.f, 0.f, 0.f, 0.f};
    #pragma unroll
    for (int k0 = 0; k0 < 2; k0++) {
        bf16x8 a = *(const bf16x8*)&sG[wave * 16 + l15][k0 * 32 + quad * 8];
        #pragma unroll
        for (int nt = 0; nt < 8; nt++) {
            bf16x8 bv = *(const bf16x8*)&sBT[nt * 16 + l15][k0 * 32 + quad * 8];
            accS[nt] = __builtin_amdgcn_mfma_f32_16x16x32_bf16(a, bv, accS[nt], 0, 0, 0);
        }
    }
    unsigned short* sout = Sbuf + ((size_t)bh * NCHUNK + c) * 8192;
    #pragma unroll
    for (int nt = 0; nt < 8; nt++) {
        int n = nt * 16 + l15;
        #pragma unroll
        for (int rr = 0; rr < 4; rr++) {
            int p = wave * 16 + quad * 4 + rr;
            sout[p * 128 + n] = f2b(accS[nt][rr]);
        }
    }
}

// ---------------- SSM K2: h-contribution, chunk-parallel (grid = (NCHUNK-1) x B*H) ------
// h_start(c) = sum_{j<c} S_j * prod_{j<k<c} P_k  (f32 accumulate), then y += C~ . h^T.
__global__ __launch_bounds__(256)
void k_ssm_fix(const float* __restrict__ xBC, const float* __restrict__ dtb,
               const float* __restrict__ Alog, const unsigned short* __restrict__ Sbuf,
               const float* __restrict__ Pbuf, float* __restrict__ y) {
    __shared__ unsigned short sC[64][136];    // C~ = C * exp(L_t)
    __shared__ unsigned short sHB[64][136];   // h_start bf16 [p][n]
    __shared__ float sL[64];
    int c = blockIdx.x + 1, bh = blockIdx.y;
    int h = bh % NHEADS, b = bh / NHEADS;
    int tid = threadIdx.x;
    int lane = tid & 63, wave = tid >> 6;
    int l15 = lane & 15, quad = lane >> 4;
    int r = tid >> 2, q4 = tid & 3;
    int base = b * SEQ + c * CT;
    if (tid < 64) {
        float dt = dtb[(base + tid) * NHEADS + h];
        float v = -expf(Alog[h]) * dt;
        #pragma unroll
        for (int off = 1; off < 64; off <<= 1) {
            float u2 = __shfl_up(v, off, 64);
            if (tid >= off) v += u2;
        }
        sL[tid] = v;
    }
    // h_start: thread owns row p=r, cols [q4*32, q4*32+32)
    float hacc[32];
    #pragma unroll
    for (int e = 0; e < 32; e++) hacc[e] = 0.f;
    {
        const unsigned short* sp = Sbuf + (size_t)bh * NCHUNK * 8192 + r * 128 + q4 * 32;
        float w = 1.f;
        for (int j = c - 1; j >= 0; j--) {
            const unsigned short* srow = sp + (size_t)j * 8192;
            #pragma unroll
            for (int q = 0; q < 4; q++) {
                bf16x8 vv = *(const bf16x8*)&srow[q * 8];
                #pragma unroll
                for (int e = 0; e < 8; e++)
                    hacc[q * 8 + e] += w * b2f((unsigned short)vv[e]);
            }
            w *= Pbuf[bh * NCHUNK + j];
        }
    }
    __syncthreads();
    // write h to LDS bf16; stage C~ rows
    #pragma unroll
    for (int e = 0; e < 32; e++) sHB[r][q4 * 32 + e] = f2b(hacc[e]);
    {
        float el = expf(sL[r]);
        const float* xrow = xBC + (size_t)(base + r) * CONV_DIM + D_INNER + D_STATE;
        #pragma unroll
        for (int j = 0; j < 8; j++) {
            float4 v = *(const float4*)&xrow[q4 * 32 + j * 4];
            int n0 = q4 * 32 + j * 4;
            sC[r][n0 + 0] = f2b(v.x * el); sC[r][n0 + 1] = f2b(v.y * el);
            sC[r][n0 + 2] = f2b(v.z * el); sC[r][n0 + 3] = f2b(v.w * el);
        }
    }
    __syncthreads();
    // y[t][p] += sum_n C~[t][n] h[p][n]
    f32x4 acc[4];
    #pragma unroll
    for (int j = 0; j < 4; j++) acc[j] = (f32x4){0.f, 0.f, 0.f, 0.f};
    #pragma unroll
    for (int k0 = 0; k0 < 4; k0++) {
        bf16x8 a = *(const bf16x8*)&sC[wave * 16 + l15][k0 * 32 + quad * 8];
        #pragma unroll
        for (int nt = 0; nt < 4; nt++) {
            bf16x8 bv = *(const bf16x8*)&sHB[nt * 16 + l15][k0 * 32 + quad * 8];
            acc[nt] = __builtin_amdgcn_mfma_f32_16x16x32_bf16(a, bv, acc[nt], 0, 0, 0);
        }
    }
    #pragma unroll
    for (int nt = 0; nt < 4; nt++) {
        int p = nt * 16 + l15;
        #pragma unroll
        for (int rr = 0; rr < 4; rr++) {
            int i = wave * 16 + quad * 4 + rr;
            size_t idx = (size_t)(base + i) * D_INNER + h * HEADDIM + p;
            y[idx] += acc[nt][rr];
        }
    }
}

// ---------------- gated rmsnorm -> bf16 ----------------
__global__ void k_gatednorm(const float* __restrict__ yscan, const float* __restrict__ zx,
                            const float* __restrict__ nw, unsigned short* __restrict__ out) {
    __shared__ float s4[4];
    int row = blockIdx.x;
    const float* yp = yscan + (size_t)row * D_INNER;
    const float* zp = zx + (size_t)row * D_IN_PROJ;
    float v[6]; float ss = 0.f;
    #pragma unroll
    for (int j = 0; j < 6; j++) {
        int d = threadIdx.x + j * 256;
        float val = yp[d] * siluf(zp[d]);
        v[j] = val; ss += val * val;
    }
    ss = block_sum_256(ss, s4);
    float inv = rsqrtf(ss / (float)D_INNER + 1e-5f);
    #pragma unroll
    for (int j = 0; j < 6; j++) {
        int d = threadIdx.x + j * 256;
        out[(size_t)row * D_INNER + d] = f2b(v[j] * inv * nw[d]);
    }
}

// ---------------- hidden2 = hidden_n + g_mba*(Σ tmp partials + out_b); ln + msa mod ----
__global__ void k_fuse_ln(const float* __restrict__ hidden_n, const float* __restrict__ tmp,
                          const float* __restrict__ outb, const float* __restrict__ aff,
                          float* __restrict__ hidden2, unsigned short* __restrict__ attnx) {
    __shared__ float s4[4];
    const size_t PSTR = (size_t)ROWS * D_MODEL;
    int row = blockIdx.x;
    int b = row >> 9;
    const float* gm = aff + b * AFF + 1536;
    float v[3]; float s = 0.f;
    #pragma unroll
    for (int j = 0; j < 3; j++) {
        int d = threadIdx.x + j * 256;
        size_t idx = (size_t)row * D_MODEL + d;
        float t = tmp[idx] + tmp[idx + PSTR] + tmp[idx + 2 * PSTR] + tmp[idx + 3 * PSTR];
        float x = hidden_n[idx] + gm[d] * (t + outb[d]);
        hidden2[idx] = x;
        v[j] = x; s += x;
    }
    float mean = block_sum_256(s, s4) / (float)D_MODEL;
    float ss = 0.f;
    #pragma unroll
    for (int j = 0; j < 3; j++) { float c = v[j] - mean; ss += c * c; }
    float var = block_sum_256(ss, s4) / (float)D_MODEL;
    float inv = rsqrtf(var + 1e-6f);
    const float* sh = aff + b * AFF + 2304;
    const float* sc = aff + b * AFF + 3072;
    #pragma unroll
    for (int j = 0; j < 3; j++) {
        int d = threadIdx.x + j * 256;
        float xh = (v[j] - mean) * inv;
        attnx[(size_t)row * D_MODEL + d] = f2b(xh * (1.f + sc[d]) + sh[d]);
    }
}

// ---------------- cross-attention with fused Q-projection (MFMA) ----------------
__global__ __launch_bounds__(256)
void k_attn(const unsigned short* __restrict__ attnx, const unsigned short* __restrict__ qwt,
            const unsigned short* __restrict__ kb, const unsigned short* __restrict__ vb,
            unsigned short* __restrict__ ob) {
    int blk = blockIdx.x;
    int lt = blk & 15; int h = (blk >> 4) & 7; int b = blk >> 7;
    __shared__ unsigned short sK[64][66];
    __shared__ unsigned short sV[64][66];
    __shared__ unsigned short sA[32][136];
    __shared__ unsigned short sW[64][136];
    __shared__ float sQf[32][68];
    int tid = threadIdx.x;
    {
        int r = tid >> 2, c0 = (tid & 3) * 16;
        const unsigned short* kp = kb + (size_t)(b * LC + r) * AINNER + h * AD + c0;
        const unsigned short* vp = vb + (size_t)(b * LC + r) * AINNER + h * AD + c0;
        #pragma unroll
        for (int j = 0; j < 4; j++) {
            *(ushort4*)&sK[r][c0 + j * 4] = *(const ushort4*)&kp[j * 4];
            *(ushort4*)&sV[r][c0 + j * 4] = *(const ushort4*)&vp[j * 4];
        }
    }
    int lane = tid & 63, wave = tid >> 6;
    int l15 = lane & 15, quad = lane >> 4;
    int rt = wave >> 1, cp = (wave & 1) * 2;
    f32x4 accq[2];
    accq[0] = (f32x4){0.f, 0.f, 0.f, 0.f};
    accq[1] = (f32x4){0.f, 0.f, 0.f, 0.f};
    const size_t arow_base = (size_t)(b * SEQ + lt * 32) * D_MODEL;
    for (int k0 = 0; k0 < D_MODEL; k0 += 128) {
        __syncthreads();
        #pragma unroll
        for (int j = 0; j < 2; j++) {
            int s = tid + j * 256; int row = s >> 4, c8 = (s & 15) * 8;
            *(uint4*)&sA[row][c8] =
                *(const uint4*)&attnx[arow_base + (size_t)row * D_MODEL + k0 + c8];
        }
        #pragma unroll
        for (int j = 0; j < 4; j++) {
            int s = tid + j * 256; int row = s >> 4, c8 = (s & 15) * 8;
            *(uint4*)&sW[row][c8] =
                *(const uint4*)&qwt[(size_t)(h * AD + row) * D_MODEL + k0 + c8];
        }
        __syncthreads();
        #pragma unroll
        for (int ks = 0; ks < 4; ks++) {
            bf16x8 af = *(const bf16x8*)&sA[rt * 16 + l15][ks * 32 + quad * 8];
            #pragma unroll
            for (int j = 0; j < 2; j++) {
                bf16x8 bf = *(const bf16x8*)&sW[(cp + j) * 16 + l15][ks * 32 + quad * 8];
                accq[j] = __builtin_amdgcn_mfma_f32_16x16x32_bf16(af, bf, accq[j], 0, 0, 0);
            }
        }
    }
    #pragma unroll
    for (int j = 0; j < 2; j++)
        #pragma unroll
        for (int rr = 0; rr < 4; rr++)
            sQf[rt * 16 + quad * 4 + rr][(cp + j) * 16 + l15] = accq[j][rr] * 0.125f;
    __syncthreads();
    int m = lane;
    #pragma unroll
    for (int qq = 0; qq < 8; qq++) {
        int q = wave * 8 + qq;
        float s = 0.f;
        #pragma unroll 8
        for (int d = 0; d < AD; d++) s += sQf[q][d] * b2f(sK[m][d]);
        float mx = s;
        #pragma unroll
        for (int off = 32; off > 0; off >>= 1) mx = fmaxf(mx, __shfl_xor(mx, off, 64));
        float e = expf(s - mx);
        float sum = e;
        #pragma unroll
        for (int off = 32; off > 0; off >>= 1) sum += __shfl_xor(sum, off, 64);
        float a = e / sum;
        float acc = 0.f;
        #pragma unroll 8
        for (int mm = 0; mm < LC; mm++) {
            float am = __shfl(a, mm, 64);
            acc += am * b2f(sV[mm][m]);
        }
        ob[(size_t)(b * SEQ + lt * 32 + q) * AINNER + h * AD + m] = f2b(acc);
    }
}

// ---------------- final: h = hidden2 + g*(Σ raw partials + bias); rmsnorm(h + r) --------
__global__ void k_final(const float* __restrict__ hidden2, const float* __restrict__ raw,
                        const float* __restrict__ bias, const float* __restrict__ aff,
                        const float* __restrict__ residual, const float* __restrict__ w,
                        float* __restrict__ out) {
    __shared__ float s4[4];
    const size_t PSTR = (size_t)ROWS * D_MODEL;
    int row = blockIdx.x;
    int b = row >> 9;
    const float* gm = aff + b * AFF + 3840;
    float v[3]; float ss = 0.f;
    #pragma unroll
    for (int j = 0; j < 3; j++) {
        int d = threadIdx.x + j * 256;
        size_t idx = (size_t)row * D_MODEL + d;
        float rawv = raw[idx] + raw[idx + PSTR];
        float x = hidden2[idx] + gm[d] * (rawv + bias[d]) + residual[idx];
        v[j] = x; ss += x * x;
    }
    ss = block_sum_256(ss, s4);
    float inv = rsqrtf(ss / (float)D_MODEL + 1e-5f);
    #pragma unroll
    for (int j = 0; j < 3; j++) {
        int d = threadIdx.x + j * 256;
        out[(size_t)row * D_MODEL + d] = v[j] * inv * w[d];
    }
}

// ---------------- host launch ----------------
extern "C" void kernel_launch(void* const* d_in, const int* in_sizes, int n_in,
                              void* d_out, int out_size, void* d_ws, size_t ws_size,
                              hipStream_t stream) {
    const float* hidden_states = (const float*)d_in[0];
    const float* ref_emb  = (const float*)d_in[1];
    const float* norm_w   = (const float*)d_in[2];
    const float* ada_w    = (const float*)d_in[3];
    const float* ada_b    = (const float*)d_in[4];
    const float* in_w     = (const float*)d_in[5];
    const float* conv_w   = (const float*)d_in[6];
    const float* conv_b   = (const float*)d_in[7];
    const float* dt_bias  = (const float*)d_in[8];
    const float* A_log    = (const float*)d_in[9];
    const float* D_ssm    = (const float*)d_in[10];
    const float* ssm_nw   = (const float*)d_in[11];
    const float* out_w    = (const float*)d_in[12];
    const float* out_b    = (const float*)d_in[13];
    const float* q_w      = (const float*)d_in[14];
    const float* k_w      = (const float*)d_in[15];
    const float* v_w      = (const float*)d_in[16];
    const float* o_w      = (const float*)d_in[17];
    const float* o_b      = (const float*)d_in[18];
    const float* norm_f_w = (const float*)d_in[19];
    float* out = (float*)d_out;

    char* p = (char*)d_ws;
    auto alloc = [&](size_t bytes) -> char* {
        char* r = p; p += (bytes + 255) & ~(size_t)255; return r;
    };
    float* residual = (float*)alloc((size_t)ROWS * D_MODEL * 4);
    float* hidden2  = (float*)alloc((size_t)ROWS * D_MODEL * 4);
    float* hidden_n = (float*)alloc((size_t)ROWS * D_MODEL * 4);
    float* tmpM     = (float*)alloc((size_t)4 * ROWS * D_MODEL * 4);  // out-proj partials
    float* tmpO     = (float*)alloc((size_t)2 * ROWS * D_MODEL * 4);  // o-proj partials
    float* zx       = (float*)alloc((size_t)ROWS * D_IN_PROJ * 4);
    float* xBC      = (float*)alloc((size_t)ROWS * CONV_DIM * 4);
    float* dtb      = (float*)alloc((size_t)ROWS * NHEADS * 4);
    float* yscan    = (float*)alloc((size_t)ROWS * D_INNER * 4);
    float* aff_all  = (float*)alloc((size_t)N_LAYER * BSZ * AFF * 4);
    float* smc      = (float*)alloc((size_t)BSZ * D_MODEL * 4);
    float* Pbuf     = (float*)alloc((size_t)BSZ * NHEADS * NCHUNK * 4);
    unsigned short* Sbuf   = (unsigned short*)alloc((size_t)BSZ * NHEADS * NCHUNK * 8192 * 2);
    unsigned short* u_bf   = (unsigned short*)alloc((size_t)ROWS * D_MODEL * 2);
    unsigned short* ynorm  = (unsigned short*)alloc((size_t)ROWS * D_INNER * 2);
    unsigned short* attnx  = (unsigned short*)alloc((size_t)ROWS * D_MODEL * 2);
    unsigned short* ob     = (unsigned short*)alloc((size_t)ROWS * AINNER * 2);
    unsigned short* ref_bf = (unsigned short*)alloc((size_t)BSZ * LC * D_MODEL * 2);
    unsigned short* kb_all  = (unsigned short*)alloc((size_t)N_LAYER * BSZ * LC * AINNER * 2);
    unsigned short* vb_all  = (unsigned short*)alloc((size_t)N_LAYER * BSZ * LC * AINNER * 2);
    unsigned short* in_wt_all  = (unsigned short*)alloc((size_t)N_LAYER * NP1 * D_MODEL * 2);
    unsigned short* out_wt_all = (unsigned short*)alloc((size_t)N_LAYER * D_MODEL * D_INNER * 2);
    unsigned short* q_wt_all   = (unsigned short*)alloc((size_t)N_LAYER * AINNER * D_MODEL * 2);
    unsigned short* o_wt_all   = (unsigned short*)alloc((size_t)N_LAYER * D_MODEL * AINNER * 2);
    unsigned short* kwt_all = (unsigned short*)alloc((size_t)N_LAYER * AINNER * D_MODEL * 2);
    unsigned short* vwt_all = (unsigned short*)alloc((size_t)N_LAYER * AINNER * D_MODEL * 2);

    hipMemsetAsync(residual, 0, (size_t)ROWS * D_MODEL * sizeof(float), stream);
    k_pre<<<678, 256, 0, stream>>>(ref_emb, ref_bf, smc, ada_b, aff_all);
    k_ada_split<<<dim3(AFF / 256, 8, N_LAYER), 256, 0, stream>>>(smc, ada_w, aff_all);

    // weight transposes (batched over layers; q/k/v share one launch)
    k_transpose_pb<<<dim3(NP1 / 32, D_MODEL / 32, N_LAYER), 256, 0, stream>>>(in_w, in_wt_all, D_MODEL, D_IN_PROJ, NP1);
    k_transpose_pb<<<dim3(D_MODEL / 32, D_INNER / 32, N_LAYER), 256, 0, stream>>>(out_w, out_wt_all, D_INNER, D_MODEL, D_MODEL);
    k_transpose_qkv<<<dim3(AINNER / 32, D_MODEL / 32, 3 * N_LAYER), 256, 0, stream>>>(q_w, k_w, v_w, q_wt_all, kwt_all, vwt_all);
    k_transpose_pb<<<dim3(D_MODEL / 32, AINNER / 32, N_LAYER), 256, 0, stream>>>(o_w, o_wt_all, AINNER, D_MODEL, D_MODEL);
    k_gemm_kv<<<dim3(AINNER / 128, 1, N_LAYER * 2), 256, 0, stream>>>(ref_bf, kwt_all, vwt_all, kb_all, vb_all);

    for (int layer = 0; layer < N_LAYER; layer++) {
        const float* L_norm_w  = norm_w  + layer * D_MODEL;
        const float* L_conv_w  = conv_w  + layer * CONV_DIM * 4;
        const float* L_conv_b  = conv_b  + layer * CONV_DIM;
        const float* L_dt_bias = dt_bias + layer * NHEADS;
        const float* L_A_log   = A_log   + layer * NHEADS;
        const float* L_D_ssm   = D_ssm   + layer * NHEADS;
        const float* L_ssm_nw  = ssm_nw  + layer * D_INNER;
        const float* L_out_b   = out_b   + layer * D_MODEL;
        const float* L_o_b_prev= o_b     + (layer - 1) * D_MODEL;
        const float* L_aff     = aff_all + (size_t)layer * BSZ * AFF;
        const float* L_aff_prev= aff_all + (size_t)(layer - 1) * BSZ * AFF;
        const unsigned short* in_wt  = in_wt_all  + (size_t)layer * NP1 * D_MODEL;
        const unsigned short* out_wt = out_wt_all + (size_t)layer * D_MODEL * D_INNER;
        const unsigned short* q_wt   = q_wt_all   + (size_t)layer * AINNER * D_MODEL;
        const unsigned short* o_wt   = o_wt_all   + (size_t)layer * D_MODEL * AINNER;

        k_addrmsmod<<<ROWS, 256, 0, stream>>>(
            layer == 0 ? hidden_states : hidden2, tmpO,
            layer == 0 ? o_b : L_o_b_prev,
            layer == 0 ? aff_all : L_aff_prev,
            residual, L_norm_w, L_aff, hidden_n, u_bf, layer == 0 ? 0 : 1);
        k_gemm<<<dim3(NP1 / 128, ROWS / 128), 256, 0, stream>>>(u_bf, in_wt, zx, ROWS, D_IN_PROJ, D_MODEL);
        k_convdt<<<(ROWS * CONV_DIM + 255) / 256, 256, 0, stream>>>(zx, L_conv_w, L_conv_b, L_dt_bias, xBC, dtb);
        k_ssm_par<<<dim3(NCHUNK, BSZ * NHEADS), 256, 0, stream>>>(xBC, dtb, L_A_log, L_D_ssm, yscan, Sbuf, Pbuf);
        k_ssm_fix<<<dim3(NCHUNK - 1, BSZ * NHEADS), 256, 0, stream>>>(xBC, dtb, L_A_log, Sbuf, Pbuf, yscan);
        k_gatednorm<<<ROWS, 256, 0, stream>>>(yscan, zx, L_ssm_nw, ynorm);
        k_gemm_sk<<<dim3(D_MODEL / 128, ROWS / 128, 4), 256, 0, stream>>>(ynorm, out_wt, tmpM, ROWS, D_MODEL, D_INNER, 384);
        k_fuse_ln<<<ROWS, 256, 0, stream>>>(hidden_n, tmpM, L_out_b, L_aff, hidden2, attnx);
        k_attn<<<BSZ * AH * 16, 256, 0, stream>>>(
            attnx, q_wt,
            kb_all + (size_t)layer * BSZ * LC * AINNER,
            vb_all + (size_t)layer * BSZ * LC * AINNER, ob);
        k_gemm_sk<<<dim3(D_MODEL / 128, ROWS / 128, 2), 256, 0, stream>>>(ob, o_wt, tmpO, ROWS, D_MODEL, AINNER, 256);
    }
    k_final<<<ROWS, 256, 0, stream>>>(hidden2, tmpO, o_b + (N_LAYER - 1) * D_MODEL,
                                      aff_all + (size_t)(N_LAYER - 1) * BSZ * AFF,
                                      residual, norm_f_w, out);
}

// Round 3
// 1139.018 us; speedup vs baseline: 1.5543x; 1.2021x over previous
//
#include <hip/hip_runtime.h>
#include <hip/hip_bf16.h>
#include <math.h>

// ---------------- constants ----------------
#define D_MODEL   768
#define N_LAYER   8
#define D_INNER   1536
#define D_STATE   128
#define HEADDIM   64
#define NHEADS    24
#define CONV_DIM  1792
#define D_IN_PROJ 3352
#define AH        8
#define AD        64
#define AINNER    512
#define BSZ       2
#define SEQ       512
#define LC        64
#define ROWS      (BSZ*SEQ)          // 1024
#define NCHUNK    8
#define CT        64                 // chunk length
#define NP1       3456               // 3352 padded to 27*128
#define AFF       4608

typedef __attribute__((ext_vector_type(8))) short bf16x8;
typedef __attribute__((ext_vector_type(4))) float f32x4;

__device__ __forceinline__ float siluf(float x) { return x / (1.f + expf(-x)); }

__device__ __forceinline__ unsigned short f2b(float x) {
    __hip_bfloat16 h = __float2bfloat16(x);
    return __builtin_bit_cast(unsigned short, h);
}
__device__ __forceinline__ float b2f(unsigned short u) {
    unsigned v = ((unsigned)u) << 16;
    return __builtin_bit_cast(float, v);
}

// async global->LDS 16B copy (wave-uniform base + lane*16 contiguity honored by callers)
__device__ __forceinline__ void gload16(const void* g, void* l) {
    __builtin_amdgcn_global_load_lds(
        (const __attribute__((address_space(1))) unsigned int*)g,
        (__attribute__((address_space(3))) unsigned int*)l,
        16, 0, 0);
}

// block-wide sum, 256 threads (4 waves)
__device__ __forceinline__ float block_sum_256(float v, float* s4) {
    #pragma unroll
    for (int o = 32; o > 0; o >>= 1) v += __shfl_down(v, o, 64);
    __syncthreads();
    if ((threadIdx.x & 63) == 0) s4[threadIdx.x >> 6] = v;
    __syncthreads();
    return s4[0] + s4[1] + s4[2] + s4[3];
}

// ---------------- fused preamble: f2b + silumean + ada init + ALL weight transposes ----
// segments (1-D grid): [0,384) ref f2b; [384,390) silumean; [390,678) ada init;
// [678,21414) in_w T; [21414,30630) out_w T; [30630,39846) q/k/v T; [39846,42918) o_w T.
__global__ void k_prep(const float* __restrict__ ref_emb, unsigned short* __restrict__ ref_bf,
                       float* __restrict__ smc, const float* __restrict__ adab,
                       float* __restrict__ aff_all,
                       const float* __restrict__ in_w, const float* __restrict__ out_w,
                       const float* __restrict__ qw, const float* __restrict__ kw,
                       const float* __restrict__ vw, const float* __restrict__ ow,
                       unsigned short* __restrict__ in_wt, unsigned short* __restrict__ out_wt,
                       unsigned short* __restrict__ qwt, unsigned short* __restrict__ kwt,
                       unsigned short* __restrict__ vwt, unsigned short* __restrict__ owt) {
    int blk = blockIdx.x, t = threadIdx.x;
    if (blk < 384) {
        int i = blk * 256 + t;
        ref_bf[i] = f2b(ref_emb[i]);
        return;
    }
    if (blk < 390) {
        int i = (blk - 384) * 256 + t;
        if (i < BSZ * D_MODEL) {
            int b = i / D_MODEL, d = i % D_MODEL;
            const float* p = ref_emb + (size_t)b * LC * D_MODEL + d;
            float s = 0.f;
            #pragma unroll 4
            for (int l = 0; l < LC; l++) s += p[l * D_MODEL];
            smc[i] = siluf(s * (1.f / (float)LC));
        }
        return;
    }
    if (blk < 678) {
        int i = (blk - 390) * 256 + t;
        int j = i % AFF; int l = (i / AFF) >> 1;
        aff_all[i] = adab[l * AFF + j];
        return;
    }
    const float* src; unsigned short* dst; int K, N, n0, k0;
    if (blk < 21414) {                       // in_w: K=768, N=3352 (pad 3456)
        int u = blk - 678; int z = u / 2592; int rem = u % 2592;
        k0 = (rem / 108) * 32; n0 = (rem % 108) * 32;
        src = in_w + (size_t)z * 768 * 3352; dst = in_wt + (size_t)z * 3456 * 768;
        K = 768; N = 3352;
    } else if (blk < 30630) {                // out_w: K=1536, N=768
        int u = blk - 21414; int z = u / 1152; int rem = u % 1152;
        k0 = (rem / 24) * 32; n0 = (rem % 24) * 32;
        src = out_w + (size_t)z * 1536 * 768; dst = out_wt + (size_t)z * 768 * 1536;
        K = 1536; N = 768;
    } else if (blk < 39846) {                // q/k/v: K=768, N=512
        int u = blk - 30630; int z = u / 384; int rem = u % 384;
        k0 = (rem / 16) * 32; n0 = (rem % 16) * 32;
        int which = z >> 3, layer = z & 7;
        src = (which == 0 ? qw : which == 1 ? kw : vw) + (size_t)layer * 768 * 512;
        dst = (which == 0 ? qwt : which == 1 ? kwt : vwt) + (size_t)layer * 512 * 768;
        K = 768; N = 512;
    } else {                                 // o_w: K=512, N=768
        int u = blk - 39846; int z = u / 384; int rem = u % 384;
        k0 = (rem / 24) * 32; n0 = (rem % 24) * 32;
        src = ow + (size_t)z * 512 * 768; dst = owt + (size_t)z * 768 * 512;
        K = 512; N = 768;
    }
    __shared__ float tile[32][33];
    int nl = t & 31, kl = t >> 5;
    #pragma unroll
    for (int p = 0; p < 4; p++) {
        int k = kl + p * 8;
        int n = n0 + nl;
        tile[k][nl] = (n < N) ? src[(size_t)(k0 + k) * N + n] : 0.f;
    }
    __syncthreads();
    int kl2 = t & 31, nl2 = t >> 5;
    #pragma unroll
    for (int p = 0; p < 4; p++) {
        int n = nl2 + p * 8;
        dst[(size_t)(n0 + n) * K + k0 + kl2] = f2b(tile[kl2][n]);
    }
}

// ---------------- merged K/V projection GEMM + ada split-K ----------------
// grid (18,1,80): z<16 -> kv gemm (x<4); z>=16 -> ada (l=(z-16)>>3, kc=(z-16)&7)
__global__ __launch_bounds__(256)
void k_kvada(const unsigned short* __restrict__ A, const unsigned short* __restrict__ Kwt,
             const unsigned short* __restrict__ Vwt, unsigned short* __restrict__ Kb,
             unsigned short* __restrict__ Vb,
             const float* __restrict__ smc, const float* __restrict__ adaw,
             float* __restrict__ aff_all) {
    int z = blockIdx.z;
    if (z >= 16) {
        int zz = z - 16; int l = zz >> 3, kc = zz & 7;
        int j = blockIdx.x * 256 + threadIdx.x;
        const float* w = adaw + (size_t)l * D_MODEL * AFF + j;
        const float* x0 = smc;
        const float* x1 = smc + D_MODEL;
        float s0 = 0.f, s1 = 0.f;
        int d0 = kc * 96;
        #pragma unroll 8
        for (int d = d0; d < d0 + 96; d++) {
            float wv = w[(size_t)d * AFF];
            s0 += x0[d] * wv; s1 += x1[d] * wv;
        }
        atomicAdd(&aff_all[(size_t)l * BSZ * AFF + j], s0);
        atomicAdd(&aff_all[(size_t)l * BSZ * AFF + AFF + j], s1);
        return;
    }
    if (blockIdx.x >= 4) return;
    int layer = z >> 1; int which = z & 1;
    const unsigned short* Bt = (which ? Vwt : Kwt) + (size_t)layer * AINNER * D_MODEL;
    unsigned short* C = (which ? Vb : Kb) + (size_t)layer * (BSZ * LC) * AINNER;
    __shared__ __align__(16) unsigned short As[128][32];
    __shared__ __align__(16) unsigned short Bs[128][32];
    int n0 = blockIdx.x * 128;
    int tid = threadIdx.x;
    int lane = tid & 63, wave = tid >> 6;
    int wm = (wave >> 1) * 64, wn = (wave & 1) * 64;
    int l15 = lane & 15, quad = lane >> 4;
    f32x4 acc[4][4];
    #pragma unroll
    for (int i = 0; i < 4; i++)
        #pragma unroll
        for (int j = 0; j < 4; j++) acc[i][j] = (f32x4){0.f, 0.f, 0.f, 0.f};
    int srow = tid >> 2, schunk = (tid & 3) * 8;
    for (int k0 = 0; k0 < D_MODEL; k0 += 32) {
        #pragma unroll
        for (int ps = 0; ps < 2; ps++) {
            int r = srow + ps * 64;
            gload16(&A[(size_t)r * D_MODEL + k0 + schunk], &As[r][schunk]);
            gload16(&Bt[(size_t)(n0 + r) * D_MODEL + k0 + schunk], &Bs[r][schunk]);
        }
        __syncthreads();
        bf16x8 af[4], bfr[4];
        #pragma unroll
        for (int i = 0; i < 4; i++) af[i]  = *(const bf16x8*)&As[wm + i * 16 + l15][quad * 8];
        #pragma unroll
        for (int j = 0; j < 4; j++) bfr[j] = *(const bf16x8*)&Bs[wn + j * 16 + l15][quad * 8];
        #pragma unroll
        for (int i = 0; i < 4; i++)
            #pragma unroll
            for (int j = 0; j < 4; j++)
                acc[i][j] = __builtin_amdgcn_mfma_f32_16x16x32_bf16(af[i], bfr[j], acc[i][j], 0, 0, 0);
        __syncthreads();
    }
    #pragma unroll
    for (int i = 0; i < 4; i++) {
        #pragma unroll
        for (int j = 0; j < 4; j++) {
            int col = n0 + wn + j * 16 + l15;
            #pragma unroll
            for (int r = 0; r < 4; r++) {
                int row = wm + i * 16 + quad * 4 + r;
                C[(size_t)row * AINNER + col] = f2b(acc[i][j][r]);
            }
        }
    }
}

// ---------------- split-K GEMM: grid.z slices of width Kc; partial -> C + z*M*N ----------
__global__ __launch_bounds__(256)
void k_gemm_sk(const unsigned short* __restrict__ A, const unsigned short* __restrict__ Bt,
               float* __restrict__ C, int M, int N, int K, int Kc) {
    int z = blockIdx.z;
    C += (size_t)z * M * N;
    int kbeg = z * Kc;
    int kend = kbeg + Kc; if (kend > K) kend = K;
    __shared__ __align__(16) unsigned short As[128][32];
    __shared__ __align__(16) unsigned short Bs[128][32];
    int m0 = blockIdx.y * 128, n0 = blockIdx.x * 128;
    int tid = threadIdx.x;
    int lane = tid & 63, wave = tid >> 6;
    int wm = (wave >> 1) * 64, wn = (wave & 1) * 64;
    int l15 = lane & 15, quad = lane >> 4;
    f32x4 acc[4][4];
    #pragma unroll
    for (int i = 0; i < 4; i++)
        #pragma unroll
        for (int j = 0; j < 4; j++) acc[i][j] = (f32x4){0.f, 0.f, 0.f, 0.f};

    int srow = tid >> 2;
    int schunk = (tid & 3) * 8;

    for (int k0 = kbeg; k0 < kend; k0 += 32) {
        #pragma unroll
        for (int ps = 0; ps < 2; ps++) {
            int r = srow + ps * 64;
            gload16(&A[(size_t)(m0 + r) * K + k0 + schunk], &As[r][schunk]);
            gload16(&Bt[(size_t)(n0 + r) * K + k0 + schunk], &Bs[r][schunk]);
        }
        __syncthreads();
        bf16x8 af[4], bfr[4];
        #pragma unroll
        for (int i = 0; i < 4; i++) af[i]  = *(const bf16x8*)&As[wm + i * 16 + l15][quad * 8];
        #pragma unroll
        for (int j = 0; j < 4; j++) bfr[j] = *(const bf16x8*)&Bs[wn + j * 16 + l15][quad * 8];
        #pragma unroll
        for (int i = 0; i < 4; i++)
            #pragma unroll
            for (int j = 0; j < 4; j++)
                acc[i][j] = __builtin_amdgcn_mfma_f32_16x16x32_bf16(af[i], bfr[j], acc[i][j], 0, 0, 0);
        __syncthreads();
    }
    #pragma unroll
    for (int i = 0; i < 4; i++) {
        #pragma unroll
        for (int j = 0; j < 4; j++) {
            int col = n0 + wn + j * 16 + l15;
            if (col < N) {
                #pragma unroll
                for (int r = 0; r < 4; r++) {
                    int row = m0 + wm + i * 16 + quad * 4 + r;
                    C[(size_t)row * N + col] = acc[i][j][r];
                }
            }
        }
    }
}

// ---------------- [fused prev-attn out (2 split-K partials)] + residual + rmsnorm + mod ----
__global__ void k_addrmsmod(const float* __restrict__ hin, const float* __restrict__ raw,
                            const float* __restrict__ bias, const float* __restrict__ affprev,
                            float* __restrict__ residual, const float* __restrict__ normw,
                            const float* __restrict__ affcur,
                            float* __restrict__ hidden_n, unsigned short* __restrict__ u,
                            int has_raw) {
    __shared__ float s4[4];
    const size_t PSTR = (size_t)ROWS * D_MODEL;
    int row = blockIdx.x;
    int b = row >> 9;
    const float* hp = hin + (size_t)row * D_MODEL;
    float* rp = residual + (size_t)row * D_MODEL;
    float v[3]; float ss = 0.f;
    #pragma unroll
    for (int j = 0; j < 3; j++) {
        int d = threadIdx.x + j * 256;
        float x = hp[d];
        if (has_raw) {
            float g = affprev[b * AFF + 3840 + d];
            float rawv = raw[(size_t)row * D_MODEL + d] + raw[PSTR + (size_t)row * D_MODEL + d];
            x += g * (rawv + bias[d]) + rp[d];
        }
        rp[d] = x; v[j] = x; ss += x * x;
    }
    ss = block_sum_256(ss, s4);
    float inv = rsqrtf(ss / (float)D_MODEL + 1e-5f);
    const float* sh = affcur + b * AFF;
    const float* sc = affcur + b * AFF + 768;
    #pragma unroll
    for (int j = 0; j < 3; j++) {
        int d = threadIdx.x + j * 256;
        float hn = v[j] * inv * normw[d];
        hidden_n[(size_t)row * D_MODEL + d] = hn;
        u[(size_t)row * D_MODEL + d] = f2b(hn * (1.f + sc[d]) + sh[d]);
    }
}

// ---------------- depthwise causal conv + silu (zx 2 partials) -> bf16; softplus(dt) ----
__global__ void k_convdt(const float* __restrict__ zx, const float* __restrict__ convw,
                         const float* __restrict__ convb, const float* __restrict__ dtbias,
                         unsigned short* __restrict__ xBC, float* __restrict__ dtb) {
    const size_t PSTRZ = (size_t)ROWS * D_IN_PROJ;
    int i = blockIdx.x * 256 + threadIdx.x;
    if (i < ROWS * NHEADS) {
        int h = i % NHEADS; int row = i / NHEADS;
        size_t off = (size_t)row * D_IN_PROJ + D_INNER + CONV_DIM + h;
        float x = zx[off] + zx[off + PSTRZ] + dtbias[h];
        dtb[i] = (x > 20.f) ? x : log1pf(expf(x));
    }
    if (i >= ROWS * CONV_DIM) return;
    int c = i % CONV_DIM; int row = i / CONV_DIM;
    int l = row & 511; int b = row >> 9;
    float acc = convb[c];
    #pragma unroll
    for (int k = 0; k < 4; k++) {
        int t = l - 3 + k;
        if (t >= 0) {
            size_t idx = (size_t)(b * SEQ + t) * D_IN_PROJ + D_INNER + c;
            acc += convw[c * 4 + k] * (zx[idx] + zx[idx + PSTRZ]);
        }
    }
    xBC[i] = f2b(siluf(acc));
}

// ---------------- SSM K1: chunk-parallel (grid = NCHUNK x B*H), xBC bf16 ----------------
__global__ __launch_bounds__(256)
void k_ssm_par(const unsigned short* __restrict__ xBC, const float* __restrict__ dtb,
               const float* __restrict__ Alog, const float* __restrict__ Dssm,
               float* __restrict__ y, unsigned short* __restrict__ Sbuf,
               float* __restrict__ Pbuf) {
    __shared__ unsigned short sB[64][136];    // [t][n]
    __shared__ unsigned short sC[64][136];    // [t][n]
    __shared__ unsigned short sXT[64][72];    // [p][t]
    __shared__ unsigned short sG[64][72];     // G[i][s]; reused as XwT [p][t]
    __shared__ unsigned short sBT[128][72];   // [n][t]
    __shared__ float sL[64], sDt[64];
    int c = blockIdx.x, bh = blockIdx.y;
    int h = bh % NHEADS, b = bh / NHEADS;
    int tid = threadIdx.x;
    int lane = tid & 63, wave = tid >> 6;
    int l15 = lane & 15, quad = lane >> 4;
    int r = tid >> 2, q4 = tid & 3;
    int base = b * SEQ + c * CT;
    float a_h = expf(Alog[h]);
    float Dh = Dssm[h];
    if (tid < 64) {
        float dt = dtb[(base + tid) * NHEADS + h];
        float v = -a_h * dt;
        #pragma unroll
        for (int off = 1; off < 64; off <<= 1) {
            float u2 = __shfl_up(v, off, 64);
            if (tid >= off) v += u2;
        }
        sL[tid] = v; sDt[tid] = dt;
    }
    const unsigned short* xrow = xBC + (size_t)(base + r) * CONV_DIM;
    #pragma unroll
    for (int j = 0; j < 4; j++) {
        int n0 = q4 * 32 + j * 8;
        uint4 v = *(const uint4*)&xrow[D_INNER + n0];
        *(uint4*)&sB[r][n0] = v;
        const unsigned short* hv = (const unsigned short*)&v;
        #pragma unroll
        for (int e = 0; e < 8; e++) sBT[n0 + e][r] = hv[e];
        uint4 w = *(const uint4*)&xrow[D_INNER + D_STATE + n0];
        *(uint4*)&sC[r][n0] = w;
    }
    #pragma unroll
    for (int j = 0; j < 2; j++) {
        int p0 = q4 * 16 + j * 8;
        uint4 v = *(const uint4*)&xrow[h * HEADDIM + p0];
        const unsigned short* hv = (const unsigned short*)&v;
        #pragma unroll
        for (int e = 0; e < 8; e++) sXT[p0 + e][r] = hv[e];
    }
    __syncthreads();
    if (tid == 0) Pbuf[bh * NCHUNK + c] = expf(sL[63]);

    // acc1 = C·B^T  (CB[t][s])
    f32x4 acc1[4];
    #pragma unroll
    for (int j = 0; j < 4; j++) acc1[j] = (f32x4){0.f, 0.f, 0.f, 0.f};
    #pragma unroll
    for (int k0 = 0; k0 < 4; k0++) {
        bf16x8 a = *(const bf16x8*)&sC[wave * 16 + l15][k0 * 32 + quad * 8];
        #pragma unroll
        for (int nt = 0; nt < 4; nt++) {
            bf16x8 bv = *(const bf16x8*)&sB[nt * 16 + l15][k0 * 32 + quad * 8];
            acc1[nt] = __builtin_amdgcn_mfma_f32_16x16x32_bf16(a, bv, acc1[nt], 0, 0, 0);
        }
    }
    // G[i][s] = causal mask * CB * exp(L_i - L_s) * dt_s
    #pragma unroll
    for (int nt = 0; nt < 4; nt++) {
        int s = nt * 16 + l15;
        float Ls = sL[s], dts = sDt[s];
        #pragma unroll
        for (int rr = 0; rr < 4; rr++) {
            int i = wave * 16 + quad * 4 + rr;
            float g = (s <= i) ? acc1[nt][rr] * expf(sL[i] - Ls) * dts : 0.f;
            sG[i][s] = f2b(g);
        }
    }
    __syncthreads();

    // acc2 = G·X^T ; y_partial write (+ D·x)
    f32x4 acc2[4];
    #pragma unroll
    for (int j = 0; j < 4; j++) acc2[j] = (f32x4){0.f, 0.f, 0.f, 0.f};
    #pragma unroll
    for (int k0 = 0; k0 < 2; k0++) {
        bf16x8 a = *(const bf16x8*)&sG[wave * 16 + l15][k0 * 32 + quad * 8];
        #pragma unroll
        for (int nt = 0; nt < 4; nt++) {
            bf16x8 bv = *(const bf16x8*)&sXT[nt * 16 + l15][k0 * 32 + quad * 8];
            acc2[nt] = __builtin_amdgcn_mfma_f32_16x16x32_bf16(a, bv, acc2[nt], 0, 0, 0);
        }
    }
    #pragma unroll
    for (int nt = 0; nt < 4; nt++) {
        int p = nt * 16 + l15;
        #pragma unroll
        for (int rr = 0; rr < 4; rr++) {
            int i = wave * 16 + quad * 4 + rr;
            float xv = b2f(sXT[p][i]);
            y[(size_t)(base + i) * D_INNER + h * HEADDIM + p] = acc2[nt][rr] + Dh * xv;
        }
    }
    __syncthreads();
    // XwT[p][t] = X[t][p] * exp(Lend - L_t) * dt_t  (reuse sG)
    {
        float wr2 = expf(sL[63] - sL[r]) * sDt[r];
        #pragma unroll
        for (int j = 0; j < 16; j++) {
            int pp = q4 * 16 + j;
            sG[pp][r] = f2b(b2f(sXT[pp][r]) * wr2);
        }
    }
    __syncthreads();
    // S[p][n] = Xw·B -> Sbuf bf16
    f32x4 accS[8];
    #pragma unroll
    for (int j = 0; j < 8; j++) accS[j] = (f32x4){0.f, 0.f, 0.f, 0.f};
    #pragma unroll
    for (int k0 = 0; k0 < 2; k0++) {
        bf16x8 a = *(const bf16x8*)&sG[wave * 16 + l15][k0 * 32 + quad * 8];
        #pragma unroll
        for (int nt = 0; nt < 8; nt++) {
            bf16x8 bv = *(const bf16x8*)&sBT[nt * 16 + l15][k0 * 32 + quad * 8];
            accS[nt] = __builtin_amdgcn_mfma_f32_16x16x32_bf16(a, bv, accS[nt], 0, 0, 0);
        }
    }
    unsigned short* sout = Sbuf + ((size_t)bh * NCHUNK + c) * 8192;
    #pragma unroll
    for (int nt = 0; nt < 8; nt++) {
        int n = nt * 16 + l15;
        #pragma unroll
        for (int rr = 0; rr < 4; rr++) {
            int p = wave * 16 + quad * 4 + rr;
            sout[p * 128 + n] = f2b(accS[nt][rr]);
        }
    }
}

// ---------------- SSM K2: h-contribution, chunk-parallel (grid = (NCHUNK-1) x B*H) ------
__global__ __launch_bounds__(256)
void k_ssm_fix(const unsigned short* __restrict__ xBC, const float* __restrict__ dtb,
               const float* __restrict__ Alog, const unsigned short* __restrict__ Sbuf,
               const float* __restrict__ Pbuf, float* __restrict__ y) {
    __shared__ unsigned short sC[64][136];    // C~ = C * exp(L_t)
    __shared__ unsigned short sHB[64][136];   // h_start bf16 [p][n]
    __shared__ float sL[64];
    int c = blockIdx.x + 1, bh = blockIdx.y;
    int h = bh % NHEADS, b = bh / NHEADS;
    int tid = threadIdx.x;
    int lane = tid & 63, wave = tid >> 6;
    int l15 = lane & 15, quad = lane >> 4;
    int r = tid >> 2, q4 = tid & 3;
    int base = b * SEQ + c * CT;
    if (tid < 64) {
        float dt = dtb[(base + tid) * NHEADS + h];
        float v = -expf(Alog[h]) * dt;
        #pragma unroll
        for (int off = 1; off < 64; off <<= 1) {
            float u2 = __shfl_up(v, off, 64);
            if (tid >= off) v += u2;
        }
        sL[tid] = v;
    }
    // h_start: thread owns row p=r, cols [q4*32, q4*32+32)
    float hacc[32];
    #pragma unroll
    for (int e = 0; e < 32; e++) hacc[e] = 0.f;
    {
        const unsigned short* sp = Sbuf + (size_t)bh * NCHUNK * 8192 + r * 128 + q4 * 32;
        float w = 1.f;
        for (int j = c - 1; j >= 0; j--) {
            const unsigned short* srow = sp + (size_t)j * 8192;
            #pragma unroll
            for (int q = 0; q < 4; q++) {
                bf16x8 vv = *(const bf16x8*)&srow[q * 8];
                #pragma unroll
                for (int e = 0; e < 8; e++)
                    hacc[q * 8 + e] += w * b2f((unsigned short)vv[e]);
            }
            w *= Pbuf[bh * NCHUNK + j];
        }
    }
    __syncthreads();
    #pragma unroll
    for (int e = 0; e < 32; e++) sHB[r][q4 * 32 + e] = f2b(hacc[e]);
    {
        float el = expf(sL[r]);
        const unsigned short* xrow = xBC + (size_t)(base + r) * CONV_DIM + D_INNER + D_STATE;
        #pragma unroll
        for (int j = 0; j < 4; j++) {
            int n0 = q4 * 32 + j * 8;
            uint4 v = *(const uint4*)&xrow[n0];
            const unsigned short* hv = (const unsigned short*)&v;
            #pragma unroll
            for (int e = 0; e < 8; e++) sC[r][n0 + e] = f2b(b2f(hv[e]) * el);
        }
    }
    __syncthreads();
    // y[t][p] += sum_n C~[t][n] h[p][n]
    f32x4 acc[4];
    #pragma unroll
    for (int j = 0; j < 4; j++) acc[j] = (f32x4){0.f, 0.f, 0.f, 0.f};
    #pragma unroll
    for (int k0 = 0; k0 < 4; k0++) {
        bf16x8 a = *(const bf16x8*)&sC[wave * 16 + l15][k0 * 32 + quad * 8];
        #pragma unroll
        for (int nt = 0; nt < 4; nt++) {
            bf16x8 bv = *(const bf16x8*)&sHB[nt * 16 + l15][k0 * 32 + quad * 8];
            acc[nt] = __builtin_amdgcn_mfma_f32_16x16x32_bf16(a, bv, acc[nt], 0, 0, 0);
        }
    }
    #pragma unroll
    for (int nt = 0; nt < 4; nt++) {
        int p = nt * 16 + l15;
        #pragma unroll
        for (int rr = 0; rr < 4; rr++) {
            int i = wave * 16 + quad * 4 + rr;
            size_t idx = (size_t)(base + i) * D_INNER + h * HEADDIM + p;
            y[idx] += acc[nt][rr];
        }
    }
}

// ---------------- gated rmsnorm (z from 2 zx partials) -> bf16 ----------------
__global__ void k_gatednorm(const float* __restrict__ yscan, const float* __restrict__ zx,
                            const float* __restrict__ nw, unsigned short* __restrict__ out) {
    __shared__ float s4[4];
    const size_t PSTRZ = (size_t)ROWS * D_IN_PROJ;
    int row = blockIdx.x;
    const float* yp = yscan + (size_t)row * D_INNER;
    const float* zp0 = zx + (size_t)row * D_IN_PROJ;
    const float* zp1 = zp0 + PSTRZ;
    float v[6]; float ss = 0.f;
    #pragma unroll
    for (int j = 0; j < 6; j++) {
        int d = threadIdx.x + j * 256;
        float val = yp[d] * siluf(zp0[d] + zp1[d]);
        v[j] = val; ss += val * val;
    }
    ss = block_sum_256(ss, s4);
    float inv = rsqrtf(ss / (float)D_INNER + 1e-5f);
    #pragma unroll
    for (int j = 0; j < 6; j++) {
        int d = threadIdx.x + j * 256;
        out[(size_t)row * D_INNER + d] = f2b(v[j] * inv * nw[d]);
    }
}

// ---------------- hidden2 = hidden_n + g_mba*(Σ tmp partials + out_b); ln + msa mod ----
__global__ void k_fuse_ln(const float* __restrict__ hidden_n, const float* __restrict__ tmp,
                          const float* __restrict__ outb, const float* __restrict__ aff,
                          float* __restrict__ hidden2, unsigned short* __restrict__ attnx) {
    __shared__ float s4[4];
    const size_t PSTR = (size_t)ROWS * D_MODEL;
    int row = blockIdx.x;
    int b = row >> 9;
    const float* gm = aff + b * AFF + 1536;
    float v[3]; float s = 0.f;
    #pragma unroll
    for (int j = 0; j < 3; j++) {
        int d = threadIdx.x + j * 256;
        size_t idx = (size_t)row * D_MODEL + d;
        float t = tmp[idx] + tmp[idx + PSTR] + tmp[idx + 2 * PSTR] + tmp[idx + 3 * PSTR];
        float x = hidden_n[idx] + gm[d] * (t + outb[d]);
        hidden2[idx] = x;
        v[j] = x; s += x;
    }
    float mean = block_sum_256(s, s4) / (float)D_MODEL;
    float ss = 0.f;
    #pragma unroll
    for (int j = 0; j < 3; j++) { float c = v[j] - mean; ss += c * c; }
    float var = block_sum_256(ss, s4) / (float)D_MODEL;
    float inv = rsqrtf(var + 1e-6f);
    const float* sh = aff + b * AFF + 2304;
    const float* sc = aff + b * AFF + 3072;
    #pragma unroll
    for (int j = 0; j < 3; j++) {
        int d = threadIdx.x + j * 256;
        float xh = (v[j] - mean) * inv;
        attnx[(size_t)row * D_MODEL + d] = f2b(xh * (1.f + sc[d]) + sh[d]);
    }
}

// ---------------- cross-attention: fused Q-proj + MFMA QK^T + softmax + MFMA PV ---------
__global__ __launch_bounds__(256)
void k_attn(const unsigned short* __restrict__ attnx, const unsigned short* __restrict__ qwt,
            const unsigned short* __restrict__ kb, const unsigned short* __restrict__ vb,
            unsigned short* __restrict__ ob) {
    int blk = blockIdx.x;
    int lt = blk & 15; int h = (blk >> 4) & 7; int b = blk >> 7;
    __shared__ unsigned short sK[64][72];     // K [m][d]
    __shared__ unsigned short sVT[64][72];    // V^T [d][m]
    __shared__ unsigned short sA[32][136];
    __shared__ unsigned short sW[64][136];
    __shared__ unsigned short sQb[32][72];    // Q bf16 (pre-scaled)
    __shared__ unsigned short sP[32][72];     // softmax probs bf16
    int tid = threadIdx.x;
    // stage K rows + V transposed
    {
        int r = tid >> 2, c0 = (tid & 3) * 16;
        const unsigned short* kp = kb + (size_t)(b * LC + r) * AINNER + h * AD + c0;
        const unsigned short* vp = vb + (size_t)(b * LC + r) * AINNER + h * AD + c0;
        #pragma unroll
        for (int j = 0; j < 4; j++) {
            *(ushort4*)&sK[r][c0 + j * 4] = *(const ushort4*)&kp[j * 4];
            ushort4 vv = *(const ushort4*)&vp[j * 4];
            const unsigned short* hv = (const unsigned short*)&vv;
            #pragma unroll
            for (int e = 0; e < 4; e++) sVT[c0 + j * 4 + e][r] = hv[e];
        }
    }
    int lane = tid & 63, wave = tid >> 6;
    int l15 = lane & 15, quad = lane >> 4;
    int rt = wave >> 1, cp = (wave & 1) * 2;
    f32x4 accq[2];
    accq[0] = (f32x4){0.f, 0.f, 0.f, 0.f};
    accq[1] = (f32x4){0.f, 0.f, 0.f, 0.f};
    const size_t arow_base = (size_t)(b * SEQ + lt * 32) * D_MODEL;
    for (int k0 = 0; k0 < D_MODEL; k0 += 128) {
        __syncthreads();
        #pragma unroll
        for (int j = 0; j < 2; j++) {
            int s = tid + j * 256; int row = s >> 4, c8 = (s & 15) * 8;
            *(uint4*)&sA[row][c8] =
                *(const uint4*)&attnx[arow_base + (size_t)row * D_MODEL + k0 + c8];
        }
        #pragma unroll
        for (int j = 0; j < 4; j++) {
            int s = tid + j * 256; int row = s >> 4, c8 = (s & 15) * 8;
            *(uint4*)&sW[row][c8] =
                *(const uint4*)&qwt[(size_t)(h * AD + row) * D_MODEL + k0 + c8];
        }
        __syncthreads();
        #pragma unroll
        for (int ks = 0; ks < 4; ks++) {
            bf16x8 af = *(const bf16x8*)&sA[rt * 16 + l15][ks * 32 + quad * 8];
            #pragma unroll
            for (int j = 0; j < 2; j++) {
                bf16x8 bf = *(const bf16x8*)&sW[(cp + j) * 16 + l15][ks * 32 + quad * 8];
                accq[j] = __builtin_amdgcn_mfma_f32_16x16x32_bf16(af, bf, accq[j], 0, 0, 0);
            }
        }
    }
    // Q -> LDS bf16, scaled by 1/sqrt(AD)
    #pragma unroll
    for (int j = 0; j < 2; j++)
        #pragma unroll
        for (int rr = 0; rr < 4; rr++)
            sQb[rt * 16 + quad * 4 + rr][(cp + j) * 16 + l15] = f2b(accq[j][rr] * 0.125f);
    __syncthreads();
    // QK^T + softmax on waves 0,1 (qt = wave)
    if (wave < 2) {
        int qt = wave;
        f32x4 s[4];
        #pragma unroll
        for (int mt = 0; mt < 4; mt++) s[mt] = (f32x4){0.f, 0.f, 0.f, 0.f};
        #pragma unroll
        for (int k0 = 0; k0 < 2; k0++) {
            bf16x8 aq = *(const bf16x8*)&sQb[qt * 16 + l15][k0 * 32 + quad * 8];
            #pragma unroll
            for (int mt = 0; mt < 4; mt++) {
                bf16x8 bk = *(const bf16x8*)&sK[mt * 16 + l15][k0 * 32 + quad * 8];
                s[mt] = __builtin_amdgcn_mfma_f32_16x16x32_bf16(aq, bk, s[mt], 0, 0, 0);
            }
        }
        #pragma unroll
        for (int rr = 0; rr < 4; rr++) {
            float mx = fmaxf(fmaxf(s[0][rr], s[1][rr]), fmaxf(s[2][rr], s[3][rr]));
            #pragma unroll
            for (int off = 8; off > 0; off >>= 1) mx = fmaxf(mx, __shfl_xor(mx, off, 64));
            float e0 = expf(s[0][rr] - mx), e1 = expf(s[1][rr] - mx);
            float e2 = expf(s[2][rr] - mx), e3 = expf(s[3][rr] - mx);
            float sum = e0 + e1 + e2 + e3;
            #pragma unroll
            for (int off = 8; off > 0; off >>= 1) sum += __shfl_xor(sum, off, 64);
            float inv = 1.f / sum;
            int q = qt * 16 + quad * 4 + rr;
            sP[q][0 * 16 + l15] = f2b(e0 * inv);
            sP[q][1 * 16 + l15] = f2b(e1 * inv);
            sP[q][2 * 16 + l15] = f2b(e2 * inv);
            sP[q][3 * 16 + l15] = f2b(e3 * inv);
        }
    }
    __syncthreads();
    // PV: all 4 waves; qt = wave>>1, d-tile pair = (wave&1)*2
    {
        int qt = wave >> 1, dp = (wave & 1) * 2;
        f32x4 o[2];
        o[0] = (f32x4){0.f, 0.f, 0.f, 0.f};
        o[1] = (f32x4){0.f, 0.f, 0.f, 0.f};
        #pragma unroll
        for (int k0 = 0; k0 < 2; k0++) {
            bf16x8 ap = *(const bf16x8*)&sP[qt * 16 + l15][k0 * 32 + quad * 8];
            #pragma unroll
            for (int j = 0; j < 2; j++) {
                bf16x8 bv = *(const bf16x8*)&sVT[(dp + j) * 16 + l15][k0 * 32 + quad * 8];
                o[j] = __builtin_amdgcn_mfma_f32_16x16x32_bf16(ap, bv, o[j], 0, 0, 0);
            }
        }
        #pragma unroll
        for (int j = 0; j < 2; j++) {
            int d = (dp + j) * 16 + l15;
            #pragma unroll
            for (int rr = 0; rr < 4; rr++) {
                int q = qt * 16 + quad * 4 + rr;
                ob[(size_t)(b * SEQ + lt * 32 + q) * AINNER + h * AD + d] = f2b(o[j][rr]);
            }
        }
    }
}

// ---------------- final: h = hidden2 + g*(Σ raw partials + bias); rmsnorm(h + r) --------
__global__ void k_final(const float* __restrict__ hidden2, const float* __restrict__ raw,
                        const float* __restrict__ bias, const float* __restrict__ aff,
                        const float* __restrict__ residual, const float* __restrict__ w,
                        float* __restrict__ out) {
    __shared__ float s4[4];
    const size_t PSTR = (size_t)ROWS * D_MODEL;
    int row = blockIdx.x;
    int b = row >> 9;
    const float* gm = aff + b * AFF + 3840;
    float v[3]; float ss = 0.f;
    #pragma unroll
    for (int j = 0; j < 3; j++) {
        int d = threadIdx.x + j * 256;
        size_t idx = (size_t)row * D_MODEL + d;
        float rawv = raw[idx] + raw[idx + PSTR];
        float x = hidden2[idx] + gm[d] * (rawv + bias[d]) + residual[idx];
        v[j] = x; ss += x * x;
    }
    ss = block_sum_256(ss, s4);
    float inv = rsqrtf(ss / (float)D_MODEL + 1e-5f);
    #pragma unroll
    for (int j = 0; j < 3; j++) {
        int d = threadIdx.x + j * 256;
        out[(size_t)row * D_MODEL + d] = v[j] * inv * w[d];
    }
}

// ---------------- host launch ----------------
extern "C" void kernel_launch(void* const* d_in, const int* in_sizes, int n_in,
                              void* d_out, int out_size, void* d_ws, size_t ws_size,
                              hipStream_t stream) {
    const float* hidden_states = (const float*)d_in[0];
    const float* ref_emb  = (const float*)d_in[1];
    const float* norm_w   = (const float*)d_in[2];
    const float* ada_w    = (const float*)d_in[3];
    const float* ada_b    = (const float*)d_in[4];
    const float* in_w     = (const float*)d_in[5];
    const float* conv_w   = (const float*)d_in[6];
    const float* conv_b   = (const float*)d_in[7];
    const float* dt_bias  = (const float*)d_in[8];
    const float* A_log    = (const float*)d_in[9];
    const float* D_ssm    = (const float*)d_in[10];
    const float* ssm_nw   = (const float*)d_in[11];
    const float* out_w    = (const float*)d_in[12];
    const float* out_b    = (const float*)d_in[13];
    const float* q_w      = (const float*)d_in[14];
    const float* k_w      = (const float*)d_in[15];
    const float* v_w      = (const float*)d_in[16];
    const float* o_w      = (const float*)d_in[17];
    const float* o_b      = (const float*)d_in[18];
    const float* norm_f_w = (const float*)d_in[19];
    float* out = (float*)d_out;

    char* p = (char*)d_ws;
    auto alloc = [&](size_t bytes) -> char* {
        char* r = p; p += (bytes + 255) & ~(size_t)255; return r;
    };
    float* residual = (float*)alloc((size_t)ROWS * D_MODEL * 4);
    float* hidden2  = (float*)alloc((size_t)ROWS * D_MODEL * 4);
    float* hidden_n = (float*)alloc((size_t)ROWS * D_MODEL * 4);
    float* tmpM     = (float*)alloc((size_t)4 * ROWS * D_MODEL * 4);  // out-proj partials
    float* tmpO     = (float*)alloc((size_t)2 * ROWS * D_MODEL * 4);  // o-proj partials
    float* zx       = (float*)alloc((size_t)2 * ROWS * D_IN_PROJ * 4); // in-proj partials
    float* dtb      = (float*)alloc((size_t)ROWS * NHEADS * 4);
    float* yscan    = (float*)alloc((size_t)ROWS * D_INNER * 4);
    float* aff_all  = (float*)alloc((size_t)N_LAYER * BSZ * AFF * 4);
    float* smc      = (float*)alloc((size_t)BSZ * D_MODEL * 4);
    float* Pbuf     = (float*)alloc((size_t)BSZ * NHEADS * NCHUNK * 4);
    unsigned short* xBC    = (unsigned short*)alloc((size_t)ROWS * CONV_DIM * 2);
    unsigned short* Sbuf   = (unsigned short*)alloc((size_t)BSZ * NHEADS * NCHUNK * 8192 * 2);
    unsigned short* u_bf   = (unsigned short*)alloc((size_t)ROWS * D_MODEL * 2);
    unsigned short* ynorm  = (unsigned short*)alloc((size_t)ROWS * D_INNER * 2);
    unsigned short* attnx  = (unsigned short*)alloc((size_t)ROWS * D_MODEL * 2);
    unsigned short* ob     = (unsigned short*)alloc((size_t)ROWS * AINNER * 2);
    unsigned short* ref_bf = (unsigned short*)alloc((size_t)BSZ * LC * D_MODEL * 2);
    unsigned short* kb_all  = (unsigned short*)alloc((size_t)N_LAYER * BSZ * LC * AINNER * 2);
    unsigned short* vb_all  = (unsigned short*)alloc((size_t)N_LAYER * BSZ * LC * AINNER * 2);
    unsigned short* in_wt_all  = (unsigned short*)alloc((size_t)N_LAYER * NP1 * D_MODEL * 2);
    unsigned short* out_wt_all = (unsigned short*)alloc((size_t)N_LAYER * D_MODEL * D_INNER * 2);
    unsigned short* q_wt_all   = (unsigned short*)alloc((size_t)N_LAYER * AINNER * D_MODEL * 2);
    unsigned short* o_wt_all   = (unsigned short*)alloc((size_t)N_LAYER * D_MODEL * AINNER * 2);
    unsigned short* kwt_all = (unsigned short*)alloc((size_t)N_LAYER * AINNER * D_MODEL * 2);
    unsigned short* vwt_all = (unsigned short*)alloc((size_t)N_LAYER * AINNER * D_MODEL * 2);

    k_prep<<<42918, 256, 0, stream>>>(ref_emb, ref_bf, smc, ada_b, aff_all,
                                      in_w, out_w, q_w, k_w, v_w, o_w,
                                      in_wt_all, out_wt_all, q_wt_all, kwt_all, vwt_all,
                                      o_wt_all);
    k_kvada<<<dim3(18, 1, 80), 256, 0, stream>>>(ref_bf, kwt_all, vwt_all, kb_all, vb_all,
                                                 smc, ada_w, aff_all);

    for (int layer = 0; layer < N_LAYER; layer++) {
        const float* L_norm_w  = norm_w  + layer * D_MODEL;
        const float* L_conv_w  = conv_w  + layer * CONV_DIM * 4;
        const float* L_conv_b  = conv_b  + layer * CONV_DIM;
        const float* L_dt_bias = dt_bias + layer * NHEADS;
        const float* L_A_log   = A_log   + layer * NHEADS;
        const float* L_D_ssm   = D_ssm   + layer * NHEADS;
        const float* L_ssm_nw  = ssm_nw  + layer * D_INNER;
        const float* L_out_b   = out_b   + layer * D_MODEL;
        const float* L_o_b_prev= o_b     + (layer - 1) * D_MODEL;
        const float* L_aff     = aff_all + (size_t)layer * BSZ * AFF;
        const float* L_aff_prev= aff_all + (size_t)(layer - 1) * BSZ * AFF;
        const unsigned short* in_wt  = in_wt_all  + (size_t)layer * NP1 * D_MODEL;
        const unsigned short* out_wt = out_wt_all + (size_t)layer * D_MODEL * D_INNER;
        const unsigned short* q_wt   = q_wt_all   + (size_t)layer * AINNER * D_MODEL;
        const unsigned short* o_wt   = o_wt_all   + (size_t)layer * D_MODEL * AINNER;

        k_addrmsmod<<<ROWS, 256, 0, stream>>>(
            layer == 0 ? hidden_states : hidden2, tmpO,
            layer == 0 ? o_b : L_o_b_prev,
            layer == 0 ? aff_all : L_aff_prev,
            residual, L_norm_w, L_aff, hidden_n, u_bf, layer == 0 ? 0 : 1);
        k_gemm_sk<<<dim3(NP1 / 128, ROWS / 128, 2), 256, 0, stream>>>(u_bf, in_wt, zx, ROWS, D_IN_PROJ, D_MODEL, 384);
        k_convdt<<<(ROWS * CONV_DIM + 255) / 256, 256, 0, stream>>>(zx, L_conv_w, L_conv_b, L_dt_bias, xBC, dtb);
        k_ssm_par<<<dim3(NCHUNK, BSZ * NHEADS), 256, 0, stream>>>(xBC, dtb, L_A_log, L_D_ssm, yscan, Sbuf, Pbuf);
        k_ssm_fix<<<dim3(NCHUNK - 1, BSZ * NHEADS), 256, 0, stream>>>(xBC, dtb, L_A_log, Sbuf, Pbuf, yscan);
        k_gatednorm<<<ROWS, 256, 0, stream>>>(yscan, zx, L_ssm_nw, ynorm);
        k_gemm_sk<<<dim3(D_MODEL / 128, ROWS / 128, 4), 256, 0, stream>>>(ynorm, out_wt, tmpM, ROWS, D_MODEL, D_INNER, 384);
        k_fuse_ln<<<ROWS, 256, 0, stream>>>(hidden_n, tmpM, L_out_b, L_aff, hidden2, attnx);
        k_attn<<<BSZ * AH * 16, 256, 0, stream>>>(
            attnx, q_wt,
            kb_all + (size_t)layer * BSZ * LC * AINNER,
            vb_all + (size_t)layer * BSZ * LC * AINNER, ob);
        k_gemm_sk<<<dim3(D_MODEL / 128, ROWS / 128, 2), 256, 0, stream>>>(ob, o_wt, tmpO, ROWS, D_MODEL, AINNER, 256);
    }
    k_final<<<ROWS, 256, 0, stream>>>(hidden2, tmpO, o_b + (N_LAYER - 1) * D_MODEL,
                                      aff_all + (size_t)(N_LAYER - 1) * BSZ * AFF,
                                      residual, norm_f_w, out);
}

// Round 4
// 1089.146 us; speedup vs baseline: 1.6255x; 1.0458x over previous
//
#include <hip/hip_runtime.h>
#include <hip/hip_bf16.h>
#include <math.h>

// ---------------- constants ----------------
#define D_MODEL   768
#define N_LAYER   8
#define D_INNER   1536
#define D_STATE   128
#define HEADDIM   64
#define NHEADS    24
#define CONV_DIM  1792
#define D_IN_PROJ 3352
#define AH        8
#define AD        64
#define AINNER    512
#define BSZ       2
#define SEQ       512
#define LC        64
#define ROWS      (BSZ*SEQ)          // 1024
#define NCHUNK    8
#define CT        64                 // chunk length
#define NP1       3456               // 3352 padded to 27*128
#define AFF       4608

typedef __attribute__((ext_vector_type(8))) short bf16x8;
typedef __attribute__((ext_vector_type(4))) float f32x4;

__device__ __forceinline__ float siluf(float x) { return x / (1.f + expf(-x)); }

__device__ __forceinline__ unsigned short f2b(float x) {
    __hip_bfloat16 h = __float2bfloat16(x);
    return __builtin_bit_cast(unsigned short, h);
}
__device__ __forceinline__ float b2f(unsigned short u) {
    unsigned v = ((unsigned)u) << 16;
    return __builtin_bit_cast(float, v);
}

// async global->LDS 16B copy (wave-uniform base + lane*16 contiguity honored by callers)
__device__ __forceinline__ void gload16(const void* g, void* l) {
    __builtin_amdgcn_global_load_lds(
        (const __attribute__((address_space(1))) unsigned int*)g,
        (__attribute__((address_space(3))) unsigned int*)l,
        16, 0, 0);
}

// block-wide sum, 256 threads (4 waves)
__device__ __forceinline__ float block_sum_256(float v, float* s4) {
    #pragma unroll
    for (int o = 32; o > 0; o >>= 1) v += __shfl_down(v, o, 64);
    __syncthreads();
    if ((threadIdx.x & 63) == 0) s4[threadIdx.x >> 6] = v;
    __syncthreads();
    return s4[0] + s4[1] + s4[2] + s4[3];
}

// ---------------- fused preamble: f2b + silumean + ada init + ALL weight transposes ----
// segments: [0,96) ref f2b x4; [96,102) silumean; [102,390) ada init;
// [390,5574) in_w T; [5574,7878) out_w T; [7878,10182) q/k/v T; [10182,10950) o_w T.
// Transposes use 64x64 tiles: float4 reads (16B/lane), ushort4 transposed writes.
__global__ void k_prep(const float* __restrict__ ref_emb, unsigned short* __restrict__ ref_bf,
                       float* __restrict__ smc, const float* __restrict__ adab,
                       float* __restrict__ aff_all,
                       const float* __restrict__ in_w, const float* __restrict__ out_w,
                       const float* __restrict__ qw, const float* __restrict__ kw,
                       const float* __restrict__ vw, const float* __restrict__ ow,
                       unsigned short* __restrict__ in_wt, unsigned short* __restrict__ out_wt,
                       unsigned short* __restrict__ qwt, unsigned short* __restrict__ kwt,
                       unsigned short* __restrict__ vwt, unsigned short* __restrict__ owt) {
    int blk = blockIdx.x, t = threadIdx.x;
    if (blk < 96) {                               // ref f2b, vectorized x4
        int i4 = blk * 256 + t;
        float4 v = *(const float4*)&ref_emb[(size_t)i4 * 4];
        ushort4 o; o.x = f2b(v.x); o.y = f2b(v.y); o.z = f2b(v.z); o.w = f2b(v.w);
        *(ushort4*)&ref_bf[(size_t)i4 * 4] = o;
        return;
    }
    if (blk < 102) {                              // silu(mean(cond,1))
        int i = (blk - 96) * 256 + t;
        if (i < BSZ * D_MODEL) {
            int b = i / D_MODEL, d = i % D_MODEL;
            const float* p = ref_emb + (size_t)b * LC * D_MODEL + d;
            float s = 0.f;
            #pragma unroll 4
            for (int l = 0; l < LC; l++) s += p[l * D_MODEL];
            smc[i] = siluf(s * (1.f / (float)LC));
        }
        return;
    }
    if (blk < 390) {                              // aff init with bias
        int i = (blk - 102) * 256 + t;
        int j = i % AFF; int l = (i / AFF) >> 1;
        aff_all[i] = adab[l * AFF + j];
        return;
    }
    const float* src; unsigned short* dst; int K, N, n0, k0;
    int u = blk - 390;
    if (u < 5184) {                               // in_w: K=768, N=3352 (pad 3456)
        int z = u / 648, rem = u % 648;
        k0 = (rem / 54) * 64; n0 = (rem % 54) * 64;
        src = in_w + (size_t)z * 768 * 3352; dst = in_wt + (size_t)z * 3456 * 768;
        K = 768; N = 3352;
    } else if (u < 7488) {                        // out_w: K=1536, N=768
        u -= 5184; int z = u / 288, rem = u % 288;
        k0 = (rem / 12) * 64; n0 = (rem % 12) * 64;
        src = out_w + (size_t)z * 1536 * 768; dst = out_wt + (size_t)z * 768 * 1536;
        K = 1536; N = 768;
    } else if (u < 9792) {                        // q/k/v: K=768, N=512
        u -= 7488; int z = u / 96, rem = u % 96;
        k0 = (rem / 8) * 64; n0 = (rem % 8) * 64;
        int which = z >> 3, layer = z & 7;
        src = (which == 0 ? qw : which == 1 ? kw : vw) + (size_t)layer * 768 * 512;
        dst = (which == 0 ? qwt : which == 1 ? kwt : vwt) + (size_t)layer * 512 * 768;
        K = 768; N = 512;
    } else {                                      // o_w: K=512, N=768
        u -= 9792; int z = u / 96, rem = u % 96;
        k0 = (rem / 12) * 64; n0 = (rem % 12) * 64;
        src = ow + (size_t)z * 512 * 768; dst = owt + (size_t)z * 768 * 512;
        K = 512; N = 768;
    }
    __shared__ float tile[64][65];
    #pragma unroll
    for (int p2 = 0; p2 < 4; p2++) {
        int k = (t >> 4) + p2 * 16;
        int c = (t & 15) * 4;
        int n = n0 + c;
        float4 v = (float4){0.f, 0.f, 0.f, 0.f};
        if (n < N) v = *(const float4*)&src[(size_t)(k0 + k) * N + n];  // N%4==0: no straddle
        tile[k][c + 0] = v.x; tile[k][c + 1] = v.y;
        tile[k][c + 2] = v.z; tile[k][c + 3] = v.w;
    }
    __syncthreads();
    #pragma unroll
    for (int p2 = 0; p2 < 4; p2++) {
        int n = (t >> 4) + p2 * 16;
        int kk = (t & 15) * 4;
        ushort4 o;
        o.x = f2b(tile[kk + 0][n]); o.y = f2b(tile[kk + 1][n]);
        o.z = f2b(tile[kk + 2][n]); o.w = f2b(tile[kk + 3][n]);
        *(ushort4*)&dst[(size_t)(n0 + n) * K + k0 + kk] = o;
    }
}

// ---------------- merged K/V projection GEMM + ada split-K ----------------
// grid (18,1,80): z<16 -> kv gemm (x<4); z>=16 -> ada (l=(z-16)>>3, kc=(z-16)&7)
__global__ __launch_bounds__(256)
void k_kvada(const unsigned short* __restrict__ A, const unsigned short* __restrict__ Kwt,
             const unsigned short* __restrict__ Vwt, unsigned short* __restrict__ Kb,
             unsigned short* __restrict__ Vb,
             const float* __restrict__ smc, const float* __restrict__ adaw,
             float* __restrict__ aff_all) {
    int z = blockIdx.z;
    if (z >= 16) {
        int zz = z - 16; int l = zz >> 3, kc = zz & 7;
        int j = blockIdx.x * 256 + threadIdx.x;
        const float* w = adaw + (size_t)l * D_MODEL * AFF + j;
        const float* x0 = smc;
        const float* x1 = smc + D_MODEL;
        float s0 = 0.f, s1 = 0.f;
        int d0 = kc * 96;
        #pragma unroll 8
        for (int d = d0; d < d0 + 96; d++) {
            float wv = w[(size_t)d * AFF];
            s0 += x0[d] * wv; s1 += x1[d] * wv;
        }
        atomicAdd(&aff_all[(size_t)l * BSZ * AFF + j], s0);
        atomicAdd(&aff_all[(size_t)l * BSZ * AFF + AFF + j], s1);
        return;
    }
    if (blockIdx.x >= 4) return;
    int layer = z >> 1; int which = z & 1;
    const unsigned short* Bt = (which ? Vwt : Kwt) + (size_t)layer * AINNER * D_MODEL;
    unsigned short* C = (which ? Vb : Kb) + (size_t)layer * (BSZ * LC) * AINNER;
    __shared__ __align__(16) unsigned short As[128][32];
    __shared__ __align__(16) unsigned short Bs[128][32];
    int n0 = blockIdx.x * 128;
    int tid = threadIdx.x;
    int lane = tid & 63, wave = tid >> 6;
    int wm = (wave >> 1) * 64, wn = (wave & 1) * 64;
    int l15 = lane & 15, quad = lane >> 4;
    f32x4 acc[4][4];
    #pragma unroll
    for (int i = 0; i < 4; i++)
        #pragma unroll
        for (int j = 0; j < 4; j++) acc[i][j] = (f32x4){0.f, 0.f, 0.f, 0.f};
    int srow = tid >> 2, schunk = (tid & 3) * 8;
    for (int k0 = 0; k0 < D_MODEL; k0 += 32) {
        #pragma unroll
        for (int ps = 0; ps < 2; ps++) {
            int r = srow + ps * 64;
            gload16(&A[(size_t)r * D_MODEL + k0 + schunk], &As[r][schunk]);
            gload16(&Bt[(size_t)(n0 + r) * D_MODEL + k0 + schunk], &Bs[r][schunk]);
        }
        __syncthreads();
        bf16x8 af[4], bfr[4];
        #pragma unroll
        for (int i = 0; i < 4; i++) af[i]  = *(const bf16x8*)&As[wm + i * 16 + l15][quad * 8];
        #pragma unroll
        for (int j = 0; j < 4; j++) bfr[j] = *(const bf16x8*)&Bs[wn + j * 16 + l15][quad * 8];
        #pragma unroll
        for (int i = 0; i < 4; i++)
            #pragma unroll
            for (int j = 0; j < 4; j++)
                acc[i][j] = __builtin_amdgcn_mfma_f32_16x16x32_bf16(af[i], bfr[j], acc[i][j], 0, 0, 0);
        __syncthreads();
    }
    #pragma unroll
    for (int i = 0; i < 4; i++) {
        #pragma unroll
        for (int j = 0; j < 4; j++) {
            int col = n0 + wn + j * 16 + l15;
            #pragma unroll
            for (int r = 0; r < 4; r++) {
                int row = wm + i * 16 + quad * 4 + r;
                C[(size_t)row * AINNER + col] = f2b(acc[i][j][r]);
            }
        }
    }
}

// ---------------- split-K GEMM, double-buffered LDS + counted vmcnt (T3 min-2-phase) ----
// grid.z slices of width Kc; partial -> C + z*M*N
__global__ __launch_bounds__(256)
void k_gemm_sk(const unsigned short* __restrict__ A, const unsigned short* __restrict__ Bt,
               float* __restrict__ C, int M, int N, int K, int Kc) {
    int z = blockIdx.z;
    C += (size_t)z * M * N;
    int kbeg = z * Kc;
    int kend = kbeg + Kc; if (kend > K) kend = K;
    int nt = (kend - kbeg) >> 5;
    __shared__ __align__(16) unsigned short As[2][128][32];
    __shared__ __align__(16) unsigned short Bs[2][128][32];
    int m0 = blockIdx.y * 128, n0 = blockIdx.x * 128;
    int tid = threadIdx.x;
    int lane = tid & 63, wave = tid >> 6;
    int wm = (wave >> 1) * 64, wn = (wave & 1) * 64;
    int l15 = lane & 15, quad = lane >> 4;
    f32x4 acc[4][4];
    #pragma unroll
    for (int i = 0; i < 4; i++)
        #pragma unroll
        for (int j = 0; j < 4; j++) acc[i][j] = (f32x4){0.f, 0.f, 0.f, 0.f};

    int srow = tid >> 2;
    int schunk = (tid & 3) * 8;

    // stage: 4 gload16 per thread (2 A + 2 B) -> vmcnt counts 4 per wave per stage
    #define STAGE_SK(buf, kk0)                                                        \
        do {                                                                          \
            _Pragma("unroll")                                                         \
            for (int ps = 0; ps < 2; ps++) {                                          \
                int r = srow + ps * 64;                                               \
                gload16(&A[(size_t)(m0 + r) * K + (kk0) + schunk], &As[buf][r][schunk]); \
                gload16(&Bt[(size_t)(n0 + r) * K + (kk0) + schunk], &Bs[buf][r][schunk]); \
            }                                                                         \
        } while (0)

    STAGE_SK(0, kbeg);
    int cur = 0;
    for (int it = 0; it < nt; ++it) {
        if (it + 1 < nt) {
            STAGE_SK(cur ^ 1, kbeg + (it + 1) * 32);
            asm volatile("s_waitcnt vmcnt(4)" ::: "memory");   // wait tile it only; it+1 stays in flight
        } else {
            asm volatile("s_waitcnt vmcnt(0)" ::: "memory");
        }
        __builtin_amdgcn_s_barrier();                          // all waves' stage(it) visible
        bf16x8 af[4], bfr[4];
        #pragma unroll
        for (int i = 0; i < 4; i++) af[i]  = *(const bf16x8*)&As[cur][wm + i * 16 + l15][quad * 8];
        #pragma unroll
        for (int j = 0; j < 4; j++) bfr[j] = *(const bf16x8*)&Bs[cur][wn + j * 16 + l15][quad * 8];
        #pragma unroll
        for (int i = 0; i < 4; i++)
            #pragma unroll
            for (int j = 0; j < 4; j++)
                acc[i][j] = __builtin_amdgcn_mfma_f32_16x16x32_bf16(af[i], bfr[j], acc[i][j], 0, 0, 0);
        __builtin_amdgcn_s_barrier();                          // reads of buf[cur] done before overwrite
        cur ^= 1;
    }
    #undef STAGE_SK
    #pragma unroll
    for (int i = 0; i < 4; i++) {
        #pragma unroll
        for (int j = 0; j < 4; j++) {
            int col = n0 + wn + j * 16 + l15;
            if (col < N) {
                #pragma unroll
                for (int r = 0; r < 4; r++) {
                    int row = m0 + wm + i * 16 + quad * 4 + r;
                    C[(size_t)row * N + col] = acc[i][j][r];
                }
            }
        }
    }
}

// ---------------- [fused prev-attn out (2 split-K partials)] + residual + rmsnorm + mod ----
__global__ void k_addrmsmod(const float* __restrict__ hin, const float* __restrict__ raw,
                            const float* __restrict__ bias, const float* __restrict__ affprev,
                            float* __restrict__ residual, const float* __restrict__ normw,
                            const float* __restrict__ affcur,
                            float* __restrict__ hidden_n, unsigned short* __restrict__ u,
                            int has_raw) {
    __shared__ float s4[4];
    const size_t PSTR = (size_t)ROWS * D_MODEL;
    int row = blockIdx.x;
    int b = row >> 9;
    const float* hp = hin + (size_t)row * D_MODEL;
    float* rp = residual + (size_t)row * D_MODEL;
    float v[3]; float ss = 0.f;
    #pragma unroll
    for (int j = 0; j < 3; j++) {
        int d = threadIdx.x + j * 256;
        float x = hp[d];
        if (has_raw) {
            float g = affprev[b * AFF + 3840 + d];
            float rawv = raw[(size_t)row * D_MODEL + d] + raw[PSTR + (size_t)row * D_MODEL + d];
            x += g * (rawv + bias[d]) + rp[d];
        }
        rp[d] = x; v[j] = x; ss += x * x;
    }
    ss = block_sum_256(ss, s4);
    float inv = rsqrtf(ss / (float)D_MODEL + 1e-5f);
    const float* sh = affcur + b * AFF;
    const float* sc = affcur + b * AFF + 768;
    #pragma unroll
    for (int j = 0; j < 3; j++) {
        int d = threadIdx.x + j * 256;
        float hn = v[j] * inv * normw[d];
        hidden_n[(size_t)row * D_MODEL + d] = hn;
        u[(size_t)row * D_MODEL + d] = f2b(hn * (1.f + sc[d]) + sh[d]);
    }
}

// ---------------- depthwise causal conv + silu (zx 2 partials) -> bf16; softplus(dt) ----
__global__ void k_convdt(const float* __restrict__ zx, const float* __restrict__ convw,
                         const float* __restrict__ convb, const float* __restrict__ dtbias,
                         unsigned short* __restrict__ xBC, float* __restrict__ dtb) {
    const size_t PSTRZ = (size_t)ROWS * D_IN_PROJ;
    int i = blockIdx.x * 256 + threadIdx.x;
    if (i < ROWS * NHEADS) {
        int h = i % NHEADS; int row = i / NHEADS;
        size_t off = (size_t)row * D_IN_PROJ + D_INNER + CONV_DIM + h;
        float x = zx[off] + zx[off + PSTRZ] + dtbias[h];
        dtb[i] = (x > 20.f) ? x : log1pf(expf(x));
    }
    if (i >= ROWS * CONV_DIM) return;
    int c = i % CONV_DIM; int row = i / CONV_DIM;
    int l = row & 511; int b = row >> 9;
    float acc = convb[c];
    #pragma unroll
    for (int k = 0; k < 4; k++) {
        int t = l - 3 + k;
        if (t >= 0) {
            size_t idx = (size_t)(b * SEQ + t) * D_IN_PROJ + D_INNER + c;
            acc += convw[c * 4 + k] * (zx[idx] + zx[idx + PSTRZ]);
        }
    }
    xBC[i] = f2b(siluf(acc));
}

// ---------------- SSM K1: chunk-parallel (grid = NCHUNK x B*H), xBC bf16 ----------------
__global__ __launch_bounds__(256)
void k_ssm_par(const unsigned short* __restrict__ xBC, const float* __restrict__ dtb,
               const float* __restrict__ Alog, const float* __restrict__ Dssm,
               float* __restrict__ y, unsigned short* __restrict__ Sbuf,
               float* __restrict__ Pbuf) {
    __shared__ unsigned short sB[64][136];    // [t][n]
    __shared__ unsigned short sC[64][136];    // [t][n]
    __shared__ unsigned short sXT[64][72];    // [p][t]
    __shared__ unsigned short sG[64][72];     // G[i][s]; reused as XwT [p][t]
    __shared__ unsigned short sBT[128][72];   // [n][t]
    __shared__ float sL[64], sDt[64];
    int c = blockIdx.x, bh = blockIdx.y;
    int h = bh % NHEADS, b = bh / NHEADS;
    int tid = threadIdx.x;
    int lane = tid & 63, wave = tid >> 6;
    int l15 = lane & 15, quad = lane >> 4;
    int r = tid >> 2, q4 = tid & 3;
    int base = b * SEQ + c * CT;
    float a_h = expf(Alog[h]);
    float Dh = Dssm[h];
    if (tid < 64) {
        float dt = dtb[(base + tid) * NHEADS + h];
        float v = -a_h * dt;
        #pragma unroll
        for (int off = 1; off < 64; off <<= 1) {
            float u2 = __shfl_up(v, off, 64);
            if (tid >= off) v += u2;
        }
        sL[tid] = v; sDt[tid] = dt;
    }
    const unsigned short* xrow = xBC + (size_t)(base + r) * CONV_DIM;
    #pragma unroll
    for (int j = 0; j < 4; j++) {
        int n0 = q4 * 32 + j * 8;
        uint4 v = *(const uint4*)&xrow[D_INNER + n0];
        *(uint4*)&sB[r][n0] = v;
        const unsigned short* hv = (const unsigned short*)&v;
        #pragma unroll
        for (int e = 0; e < 8; e++) sBT[n0 + e][r] = hv[e];
        uint4 w = *(const uint4*)&xrow[D_INNER + D_STATE + n0];
        *(uint4*)&sC[r][n0] = w;
    }
    #pragma unroll
    for (int j = 0; j < 2; j++) {
        int p0 = q4 * 16 + j * 8;
        uint4 v = *(const uint4*)&xrow[h * HEADDIM + p0];
        const unsigned short* hv = (const unsigned short*)&v;
        #pragma unroll
        for (int e = 0; e < 8; e++) sXT[p0 + e][r] = hv[e];
    }
    __syncthreads();
    if (tid == 0) Pbuf[bh * NCHUNK + c] = expf(sL[63]);

    // acc1 = C·B^T  (CB[t][s])
    f32x4 acc1[4];
    #pragma unroll
    for (int j = 0; j < 4; j++) acc1[j] = (f32x4){0.f, 0.f, 0.f, 0.f};
    #pragma unroll
    for (int k0 = 0; k0 < 4; k0++) {
        bf16x8 a = *(const bf16x8*)&sC[wave * 16 + l15][k0 * 32 + quad * 8];
        #pragma unroll
        for (int nt = 0; nt < 4; nt++) {
            bf16x8 bv = *(const bf16x8*)&sB[nt * 16 + l15][k0 * 32 + quad * 8];
            acc1[nt] = __builtin_amdgcn_mfma_f32_16x16x32_bf16(a, bv, acc1[nt], 0, 0, 0);
        }
    }
    // G[i][s] = causal mask * CB * exp(L_i - L_s) * dt_s
    #pragma unroll
    for (int nt = 0; nt < 4; nt++) {
        int s = nt * 16 + l15;
        float Ls = sL[s], dts = sDt[s];
        #pragma unroll
        for (int rr = 0; rr < 4; rr++) {
            int i = wave * 16 + quad * 4 + rr;
            float g = (s <= i) ? acc1[nt][rr] * expf(sL[i] - Ls) * dts : 0.f;
            sG[i][s] = f2b(g);
        }
    }
    __syncthreads();

    // acc2 = G·X^T ; y_partial write (+ D·x)
    f32x4 acc2[4];
    #pragma unroll
    for (int j = 0; j < 4; j++) acc2[j] = (f32x4){0.f, 0.f, 0.f, 0.f};
    #pragma unroll
    for (int k0 = 0; k0 < 2; k0++) {
        bf16x8 a = *(const bf16x8*)&sG[wave * 16 + l15][k0 * 32 + quad * 8];
        #pragma unroll
        for (int nt = 0; nt < 4; nt++) {
            bf16x8 bv = *(const bf16x8*)&sXT[nt * 16 + l15][k0 * 32 + quad * 8];
            acc2[nt] = __builtin_amdgcn_mfma_f32_16x16x32_bf16(a, bv, acc2[nt], 0, 0, 0);
        }
    }
    #pragma unroll
    for (int nt = 0; nt < 4; nt++) {
        int p = nt * 16 + l15;
        #pragma unroll
        for (int rr = 0; rr < 4; rr++) {
            int i = wave * 16 + quad * 4 + rr;
            float xv = b2f(sXT[p][i]);
            y[(size_t)(base + i) * D_INNER + h * HEADDIM + p] = acc2[nt][rr] + Dh * xv;
        }
    }
    __syncthreads();
    // XwT[p][t] = X[t][p] * exp(Lend - L_t) * dt_t  (reuse sG)
    {
        float wr2 = expf(sL[63] - sL[r]) * sDt[r];
        #pragma unroll
        for (int j = 0; j < 16; j++) {
            int pp = q4 * 16 + j;
            sG[pp][r] = f2b(b2f(sXT[pp][r]) * wr2);
        }
    }
    __syncthreads();
    // S[p][n] = Xw·B -> Sbuf bf16
    f32x4 accS[8];
    #pragma unroll
    for (int j = 0; j < 8; j++) accS[j] = (f32x4){0.f, 0.f, 0.f, 0.f};
    #pragma unroll
    for (int k0 = 0; k0 < 2; k0++) {
        bf16x8 a = *(const bf16x8*)&sG[wave * 16 + l15][k0 * 32 + quad * 8];
        #pragma unroll
        for (int nt = 0; nt < 8; nt++) {
            bf16x8 bv = *(const bf16x8*)&sBT[nt * 16 + l15][k0 * 32 + quad * 8];
            accS[nt] = __builtin_amdgcn_mfma_f32_16x16x32_bf16(a, bv, accS[nt], 0, 0, 0);
        }
    }
    unsigned short* sout = Sbuf + ((size_t)bh * NCHUNK + c) * 8192;
    #pragma unroll
    for (int nt = 0; nt < 8; nt++) {
        int n = nt * 16 + l15;
        #pragma unroll
        for (int rr = 0; rr < 4; rr++) {
            int p = wave * 16 + quad * 4 + rr;
            sout[p * 128 + n] = f2b(accS[nt][rr]);
        }
    }
}

// ---------------- SSM K2: h-contribution, chunk-parallel (grid = (NCHUNK-1) x B*H) ------
__global__ __launch_bounds__(256)
void k_ssm_fix(const unsigned short* __restrict__ xBC, const float* __restrict__ dtb,
               const float* __restrict__ Alog, const unsigned short* __restrict__ Sbuf,
               const float* __restrict__ Pbuf, float* __restrict__ y) {
    __shared__ unsigned short sC[64][136];    // C~ = C * exp(L_t)
    __shared__ unsigned short sHB[64][136];   // h_start bf16 [p][n]
    __shared__ float sL[64];
    int c = blockIdx.x + 1, bh = blockIdx.y;
    int h = bh % NHEADS, b = bh / NHEADS;
    int tid = threadIdx.x;
    int lane = tid & 63, wave = tid >> 6;
    int l15 = lane & 15, quad = lane >> 4;
    int r = tid >> 2, q4 = tid & 3;
    int base = b * SEQ + c * CT;
    if (tid < 64) {
        float dt = dtb[(base + tid) * NHEADS + h];
        float v = -expf(Alog[h]) * dt;
        #pragma unroll
        for (int off = 1; off < 64; off <<= 1) {
            float u2 = __shfl_up(v, off, 64);
            if (tid >= off) v += u2;
        }
        sL[tid] = v;
    }
    // h_start: thread owns row p=r, cols [q4*32, q4*32+32)
    float hacc[32];
    #pragma unroll
    for (int e = 0; e < 32; e++) hacc[e] = 0.f;
    {
        const unsigned short* sp = Sbuf + (size_t)bh * NCHUNK * 8192 + r * 128 + q4 * 32;
        float w = 1.f;
        for (int j = c - 1; j >= 0; j--) {
            const unsigned short* srow = sp + (size_t)j * 8192;
            #pragma unroll
            for (int q = 0; q < 4; q++) {
                bf16x8 vv = *(const bf16x8*)&srow[q * 8];
                #pragma unroll
                for (int e = 0; e < 8; e++)
                    hacc[q * 8 + e] += w * b2f((unsigned short)vv[e]);
            }
            w *= Pbuf[bh * NCHUNK + j];
        }
    }
    __syncthreads();
    #pragma unroll
    for (int e = 0; e < 32; e++) sHB[r][q4 * 32 + e] = f2b(hacc[e]);
    {
        float el = expf(sL[r]);
        const unsigned short* xrow = xBC + (size_t)(base + r) * CONV_DIM + D_INNER + D_STATE;
        #pragma unroll
        for (int j = 0; j < 4; j++) {
            int n0 = q4 * 32 + j * 8;
            uint4 v = *(const uint4*)&xrow[n0];
            const unsigned short* hv = (const unsigned short*)&v;
            #pragma unroll
            for (int e = 0; e < 8; e++) sC[r][n0 + e] = f2b(b2f(hv[e]) * el);
        }
    }
    __syncthreads();
    // y[t][p] += sum_n C~[t][n] h[p][n]
    f32x4 acc[4];
    #pragma unroll
    for (int j = 0; j < 4; j++) acc[j] = (f32x4){0.f, 0.f, 0.f, 0.f};
    #pragma unroll
    for (int k0 = 0; k0 < 4; k0++) {
        bf16x8 a = *(const bf16x8*)&sC[wave * 16 + l15][k0 * 32 + quad * 8];
        #pragma unroll
        for (int nt = 0; nt < 4; nt++) {
            bf16x8 bv = *(const bf16x8*)&sHB[nt * 16 + l15][k0 * 32 + quad * 8];
            acc[nt] = __builtin_amdgcn_mfma_f32_16x16x32_bf16(a, bv, acc[nt], 0, 0, 0);
        }
    }
    #pragma unroll
    for (int nt = 0; nt < 4; nt++) {
        int p = nt * 16 + l15;
        #pragma unroll
        for (int rr = 0; rr < 4; rr++) {
            int i = wave * 16 + quad * 4 + rr;
            size_t idx = (size_t)(base + i) * D_INNER + h * HEADDIM + p;
            y[idx] += acc[nt][rr];
        }
    }
}

// ---------------- gated rmsnorm (z from 2 zx partials) -> bf16 ----------------
__global__ void k_gatednorm(const float* __restrict__ yscan, const float* __restrict__ zx,
                            const float* __restrict__ nw, unsigned short* __restrict__ out) {
    __shared__ float s4[4];
    const size_t PSTRZ = (size_t)ROWS * D_IN_PROJ;
    int row = blockIdx.x;
    const float* yp = yscan + (size_t)row * D_INNER;
    const float* zp0 = zx + (size_t)row * D_IN_PROJ;
    const float* zp1 = zp0 + PSTRZ;
    float v[6]; float ss = 0.f;
    #pragma unroll
    for (int j = 0; j < 6; j++) {
        int d = threadIdx.x + j * 256;
        float val = yp[d] * siluf(zp0[d] + zp1[d]);
        v[j] = val; ss += val * val;
    }
    ss = block_sum_256(ss, s4);
    float inv = rsqrtf(ss / (float)D_INNER + 1e-5f);
    #pragma unroll
    for (int j = 0; j < 6; j++) {
        int d = threadIdx.x + j * 256;
        out[(size_t)row * D_INNER + d] = f2b(v[j] * inv * nw[d]);
    }
}

// ---------------- hidden2 = hidden_n + g_mba*(Σ tmp partials + out_b); ln + msa mod ----
__global__ void k_fuse_ln(const float* __restrict__ hidden_n, const float* __restrict__ tmp,
                          const float* __restrict__ outb, const float* __restrict__ aff,
                          float* __restrict__ hidden2, unsigned short* __restrict__ attnx) {
    __shared__ float s4[4];
    const size_t PSTR = (size_t)ROWS * D_MODEL;
    int row = blockIdx.x;
    int b = row >> 9;
    const float* gm = aff + b * AFF + 1536;
    float v[3]; float s = 0.f;
    #pragma unroll
    for (int j = 0; j < 3; j++) {
        int d = threadIdx.x + j * 256;
        size_t idx = (size_t)row * D_MODEL + d;
        float t = tmp[idx] + tmp[idx + PSTR] + tmp[idx + 2 * PSTR] + tmp[idx + 3 * PSTR];
        float x = hidden_n[idx] + gm[d] * (t + outb[d]);
        hidden2[idx] = x;
        v[j] = x; s += x;
    }
    float mean = block_sum_256(s, s4) / (float)D_MODEL;
    float ss = 0.f;
    #pragma unroll
    for (int j = 0; j < 3; j++) { float c = v[j] - mean; ss += c * c; }
    float var = block_sum_256(ss, s4) / (float)D_MODEL;
    float inv = rsqrtf(var + 1e-6f);
    const float* sh = aff + b * AFF + 2304;
    const float* sc = aff + b * AFF + 3072;
    #pragma unroll
    for (int j = 0; j < 3; j++) {
        int d = threadIdx.x + j * 256;
        float xh = (v[j] - mean) * inv;
        attnx[(size_t)row * D_MODEL + d] = f2b(xh * (1.f + sc[d]) + sh[d]);
    }
}

// ---------------- cross-attention: fused Q-proj + MFMA QK^T + softmax + MFMA PV ---------
__global__ __launch_bounds__(256)
void k_attn(const unsigned short* __restrict__ attnx, const unsigned short* __restrict__ qwt,
            const unsigned short* __restrict__ kb, const unsigned short* __restrict__ vb,
            unsigned short* __restrict__ ob) {
    int blk = blockIdx.x;
    int lt = blk & 15; int h = (blk >> 4) & 7; int b = blk >> 7;
    __shared__ unsigned short sK[64][72];     // K [m][d]
    __shared__ unsigned short sVT[64][72];    // V^T [d][m]
    __shared__ unsigned short sA[32][136];
    __shared__ unsigned short sW[64][136];
    __shared__ unsigned short sQb[32][72];    // Q bf16 (pre-scaled)
    __shared__ unsigned short sP[32][72];     // softmax probs bf16
    int tid = threadIdx.x;
    // stage K rows + V transposed
    {
        int r = tid >> 2, c0 = (tid & 3) * 16;
        const unsigned short* kp = kb + (size_t)(b * LC + r) * AINNER + h * AD + c0;
        const unsigned short* vp = vb + (size_t)(b * LC + r) * AINNER + h * AD + c0;
        #pragma unroll
        for (int j = 0; j < 4; j++) {
            *(ushort4*)&sK[r][c0 + j * 4] = *(const ushort4*)&kp[j * 4];
            ushort4 vv = *(const ushort4*)&vp[j * 4];
            const unsigned short* hv = (const unsigned short*)&vv;
            #pragma unroll
            for (int e = 0; e < 4; e++) sVT[c0 + j * 4 + e][r] = hv[e];
        }
    }
    int lane = tid & 63, wave = tid >> 6;
    int l15 = lane & 15, quad = lane >> 4;
    int rt = wave >> 1, cp = (wave & 1) * 2;
    f32x4 accq[2];
    accq[0] = (f32x4){0.f, 0.f, 0.f, 0.f};
    accq[1] = (f32x4){0.f, 0.f, 0.f, 0.f};
    const size_t arow_base = (size_t)(b * SEQ + lt * 32) * D_MODEL;
    for (int k0 = 0; k0 < D_MODEL; k0 += 128) {
        __syncthreads();
        #pragma unroll
        for (int j = 0; j < 2; j++) {
            int s = tid + j * 256; int row = s >> 4, c8 = (s & 15) * 8;
            *(uint4*)&sA[row][c8] =
                *(const uint4*)&attnx[arow_base + (size_t)row * D_MODEL + k0 + c8];
        }
        #pragma unroll
        for (int j = 0; j < 4; j++) {
            int s = tid + j * 256; int row = s >> 4, c8 = (s & 15) * 8;
            *(uint4*)&sW[row][c8] =
                *(const uint4*)&qwt[(size_t)(h * AD + row) * D_MODEL + k0 + c8];
        }
        __syncthreads();
        #pragma unroll
        for (int ks = 0; ks < 4; ks++) {
            bf16x8 af = *(const bf16x8*)&sA[rt * 16 + l15][ks * 32 + quad * 8];
            #pragma unroll
            for (int j = 0; j < 2; j++) {
                bf16x8 bf = *(const bf16x8*)&sW[(cp + j) * 16 + l15][ks * 32 + quad * 8];
                accq[j] = __builtin_amdgcn_mfma_f32_16x16x32_bf16(af, bf, accq[j], 0, 0, 0);
            }
        }
    }
    // Q -> LDS bf16, scaled by 1/sqrt(AD)
    #pragma unroll
    for (int j = 0; j < 2; j++)
        #pragma unroll
        for (int rr = 0; rr < 4; rr++)
            sQb[rt * 16 + quad * 4 + rr][(cp + j) * 16 + l15] = f2b(accq[j][rr] * 0.125f);
    __syncthreads();
    // QK^T + softmax on waves 0,1 (qt = wave)
    if (wave < 2) {
        int qt = wave;
        f32x4 s[4];
        #pragma unroll
        for (int mt = 0; mt < 4; mt++) s[mt] = (f32x4){0.f, 0.f, 0.f, 0.f};
        #pragma unroll
        for (int k0 = 0; k0 < 2; k0++) {
            bf16x8 aq = *(const bf16x8*)&sQb[qt * 16 + l15][k0 * 32 + quad * 8];
            #pragma unroll
            for (int mt = 0; mt < 4; mt++) {
                bf16x8 bk = *(const bf16x8*)&sK[mt * 16 + l15][k0 * 32 + quad * 8];
                s[mt] = __builtin_amdgcn_mfma_f32_16x16x32_bf16(aq, bk, s[mt], 0, 0, 0);
            }
        }
        #pragma unroll
        for (int rr = 0; rr < 4; rr++) {
            float mx = fmaxf(fmaxf(s[0][rr], s[1][rr]), fmaxf(s[2][rr], s[3][rr]));
            #pragma unroll
            for (int off = 8; off > 0; off >>= 1) mx = fmaxf(mx, __shfl_xor(mx, off, 64));
            float e0 = expf(s[0][rr] - mx), e1 = expf(s[1][rr] - mx);
            float e2 = expf(s[2][rr] - mx), e3 = expf(s[3][rr] - mx);
            float sum = e0 + e1 + e2 + e3;
            #pragma unroll
            for (int off = 8; off > 0; off >>= 1) sum += __shfl_xor(sum, off, 64);
            float inv = 1.f / sum;
            int q = qt * 16 + quad * 4 + rr;
            sP[q][0 * 16 + l15] = f2b(e0 * inv);
            sP[q][1 * 16 + l15] = f2b(e1 * inv);
            sP[q][2 * 16 + l15] = f2b(e2 * inv);
            sP[q][3 * 16 + l15] = f2b(e3 * inv);
        }
    }
    __syncthreads();
    // PV: all 4 waves; qt = wave>>1, d-tile pair = (wave&1)*2
    {
        int qt = wave >> 1, dp = (wave & 1) * 2;
        f32x4 o[2];
        o[0] = (f32x4){0.f, 0.f, 0.f, 0.f};
        o[1] = (f32x4){0.f, 0.f, 0.f, 0.f};
        #pragma unroll
        for (int k0 = 0; k0 < 2; k0++) {
            bf16x8 ap = *(const bf16x8*)&sP[qt * 16 + l15][k0 * 32 + quad * 8];
            #pragma unroll
            for (int j = 0; j < 2; j++) {
                bf16x8 bv = *(const bf16x8*)&sVT[(dp + j) * 16 + l15][k0 * 32 + quad * 8];
                o[j] = __builtin_amdgcn_mfma_f32_16x16x32_bf16(ap, bv, o[j], 0, 0, 0);
            }
        }
        #pragma unroll
        for (int j = 0; j < 2; j++) {
            int d = (dp + j) * 16 + l15;
            #pragma unroll
            for (int rr = 0; rr < 4; rr++) {
                int q = qt * 16 + quad * 4 + rr;
                ob[(size_t)(b * SEQ + lt * 32 + q) * AINNER + h * AD + d] = f2b(o[j][rr]);
            }
        }
    }
}

// ---------------- final: h = hidden2 + g*(Σ raw partials + bias); rmsnorm(h + r) --------
__global__ void k_final(const float* __restrict__ hidden2, const float* __restrict__ raw,
                        const float* __restrict__ bias, const float* __restrict__ aff,
                        const float* __restrict__ residual, const float* __restrict__ w,
                        float* __restrict__ out) {
    __shared__ float s4[4];
    const size_t PSTR = (size_t)ROWS * D_MODEL;
    int row = blockIdx.x;
    int b = row >> 9;
    const float* gm = aff + b * AFF + 3840;
    float v[3]; float ss = 0.f;
    #pragma unroll
    for (int j = 0; j < 3; j++) {
        int d = threadIdx.x + j * 256;
        size_t idx = (size_t)row * D_MODEL + d;
        float rawv = raw[idx] + raw[idx + PSTR];
        float x = hidden2[idx] + gm[d] * (rawv + bias[d]) + residual[idx];
        v[j] = x; ss += x * x;
    }
    ss = block_sum_256(ss, s4);
    float inv = rsqrtf(ss / (float)D_MODEL + 1e-5f);
    #pragma unroll
    for (int j = 0; j < 3; j++) {
        int d = threadIdx.x + j * 256;
        out[(size_t)row * D_MODEL + d] = v[j] * inv * w[d];
    }
}

// ---------------- host launch ----------------
extern "C" void kernel_launch(void* const* d_in, const int* in_sizes, int n_in,
                              void* d_out, int out_size, void* d_ws, size_t ws_size,
                              hipStream_t stream) {
    const float* hidden_states = (const float*)d_in[0];
    const float* ref_emb  = (const float*)d_in[1];
    const float* norm_w   = (const float*)d_in[2];
    const float* ada_w    = (const float*)d_in[3];
    const float* ada_b    = (const float*)d_in[4];
    const float* in_w     = (const float*)d_in[5];
    const float* conv_w   = (const float*)d_in[6];
    const float* conv_b   = (const float*)d_in[7];
    const float* dt_bias  = (const float*)d_in[8];
    const float* A_log    = (const float*)d_in[9];
    const float* D_ssm    = (const float*)d_in[10];
    const float* ssm_nw   = (const float*)d_in[11];
    const float* out_w    = (const float*)d_in[12];
    const float* out_b    = (const float*)d_in[13];
    const float* q_w      = (const float*)d_in[14];
    const float* k_w      = (const float*)d_in[15];
    const float* v_w      = (const float*)d_in[16];
    const float* o_w      = (const float*)d_in[17];
    const float* o_b      = (const float*)d_in[18];
    const float* norm_f_w = (const float*)d_in[19];
    float* out = (float*)d_out;

    char* p = (char*)d_ws;
    auto alloc = [&](size_t bytes) -> char* {
        char* r = p; p += (bytes + 255) & ~(size_t)255; return r;
    };
    float* residual = (float*)alloc((size_t)ROWS * D_MODEL * 4);
    float* hidden2  = (float*)alloc((size_t)ROWS * D_MODEL * 4);
    float* hidden_n = (float*)alloc((size_t)ROWS * D_MODEL * 4);
    float* tmpM     = (float*)alloc((size_t)4 * ROWS * D_MODEL * 4);  // out-proj partials
    float* tmpO     = (float*)alloc((size_t)2 * ROWS * D_MODEL * 4);  // o-proj partials
    float* zx       = (float*)alloc((size_t)2 * ROWS * D_IN_PROJ * 4); // in-proj partials
    float* dtb      = (float*)alloc((size_t)ROWS * NHEADS * 4);
    float* yscan    = (float*)alloc((size_t)ROWS * D_INNER * 4);
    float* aff_all  = (float*)alloc((size_t)N_LAYER * BSZ * AFF * 4);
    float* smc      = (float*)alloc((size_t)BSZ * D_MODEL * 4);
    float* Pbuf     = (float*)alloc((size_t)BSZ * NHEADS * NCHUNK * 4);
    unsigned short* xBC    = (unsigned short*)alloc((size_t)ROWS * CONV_DIM * 2);
    unsigned short* Sbuf   = (unsigned short*)alloc((size_t)BSZ * NHEADS * NCHUNK * 8192 * 2);
    unsigned short* u_bf   = (unsigned short*)alloc((size_t)ROWS * D_MODEL * 2);
    unsigned short* ynorm  = (unsigned short*)alloc((size_t)ROWS * D_INNER * 2);
    unsigned short* attnx  = (unsigned short*)alloc((size_t)ROWS * D_MODEL * 2);
    unsigned short* ob     = (unsigned short*)alloc((size_t)ROWS * AINNER * 2);
    unsigned short* ref_bf = (unsigned short*)alloc((size_t)BSZ * LC * D_MODEL * 2);
    unsigned short* kb_all  = (unsigned short*)alloc((size_t)N_LAYER * BSZ * LC * AINNER * 2);
    unsigned short* vb_all  = (unsigned short*)alloc((size_t)N_LAYER * BSZ * LC * AINNER * 2);
    unsigned short* in_wt_all  = (unsigned short*)alloc((size_t)N_LAYER * NP1 * D_MODEL * 2);
    unsigned short* out_wt_all = (unsigned short*)alloc((size_t)N_LAYER * D_MODEL * D_INNER * 2);
    unsigned short* q_wt_all   = (unsigned short*)alloc((size_t)N_LAYER * AINNER * D_MODEL * 2);
    unsigned short* o_wt_all   = (unsigned short*)alloc((size_t)N_LAYER * D_MODEL * AINNER * 2);
    unsigned short* kwt_all = (unsigned short*)alloc((size_t)N_LAYER * AINNER * D_MODEL * 2);
    unsigned short* vwt_all = (unsigned short*)alloc((size_t)N_LAYER * AINNER * D_MODEL * 2);

    k_prep<<<10950, 256, 0, stream>>>(ref_emb, ref_bf, smc, ada_b, aff_all,
                                      in_w, out_w, q_w, k_w, v_w, o_w,
                                      in_wt_all, out_wt_all, q_wt_all, kwt_all, vwt_all,
                                      o_wt_all);
    k_kvada<<<dim3(18, 1, 80), 256, 0, stream>>>(ref_bf, kwt_all, vwt_all, kb_all, vb_all,
                                                 smc, ada_w, aff_all);

    for (int layer = 0; layer < N_LAYER; layer++) {
        const float* L_norm_w  = norm_w  + layer * D_MODEL;
        const float* L_conv_w  = conv_w  + layer * CONV_DIM * 4;
        const float* L_conv_b  = conv_b  + layer * CONV_DIM;
        const float* L_dt_bias = dt_bias + layer * NHEADS;
        const float* L_A_log   = A_log   + layer * NHEADS;
        const float* L_D_ssm   = D_ssm   + layer * NHEADS;
        const float* L_ssm_nw  = ssm_nw  + layer * D_INNER;
        const float* L_out_b   = out_b   + layer * D_MODEL;
        const float* L_o_b_prev= o_b     + (layer - 1) * D_MODEL;
        const float* L_aff     = aff_all + (size_t)layer * BSZ * AFF;
        const float* L_aff_prev= aff_all + (size_t)(layer - 1) * BSZ * AFF;
        const unsigned short* in_wt  = in_wt_all  + (size_t)layer * NP1 * D_MODEL;
        const unsigned short* out_wt = out_wt_all + (size_t)layer * D_MODEL * D_INNER;
        const unsigned short* q_wt   = q_wt_all   + (size_t)layer * AINNER * D_MODEL;
        const unsigned short* o_wt   = o_wt_all   + (size_t)layer * D_MODEL * AINNER;

        k_addrmsmod<<<ROWS, 256, 0, stream>>>(
            layer == 0 ? hidden_states : hidden2, tmpO,
            layer == 0 ? o_b : L_o_b_prev,
            layer == 0 ? aff_all : L_aff_prev,
            residual, L_norm_w, L_aff, hidden_n, u_bf, layer == 0 ? 0 : 1);
        k_gemm_sk<<<dim3(NP1 / 128, ROWS / 128, 2), 256, 0, stream>>>(u_bf, in_wt, zx, ROWS, D_IN_PROJ, D_MODEL, 384);
        k_convdt<<<(ROWS * CONV_DIM + 255) / 256, 256, 0, stream>>>(zx, L_conv_w, L_conv_b, L_dt_bias, xBC, dtb);
        k_ssm_par<<<dim3(NCHUNK, BSZ * NHEADS), 256, 0, stream>>>(xBC, dtb, L_A_log, L_D_ssm, yscan, Sbuf, Pbuf);
        k_ssm_fix<<<dim3(NCHUNK - 1, BSZ * NHEADS), 256, 0, stream>>>(xBC, dtb, L_A_log, Sbuf, Pbuf, yscan);
        k_gatednorm<<<ROWS, 256, 0, stream>>>(yscan, zx, L_ssm_nw, ynorm);
        k_gemm_sk<<<dim3(D_MODEL / 128, ROWS / 128, 4), 256, 0, stream>>>(ynorm, out_wt, tmpM, ROWS, D_MODEL, D_INNER, 384);
        k_fuse_ln<<<ROWS, 256, 0, stream>>>(hidden_n, tmpM, L_out_b, L_aff, hidden2, attnx);
        k_attn<<<BSZ * AH * 16, 256, 0, stream>>>(
            attnx, q_wt,
            kb_all + (size_t)layer * BSZ * LC * AINNER,
            vb_all + (size_t)layer * BSZ * LC * AINNER, ob);
        k_gemm_sk<<<dim3(D_MODEL / 128, ROWS / 128, 2), 256, 0, stream>>>(ob, o_wt, tmpO, ROWS, D_MODEL, AINNER, 256);
    }
    k_final<<<ROWS, 256, 0, stream>>>(hidden2, tmpO, o_b + (N_LAYER - 1) * D_MODEL,
                                      aff_all + (size_t)(N_LAYER - 1) * BSZ * AFF,
                                      residual, norm_f_w, out);
}

// Round 5
// 1048.427 us; speedup vs baseline: 1.6886x; 1.0388x over previous
//
#include <hip/hip_runtime.h>
#include <hip/hip_bf16.h>
#include <math.h>

// ---------------- constants ----------------
#define D_MODEL   768
#define N_LAYER   8
#define D_INNER   1536
#define D_STATE   128
#define HEADDIM   64
#define NHEADS    24
#define CONV_DIM  1792
#define D_IN_PROJ 3352
#define AH        8
#define AD        64
#define AINNER    512
#define BSZ       2
#define SEQ       512
#define LC        64
#define ROWS      (BSZ*SEQ)          // 1024
#define NCHUNK    8
#define CT        64                 // chunk length
#define NP1       3456               // 3352 padded to 27*128
#define AFF       4608

typedef __attribute__((ext_vector_type(8))) short bf16x8;
typedef __attribute__((ext_vector_type(4))) float f32x4;
typedef __attribute__((ext_vector_type(8))) unsigned short u16x8;

__device__ __forceinline__ float siluf(float x) { return x / (1.f + expf(-x)); }

__device__ __forceinline__ unsigned short f2b(float x) {
    __hip_bfloat16 h = __float2bfloat16(x);
    return __builtin_bit_cast(unsigned short, h);
}
__device__ __forceinline__ float b2f(unsigned short u) {
    unsigned v = ((unsigned)u) << 16;
    return __builtin_bit_cast(float, v);
}

// async global->LDS 16B copy (wave-uniform base + lane*16 contiguity honored by callers)
__device__ __forceinline__ void gload16(const void* g, void* l) {
    __builtin_amdgcn_global_load_lds(
        (const __attribute__((address_space(1))) unsigned int*)g,
        (__attribute__((address_space(3))) unsigned int*)l,
        16, 0, 0);
}

// block-wide sum, 256 threads (4 waves)
__device__ __forceinline__ float block_sum_256(float v, float* s4) {
    #pragma unroll
    for (int o = 32; o > 0; o >>= 1) v += __shfl_down(v, o, 64);
    __syncthreads();
    if ((threadIdx.x & 63) == 0) s4[threadIdx.x >> 6] = v;
    __syncthreads();
    return s4[0] + s4[1] + s4[2] + s4[3];
}

// ---------------- fused preamble: f2b + silumean + ada init + ALL weight transposes ----
// segments: [0,96) ref f2b; [96,102) silumean; [102,390) ada init;
// transposes (64x128 tiles, 8 float4 loads/thread, ushort8 stores):
// [390,2982) in_w; [2982,4134) out_w; [4134,5286) q/k/v; [5286,5670) o_w.
__global__ void k_prep(const float* __restrict__ ref_emb, unsigned short* __restrict__ ref_bf,
                       float* __restrict__ smc, const float* __restrict__ adab,
                       float* __restrict__ aff_all,
                       const float* __restrict__ in_w, const float* __restrict__ out_w,
                       const float* __restrict__ qw, const float* __restrict__ kw,
                       const float* __restrict__ vw, const float* __restrict__ ow,
                       unsigned short* __restrict__ in_wt, unsigned short* __restrict__ out_wt,
                       unsigned short* __restrict__ qwt, unsigned short* __restrict__ kwt,
                       unsigned short* __restrict__ vwt, unsigned short* __restrict__ owt) {
    int blk = blockIdx.x, t = threadIdx.x;
    if (blk < 96) {                               // ref f2b, vectorized x4
        int i4 = blk * 256 + t;
        float4 v = *(const float4*)&ref_emb[(size_t)i4 * 4];
        ushort4 o; o.x = f2b(v.x); o.y = f2b(v.y); o.z = f2b(v.z); o.w = f2b(v.w);
        *(ushort4*)&ref_bf[(size_t)i4 * 4] = o;
        return;
    }
    if (blk < 102) {                              // silu(mean(cond,1))
        int i = (blk - 96) * 256 + t;
        if (i < BSZ * D_MODEL) {
            int b = i / D_MODEL, d = i % D_MODEL;
            const float* p = ref_emb + (size_t)b * LC * D_MODEL + d;
            float s = 0.f;
            #pragma unroll 4
            for (int l = 0; l < LC; l++) s += p[l * D_MODEL];
            smc[i] = siluf(s * (1.f / (float)LC));
        }
        return;
    }
    if (blk < 390) {                              // aff init with bias
        int i = (blk - 102) * 256 + t;
        int j = i % AFF; int l = (i / AFF) >> 1;
        aff_all[i] = adab[l * AFF + j];
        return;
    }
    const float* src; unsigned short* dst; int K, N, n0, k0;
    int u = blk - 390;
    if (u < 2592) {                               // in_w: K=768, N=3352 (pad 3456)
        int z = u / 324, rem = u % 324;
        k0 = (rem / 27) * 64; n0 = (rem % 27) * 128;
        src = in_w + (size_t)z * 768 * 3352; dst = in_wt + (size_t)z * 3456 * 768;
        K = 768; N = 3352;
    } else if (u < 3744) {                        // out_w: K=1536, N=768
        u -= 2592; int z = u / 144, rem = u % 144;
        k0 = (rem / 6) * 64; n0 = (rem % 6) * 128;
        src = out_w + (size_t)z * 1536 * 768; dst = out_wt + (size_t)z * 768 * 1536;
        K = 1536; N = 768;
    } else if (u < 4896) {                        // q/k/v: K=768, N=512
        u -= 3744; int z = u / 48, rem = u % 48;
        k0 = (rem / 4) * 64; n0 = (rem % 4) * 128;
        int which = z >> 3, layer = z & 7;
        src = (which == 0 ? qw : which == 1 ? kw : vw) + (size_t)layer * 768 * 512;
        dst = (which == 0 ? qwt : which == 1 ? kwt : vwt) + (size_t)layer * 512 * 768;
        K = 768; N = 512;
    } else {                                      // o_w: K=512, N=768
        u -= 4896; int z = u / 48, rem = u % 48;
        k0 = (rem / 6) * 64; n0 = (rem % 6) * 128;
        src = ow + (size_t)z * 512 * 768; dst = owt + (size_t)z * 768 * 512;
        K = 512; N = 768;
    }
    __shared__ float tile[64][129];
    // read: 64 rows x 128 cols, 8 independent float4 loads per thread
    #pragma unroll
    for (int p = 0; p < 8; p++) {
        int idx = p * 256 + t;
        int k = idx >> 5, cg = idx & 31;
        int n = n0 + cg * 4;
        float4 v = (float4){0.f, 0.f, 0.f, 0.f};
        if (n < N) v = *(const float4*)&src[(size_t)(k0 + k) * N + n];  // N%4==0: no straddle
        tile[k][cg * 4 + 0] = v.x; tile[k][cg * 4 + 1] = v.y;
        tile[k][cg * 4 + 2] = v.z; tile[k][cg * 4 + 3] = v.w;
    }
    __syncthreads();
    // write: 128 n-rows x 64 k, ushort8 (16B) stores
    #pragma unroll
    for (int p = 0; p < 4; p++) {
        int idx = p * 256 + t;
        int n = idx >> 3, kk = (idx & 7) * 8;
        u16x8 o;
        #pragma unroll
        for (int e = 0; e < 8; e++) o[e] = f2b(tile[kk + e][n]);
        *(u16x8*)&dst[(size_t)(n0 + n) * K + k0 + kk] = o;
    }
}

// ---------------- merged K/V projection GEMM + ada split-K ----------------
// grid (18,1,80): z<16 -> kv gemm (x<4); z>=16 -> ada (l=(z-16)>>3, kc=(z-16)&7)
__global__ __launch_bounds__(256)
void k_kvada(const unsigned short* __restrict__ A, const unsigned short* __restrict__ Kwt,
             const unsigned short* __restrict__ Vwt, unsigned short* __restrict__ Kb,
             unsigned short* __restrict__ Vb,
             const float* __restrict__ smc, const float* __restrict__ adaw,
             float* __restrict__ aff_all) {
    int z = blockIdx.z;
    if (z >= 16) {
        int zz = z - 16; int l = zz >> 3, kc = zz & 7;
        int j = blockIdx.x * 256 + threadIdx.x;
        const float* w = adaw + (size_t)l * D_MODEL * AFF + j;
        const float* x0 = smc;
        const float* x1 = smc + D_MODEL;
        float s0 = 0.f, s1 = 0.f;
        int d0 = kc * 96;
        #pragma unroll 8
        for (int d = d0; d < d0 + 96; d++) {
            float wv = w[(size_t)d * AFF];
            s0 += x0[d] * wv; s1 += x1[d] * wv;
        }
        atomicAdd(&aff_all[(size_t)l * BSZ * AFF + j], s0);
        atomicAdd(&aff_all[(size_t)l * BSZ * AFF + AFF + j], s1);
        return;
    }
    if (blockIdx.x >= 4) return;
    int layer = z >> 1; int which = z & 1;
    const unsigned short* Bt = (which ? Vwt : Kwt) + (size_t)layer * AINNER * D_MODEL;
    unsigned short* C = (which ? Vb : Kb) + (size_t)layer * (BSZ * LC) * AINNER;
    __shared__ __align__(16) unsigned short As[128][32];
    __shared__ __align__(16) unsigned short Bs[128][32];
    int n0 = blockIdx.x * 128;
    int tid = threadIdx.x;
    int lane = tid & 63, wave = tid >> 6;
    int wm = (wave >> 1) * 64, wn = (wave & 1) * 64;
    int l15 = lane & 15, quad = lane >> 4;
    f32x4 acc[4][4];
    #pragma unroll
    for (int i = 0; i < 4; i++)
        #pragma unroll
        for (int j = 0; j < 4; j++) acc[i][j] = (f32x4){0.f, 0.f, 0.f, 0.f};
    int srow = tid >> 2, schunk = (tid & 3) * 8;
    for (int k0 = 0; k0 < D_MODEL; k0 += 32) {
        #pragma unroll
        for (int ps = 0; ps < 2; ps++) {
            int r = srow + ps * 64;
            gload16(&A[(size_t)r * D_MODEL + k0 + schunk], &As[r][schunk]);
            gload16(&Bt[(size_t)(n0 + r) * D_MODEL + k0 + schunk], &Bs[r][schunk]);
        }
        __syncthreads();
        bf16x8 af[4], bfr[4];
        #pragma unroll
        for (int i = 0; i < 4; i++) af[i]  = *(const bf16x8*)&As[wm + i * 16 + l15][quad * 8];
        #pragma unroll
        for (int j = 0; j < 4; j++) bfr[j] = *(const bf16x8*)&Bs[wn + j * 16 + l15][quad * 8];
        #pragma unroll
        for (int i = 0; i < 4; i++)
            #pragma unroll
            for (int j = 0; j < 4; j++)
                acc[i][j] = __builtin_amdgcn_mfma_f32_16x16x32_bf16(af[i], bfr[j], acc[i][j], 0, 0, 0);
        __syncthreads();
    }
    #pragma unroll
    for (int i = 0; i < 4; i++) {
        #pragma unroll
        for (int j = 0; j < 4; j++) {
            int col = n0 + wn + j * 16 + l15;
            #pragma unroll
            for (int r = 0; r < 4; r++) {
                int row = wm + i * 16 + quad * 4 + r;
                C[(size_t)row * AINNER + col] = f2b(acc[i][j][r]);
            }
        }
    }
}

// ---------------- split-K GEMM, double-buffered LDS + counted vmcnt (T3 min-2-phase) ----
__global__ __launch_bounds__(256)
void k_gemm_sk(const unsigned short* __restrict__ A, const unsigned short* __restrict__ Bt,
               float* __restrict__ C, int M, int N, int K, int Kc) {
    int z = blockIdx.z;
    C += (size_t)z * M * N;
    int kbeg = z * Kc;
    int kend = kbeg + Kc; if (kend > K) kend = K;
    int nt = (kend - kbeg) >> 5;
    __shared__ __align__(16) unsigned short As[2][128][32];
    __shared__ __align__(16) unsigned short Bs[2][128][32];
    int m0 = blockIdx.y * 128, n0 = blockIdx.x * 128;
    int tid = threadIdx.x;
    int lane = tid & 63, wave = tid >> 6;
    int wm = (wave >> 1) * 64, wn = (wave & 1) * 64;
    int l15 = lane & 15, quad = lane >> 4;
    f32x4 acc[4][4];
    #pragma unroll
    for (int i = 0; i < 4; i++)
        #pragma unroll
        for (int j = 0; j < 4; j++) acc[i][j] = (f32x4){0.f, 0.f, 0.f, 0.f};

    int srow = tid >> 2;
    int schunk = (tid & 3) * 8;

    #define STAGE_SK(buf, kk0)                                                        \
        do {                                                                          \
            _Pragma("unroll")                                                         \
            for (int ps = 0; ps < 2; ps++) {                                          \
                int r = srow + ps * 64;                                               \
                gload16(&A[(size_t)(m0 + r) * K + (kk0) + schunk], &As[buf][r][schunk]); \
                gload16(&Bt[(size_t)(n0 + r) * K + (kk0) + schunk], &Bs[buf][r][schunk]); \
            }                                                                         \
        } while (0)

    STAGE_SK(0, kbeg);
    int cur = 0;
    for (int it = 0; it < nt; ++it) {
        if (it + 1 < nt) {
            STAGE_SK(cur ^ 1, kbeg + (it + 1) * 32);
            asm volatile("s_waitcnt vmcnt(4)" ::: "memory");
        } else {
            asm volatile("s_waitcnt vmcnt(0)" ::: "memory");
        }
        __builtin_amdgcn_s_barrier();
        bf16x8 af[4], bfr[4];
        #pragma unroll
        for (int i = 0; i < 4; i++) af[i]  = *(const bf16x8*)&As[cur][wm + i * 16 + l15][quad * 8];
        #pragma unroll
        for (int j = 0; j < 4; j++) bfr[j] = *(const bf16x8*)&Bs[cur][wn + j * 16 + l15][quad * 8];
        #pragma unroll
        for (int i = 0; i < 4; i++)
            #pragma unroll
            for (int j = 0; j < 4; j++)
                acc[i][j] = __builtin_amdgcn_mfma_f32_16x16x32_bf16(af[i], bfr[j], acc[i][j], 0, 0, 0);
        __builtin_amdgcn_s_barrier();
        cur ^= 1;
    }
    #undef STAGE_SK
    #pragma unroll
    for (int i = 0; i < 4; i++) {
        #pragma unroll
        for (int j = 0; j < 4; j++) {
            int col = n0 + wn + j * 16 + l15;
            if (col < N) {
                #pragma unroll
                for (int r = 0; r < 4; r++) {
                    int row = m0 + wm + i * 16 + quad * 4 + r;
                    C[(size_t)row * N + col] = acc[i][j][r];
                }
            }
        }
    }
}

// ---------------- [fused prev-attn out (2 split-K partials)] + residual + rmsnorm + mod ----
__global__ void k_addrmsmod(const float* __restrict__ hin, const float* __restrict__ raw,
                            const float* __restrict__ bias, const float* __restrict__ affprev,
                            float* __restrict__ residual, const float* __restrict__ normw,
                            const float* __restrict__ affcur,
                            float* __restrict__ hidden_n, unsigned short* __restrict__ u,
                            int has_raw) {
    __shared__ float s4[4];
    const size_t PSTR = (size_t)ROWS * D_MODEL;
    int row = blockIdx.x;
    int b = row >> 9;
    const float* hp = hin + (size_t)row * D_MODEL;
    float* rp = residual + (size_t)row * D_MODEL;
    float v[3]; float ss = 0.f;
    #pragma unroll
    for (int j = 0; j < 3; j++) {
        int d = threadIdx.x + j * 256;
        float x = hp[d];
        if (has_raw) {
            float g = affprev[b * AFF + 3840 + d];
            float rawv = raw[(size_t)row * D_MODEL + d] + raw[PSTR + (size_t)row * D_MODEL + d];
            x += g * (rawv + bias[d]) + rp[d];
        }
        rp[d] = x; v[j] = x; ss += x * x;
    }
    ss = block_sum_256(ss, s4);
    float inv = rsqrtf(ss / (float)D_MODEL + 1e-5f);
    const float* sh = affcur + b * AFF;
    const float* sc = affcur + b * AFF + 768;
    #pragma unroll
    for (int j = 0; j < 3; j++) {
        int d = threadIdx.x + j * 256;
        float hn = v[j] * inv * normw[d];
        hidden_n[(size_t)row * D_MODEL + d] = hn;
        u[(size_t)row * D_MODEL + d] = f2b(hn * (1.f + sc[d]) + sh[d]);
    }
}

// ---------------- depthwise causal conv + silu -> bf16; softplus(dt) ----------------
// conv: 448 blocks, thread = 4 rows x 4 channels patch, float4 loads, taps reused in regs.
// dt: blocks [448,544).
__global__ void k_convdt(const float* __restrict__ zx, const float* __restrict__ convw,
                         const float* __restrict__ convb, const float* __restrict__ dtbias,
                         unsigned short* __restrict__ xBC, float* __restrict__ dtb) {
    const size_t PSTRZ = (size_t)ROWS * D_IN_PROJ;
    int blk = blockIdx.x, tid = threadIdx.x;
    if (blk >= 448) {                             // softplus(dt) segment, exact 24576
        int i = (blk - 448) * 256 + tid;
        int h = i % NHEADS; int row = i / NHEADS;
        size_t off = (size_t)row * D_IN_PROJ + D_INNER + CONV_DIM + h;
        float x = zx[off] + zx[off + PSTRZ] + dtbias[h];
        dtb[i] = (x > 20.f) ? x : log1pf(expf(x));
        return;
    }
    int g = blk * 256 + tid;                      // 114688 = 448ch-groups x 256row-groups
    int cg = g % 448, rg = g / 448;
    int c0 = cg * 4, row0 = rg * 4;
    int l0 = row0 & 511;                          // pos in sequence (4-aligned, no b-crossing)
    size_t rowbase = (size_t)row0 * D_IN_PROJ + D_INNER + c0;
    float rr[7][4];
    #pragma unroll
    for (int k = 0; k < 7; k++) {
        int tpos = l0 - 3 + k;
        if (tpos >= 0) {
            size_t idx = rowbase + (size_t)(k - 3) * D_IN_PROJ;
            float4 a = *(const float4*)&zx[idx];
            float4 b4 = *(const float4*)&zx[idx + PSTRZ];
            rr[k][0] = a.x + b4.x; rr[k][1] = a.y + b4.y;
            rr[k][2] = a.z + b4.z; rr[k][3] = a.w + b4.w;
        } else {
            rr[k][0] = rr[k][1] = rr[k][2] = rr[k][3] = 0.f;
        }
    }
    float4 w0 = *(const float4*)&convw[(size_t)c0 * 4];
    float4 w1 = *(const float4*)&convw[(size_t)(c0 + 1) * 4];
    float4 w2 = *(const float4*)&convw[(size_t)(c0 + 2) * 4];
    float4 w3 = *(const float4*)&convw[(size_t)(c0 + 3) * 4];
    float4 bb = *(const float4*)&convb[c0];
    #pragma unroll
    for (int r = 0; r < 4; r++) {
        ushort4 o;
        float a0 = bb.x + w0.x * rr[r][0] + w0.y * rr[r + 1][0] + w0.z * rr[r + 2][0] + w0.w * rr[r + 3][0];
        float a1 = bb.y + w1.x * rr[r][1] + w1.y * rr[r + 1][1] + w1.z * rr[r + 2][1] + w1.w * rr[r + 3][1];
        float a2 = bb.z + w2.x * rr[r][2] + w2.y * rr[r + 1][2] + w2.z * rr[r + 2][2] + w2.w * rr[r + 3][2];
        float a3 = bb.w + w3.x * rr[r][3] + w3.y * rr[r + 1][3] + w3.z * rr[r + 2][3] + w3.w * rr[r + 3][3];
        o.x = f2b(siluf(a0)); o.y = f2b(siluf(a1));
        o.z = f2b(siluf(a2)); o.w = f2b(siluf(a3));
        *(ushort4*)&xBC[(size_t)(row0 + r) * CONV_DIM + c0] = o;
    }
}

// ---------------- SSM K1: chunk-parallel (grid = NCHUNK x B*H), xBC bf16 ----------------
__global__ __launch_bounds__(256)
void k_ssm_par(const unsigned short* __restrict__ xBC, const float* __restrict__ dtb,
               const float* __restrict__ Alog, const float* __restrict__ Dssm,
               float* __restrict__ y, unsigned short* __restrict__ Sbuf,
               float* __restrict__ Pbuf) {
    __shared__ unsigned short sB[64][136];    // [t][n]
    __shared__ unsigned short sC[64][136];    // [t][n]
    __shared__ unsigned short sXT[64][72];    // [p][t]
    __shared__ unsigned short sG[64][72];     // G[i][s]; reused as XwT [p][t]
    __shared__ unsigned short sBT[128][72];   // [n][t]
    __shared__ float sL[64], sDt[64];
    int c = blockIdx.x, bh = blockIdx.y;
    int h = bh % NHEADS, b = bh / NHEADS;
    int tid = threadIdx.x;
    int lane = tid & 63, wave = tid >> 6;
    int l15 = lane & 15, quad = lane >> 4;
    int r = tid >> 2, q4 = tid & 3;
    int base = b * SEQ + c * CT;
    float a_h = expf(Alog[h]);
    float Dh = Dssm[h];
    if (tid < 64) {
        float dt = dtb[(base + tid) * NHEADS + h];
        float v = -a_h * dt;
        #pragma unroll
        for (int off = 1; off < 64; off <<= 1) {
            float u2 = __shfl_up(v, off, 64);
            if (tid >= off) v += u2;
        }
        sL[tid] = v; sDt[tid] = dt;
    }
    const unsigned short* xrow = xBC + (size_t)(base + r) * CONV_DIM;
    #pragma unroll
    for (int j = 0; j < 4; j++) {
        int n0 = q4 * 32 + j * 8;
        uint4 v = *(const uint4*)&xrow[D_INNER + n0];
        *(uint4*)&sB[r][n0] = v;
        const unsigned short* hv = (const unsigned short*)&v;
        #pragma unroll
        for (int e = 0; e < 8; e++) sBT[n0 + e][r] = hv[e];
        uint4 w = *(const uint4*)&xrow[D_INNER + D_STATE + n0];
        *(uint4*)&sC[r][n0] = w;
    }
    #pragma unroll
    for (int j = 0; j < 2; j++) {
        int p0 = q4 * 16 + j * 8;
        uint4 v = *(const uint4*)&xrow[h * HEADDIM + p0];
        const unsigned short* hv = (const unsigned short*)&v;
        #pragma unroll
        for (int e = 0; e < 8; e++) sXT[p0 + e][r] = hv[e];
    }
    __syncthreads();
    if (tid == 0) Pbuf[bh * NCHUNK + c] = expf(sL[63]);

    // acc1 = C·B^T  (CB[t][s])
    f32x4 acc1[4];
    #pragma unroll
    for (int j = 0; j < 4; j++) acc1[j] = (f32x4){0.f, 0.f, 0.f, 0.f};
    #pragma unroll
    for (int k0 = 0; k0 < 4; k0++) {
        bf16x8 a = *(const bf16x8*)&sC[wave * 16 + l15][k0 * 32 + quad * 8];
        #pragma unroll
        for (int nt = 0; nt < 4; nt++) {
            bf16x8 bv = *(const bf16x8*)&sB[nt * 16 + l15][k0 * 32 + quad * 8];
            acc1[nt] = __builtin_amdgcn_mfma_f32_16x16x32_bf16(a, bv, acc1[nt], 0, 0, 0);
        }
    }
    // G[i][s] = causal mask * CB * exp(L_i - L_s) * dt_s
    #pragma unroll
    for (int nt = 0; nt < 4; nt++) {
        int s = nt * 16 + l15;
        float Ls = sL[s], dts = sDt[s];
        #pragma unroll
        for (int rr = 0; rr < 4; rr++) {
            int i = wave * 16 + quad * 4 + rr;
            float g = (s <= i) ? acc1[nt][rr] * expf(sL[i] - Ls) * dts : 0.f;
            sG[i][s] = f2b(g);
        }
    }
    __syncthreads();

    // acc2 = G·X^T ; y_partial write (+ D·x)
    f32x4 acc2[4];
    #pragma unroll
    for (int j = 0; j < 4; j++) acc2[j] = (f32x4){0.f, 0.f, 0.f, 0.f};
    #pragma unroll
    for (int k0 = 0; k0 < 2; k0++) {
        bf16x8 a = *(const bf16x8*)&sG[wave * 16 + l15][k0 * 32 + quad * 8];
        #pragma unroll
        for (int nt = 0; nt < 4; nt++) {
            bf16x8 bv = *(const bf16x8*)&sXT[nt * 16 + l15][k0 * 32 + quad * 8];
            acc2[nt] = __builtin_amdgcn_mfma_f32_16x16x32_bf16(a, bv, acc2[nt], 0, 0, 0);
        }
    }
    #pragma unroll
    for (int nt = 0; nt < 4; nt++) {
        int p = nt * 16 + l15;
        #pragma unroll
        for (int rr = 0; rr < 4; rr++) {
            int i = wave * 16 + quad * 4 + rr;
            float xv = b2f(sXT[p][i]);
            y[(size_t)(base + i) * D_INNER + h * HEADDIM + p] = acc2[nt][rr] + Dh * xv;
        }
    }
    __syncthreads();
    // XwT[p][t] = X[t][p] * exp(Lend - L_t) * dt_t  (reuse sG)
    {
        float wr2 = expf(sL[63] - sL[r]) * sDt[r];
        #pragma unroll
        for (int j = 0; j < 16; j++) {
            int pp = q4 * 16 + j;
            sG[pp][r] = f2b(b2f(sXT[pp][r]) * wr2);
        }
    }
    __syncthreads();
    // S[p][n] = Xw·B -> Sbuf bf16
    f32x4 accS[8];
    #pragma unroll
    for (int j = 0; j < 8; j++) accS[j] = (f32x4){0.f, 0.f, 0.f, 0.f};
    #pragma unroll
    for (int k0 = 0; k0 < 2; k0++) {
        bf16x8 a = *(const bf16x8*)&sG[wave * 16 + l15][k0 * 32 + quad * 8];
        #pragma unroll
        for (int nt = 0; nt < 8; nt++) {
            bf16x8 bv = *(const bf16x8*)&sBT[nt * 16 + l15][k0 * 32 + quad * 8];
            accS[nt] = __builtin_amdgcn_mfma_f32_16x16x32_bf16(a, bv, accS[nt], 0, 0, 0);
        }
    }
    unsigned short* sout = Sbuf + ((size_t)bh * NCHUNK + c) * 8192;
    #pragma unroll
    for (int nt = 0; nt < 8; nt++) {
        int n = nt * 16 + l15;
        #pragma unroll
        for (int rr = 0; rr < 4; rr++) {
            int p = wave * 16 + quad * 4 + rr;
            sout[p * 128 + n] = f2b(accS[nt][rr]);
        }
    }
}

// ---------------- SSM K2: h-contribution, chunk-parallel (grid = (NCHUNK-1) x B*H) ------
__global__ __launch_bounds__(256)
void k_ssm_fix(const unsigned short* __restrict__ xBC, const float* __restrict__ dtb,
               const float* __restrict__ Alog, const unsigned short* __restrict__ Sbuf,
               const float* __restrict__ Pbuf, float* __restrict__ y) {
    __shared__ unsigned short sC[64][136];    // C~ = C * exp(L_t)
    __shared__ unsigned short sHB[64][136];   // h_start bf16 [p][n]
    __shared__ float sL[64];
    int c = blockIdx.x + 1, bh = blockIdx.y;
    int h = bh % NHEADS, b = bh / NHEADS;
    int tid = threadIdx.x;
    int lane = tid & 63, wave = tid >> 6;
    int l15 = lane & 15, quad = lane >> 4;
    int r = tid >> 2, q4 = tid & 3;
    int base = b * SEQ + c * CT;
    if (tid < 64) {
        float dt = dtb[(base + tid) * NHEADS + h];
        float v = -expf(Alog[h]) * dt;
        #pragma unroll
        for (int off = 1; off < 64; off <<= 1) {
            float u2 = __shfl_up(v, off, 64);
            if (tid >= off) v += u2;
        }
        sL[tid] = v;
    }
    // h_start: thread owns row p=r, cols [q4*32, q4*32+32)
    float hacc[32];
    #pragma unroll
    for (int e = 0; e < 32; e++) hacc[e] = 0.f;
    {
        const unsigned short* sp = Sbuf + (size_t)bh * NCHUNK * 8192 + r * 128 + q4 * 32;
        float w = 1.f;
        for (int j = c - 1; j >= 0; j--) {
            const unsigned short* srow = sp + (size_t)j * 8192;
            #pragma unroll
            for (int q = 0; q < 4; q++) {
                bf16x8 vv = *(const bf16x8*)&srow[q * 8];
                #pragma unroll
                for (int e = 0; e < 8; e++)
                    hacc[q * 8 + e] += w * b2f((unsigned short)vv[e]);
            }
            w *= Pbuf[bh * NCHUNK + j];
        }
    }
    __syncthreads();
    #pragma unroll
    for (int e = 0; e < 32; e++) sHB[r][q4 * 32 + e] = f2b(hacc[e]);
    {
        float el = expf(sL[r]);
        const unsigned short* xrow = xBC + (size_t)(base + r) * CONV_DIM + D_INNER + D_STATE;
        #pragma unroll
        for (int j = 0; j < 4; j++) {
            int n0 = q4 * 32 + j * 8;
            uint4 v = *(const uint4*)&xrow[n0];
            const unsigned short* hv = (const unsigned short*)&v;
            #pragma unroll
            for (int e = 0; e < 8; e++) sC[r][n0 + e] = f2b(b2f(hv[e]) * el);
        }
    }
    __syncthreads();
    // y[t][p] += sum_n C~[t][n] h[p][n]
    f32x4 acc[4];
    #pragma unroll
    for (int j = 0; j < 4; j++) acc[j] = (f32x4){0.f, 0.f, 0.f, 0.f};
    #pragma unroll
    for (int k0 = 0; k0 < 4; k0++) {
        bf16x8 a = *(const bf16x8*)&sC[wave * 16 + l15][k0 * 32 + quad * 8];
        #pragma unroll
        for (int nt = 0; nt < 4; nt++) {
            bf16x8 bv = *(const bf16x8*)&sHB[nt * 16 + l15][k0 * 32 + quad * 8];
            acc[nt] = __builtin_amdgcn_mfma_f32_16x16x32_bf16(a, bv, acc[nt], 0, 0, 0);
        }
    }
    #pragma unroll
    for (int nt = 0; nt < 4; nt++) {
        int p = nt * 16 + l15;
        #pragma unroll
        for (int rr = 0; rr < 4; rr++) {
            int i = wave * 16 + quad * 4 + rr;
            size_t idx = (size_t)(base + i) * D_INNER + h * HEADDIM + p;
            y[idx] += acc[nt][rr];
        }
    }
}

// ---------------- gated rmsnorm (z from 2 zx partials) -> bf16 ----------------
__global__ void k_gatednorm(const float* __restrict__ yscan, const float* __restrict__ zx,
                            const float* __restrict__ nw, unsigned short* __restrict__ out) {
    __shared__ float s4[4];
    const size_t PSTRZ = (size_t)ROWS * D_IN_PROJ;
    int row = blockIdx.x;
    const float* yp = yscan + (size_t)row * D_INNER;
    const float* zp0 = zx + (size_t)row * D_IN_PROJ;
    const float* zp1 = zp0 + PSTRZ;
    float v[6]; float ss = 0.f;
    #pragma unroll
    for (int j = 0; j < 6; j++) {
        int d = threadIdx.x + j * 256;
        float val = yp[d] * siluf(zp0[d] + zp1[d]);
        v[j] = val; ss += val * val;
    }
    ss = block_sum_256(ss, s4);
    float inv = rsqrtf(ss / (float)D_INNER + 1e-5f);
    #pragma unroll
    for (int j = 0; j < 6; j++) {
        int d = threadIdx.x + j * 256;
        out[(size_t)row * D_INNER + d] = f2b(v[j] * inv * nw[d]);
    }
}

// ---------------- hidden2 = hidden_n + g_mba*(Σ tmp partials + out_b); ln + msa mod ----
__global__ void k_fuse_ln(const float* __restrict__ hidden_n, const float* __restrict__ tmp,
                          const float* __restrict__ outb, const float* __restrict__ aff,
                          float* __restrict__ hidden2, unsigned short* __restrict__ attnx) {
    __shared__ float s4[4];
    const size_t PSTR = (size_t)ROWS * D_MODEL;
    int row = blockIdx.x;
    int b = row >> 9;
    const float* gm = aff + b * AFF + 1536;
    float v[3]; float s = 0.f;
    #pragma unroll
    for (int j = 0; j < 3; j++) {
        int d = threadIdx.x + j * 256;
        size_t idx = (size_t)row * D_MODEL + d;
        float t = tmp[idx] + tmp[idx + PSTR] + tmp[idx + 2 * PSTR] + tmp[idx + 3 * PSTR];
        float x = hidden_n[idx] + gm[d] * (t + outb[d]);
        hidden2[idx] = x;
        v[j] = x; s += x;
    }
    float mean = block_sum_256(s, s4) / (float)D_MODEL;
    float ss = 0.f;
    #pragma unroll
    for (int j = 0; j < 3; j++) { float c = v[j] - mean; ss += c * c; }
    float var = block_sum_256(ss, s4) / (float)D_MODEL;
    float inv = rsqrtf(var + 1e-6f);
    const float* sh = aff + b * AFF + 2304;
    const float* sc = aff + b * AFF + 3072;
    #pragma unroll
    for (int j = 0; j < 3; j++) {
        int d = threadIdx.x + j * 256;
        float xh = (v[j] - mean) * inv;
        attnx[(size_t)row * D_MODEL + d] = f2b(xh * (1.f + sc[d]) + sh[d]);
    }
}

// ---------------- cross-attention: fused Q-proj + MFMA QK^T + softmax + MFMA PV ---------
__global__ __launch_bounds__(256)
void k_attn(const unsigned short* __restrict__ attnx, const unsigned short* __restrict__ qwt,
            const unsigned short* __restrict__ kb, const unsigned short* __restrict__ vb,
            unsigned short* __restrict__ ob) {
    int blk = blockIdx.x;
    int lt = blk & 15; int h = (blk >> 4) & 7; int b = blk >> 7;
    __shared__ unsigned short sK[64][72];     // K [m][d]
    __shared__ unsigned short sVT[64][72];    // V^T [d][m]
    __shared__ unsigned short sA[32][136];
    __shared__ unsigned short sW[64][136];
    __shared__ unsigned short sQb[32][72];    // Q bf16 (pre-scaled)
    __shared__ unsigned short sP[32][72];     // softmax probs bf16
    int tid = threadIdx.x;
    // stage K rows + V transposed
    {
        int r = tid >> 2, c0 = (tid & 3) * 16;
        const unsigned short* kp = kb + (size_t)(b * LC + r) * AINNER + h * AD + c0;
        const unsigned short* vp = vb + (size_t)(b * LC + r) * AINNER + h * AD + c0;
        #pragma unroll
        for (int j = 0; j < 4; j++) {
            *(ushort4*)&sK[r][c0 + j * 4] = *(const ushort4*)&kp[j * 4];
            ushort4 vv = *(const ushort4*)&vp[j * 4];
            const unsigned short* hv = (const unsigned short*)&vv;
            #pragma unroll
            for (int e = 0; e < 4; e++) sVT[c0 + j * 4 + e][r] = hv[e];
        }
    }
    int lane = tid & 63, wave = tid >> 6;
    int l15 = lane & 15, quad = lane >> 4;
    int rt = wave >> 1, cp = (wave & 1) * 2;
    f32x4 accq[2];
    accq[0] = (f32x4){0.f, 0.f, 0.f, 0.f};
    accq[1] = (f32x4){0.f, 0.f, 0.f, 0.f};
    const size_t arow_base = (size_t)(b * SEQ + lt * 32) * D_MODEL;
    for (int k0 = 0; k0 < D_MODEL; k0 += 128) {
        __syncthreads();
        #pragma unroll
        for (int j = 0; j < 2; j++) {
            int s = tid + j * 256; int row = s >> 4, c8 = (s & 15) * 8;
            *(uint4*)&sA[row][c8] =
                *(const uint4*)&attnx[arow_base + (size_t)row * D_MODEL + k0 + c8];
        }
        #pragma unroll
        for (int j = 0; j < 4; j++) {
            int s = tid + j * 256; int row = s >> 4, c8 = (s & 15) * 8;
            *(uint4*)&sW[row][c8] =
                *(const uint4*)&qwt[(size_t)(h * AD + row) * D_MODEL + k0 + c8];
        }
        __syncthreads();
        #pragma unroll
        for (int ks = 0; ks < 4; ks++) {
            bf16x8 af = *(const bf16x8*)&sA[rt * 16 + l15][ks * 32 + quad * 8];
            #pragma unroll
            for (int j = 0; j < 2; j++) {
                bf16x8 bf = *(const bf16x8*)&sW[(cp + j) * 16 + l15][ks * 32 + quad * 8];
                accq[j] = __builtin_amdgcn_mfma_f32_16x16x32_bf16(af, bf, accq[j], 0, 0, 0);
            }
        }
    }
    // Q -> LDS bf16, scaled by 1/sqrt(AD)
    #pragma unroll
    for (int j = 0; j < 2; j++)
        #pragma unroll
        for (int rr = 0; rr < 4; rr++)
            sQb[rt * 16 + quad * 4 + rr][(cp + j) * 16 + l15] = f2b(accq[j][rr] * 0.125f);
    __syncthreads();
    // QK^T + softmax on waves 0,1 (qt = wave)
    if (wave < 2) {
        int qt = wave;
        f32x4 s[4];
        #pragma unroll
        for (int mt = 0; mt < 4; mt++) s[mt] = (f32x4){0.f, 0.f, 0.f, 0.f};
        #pragma unroll
        for (int k0 = 0; k0 < 2; k0++) {
            bf16x8 aq = *(const bf16x8*)&sQb[qt * 16 + l15][k0 * 32 + quad * 8];
            #pragma unroll
            for (int mt = 0; mt < 4; mt++) {
                bf16x8 bk = *(const bf16x8*)&sK[mt * 16 + l15][k0 * 32 + quad * 8];
                s[mt] = __builtin_amdgcn_mfma_f32_16x16x32_bf16(aq, bk, s[mt], 0, 0, 0);
            }
        }
        #pragma unroll
        for (int rr = 0; rr < 4; rr++) {
            float mx = fmaxf(fmaxf(s[0][rr], s[1][rr]), fmaxf(s[2][rr], s[3][rr]));
            #pragma unroll
            for (int off = 8; off > 0; off >>= 1) mx = fmaxf(mx, __shfl_xor(mx, off, 64));
            float e0 = expf(s[0][rr] - mx), e1 = expf(s[1][rr] - mx);
            float e2 = expf(s[2][rr] - mx), e3 = expf(s[3][rr] - mx);
            float sum = e0 + e1 + e2 + e3;
            #pragma unroll
            for (int off = 8; off > 0; off >>= 1) sum += __shfl_xor(sum, off, 64);
            float inv = 1.f / sum;
            int q = qt * 16 + quad * 4 + rr;
            sP[q][0 * 16 + l15] = f2b(e0 * inv);
            sP[q][1 * 16 + l15] = f2b(e1 * inv);
            sP[q][2 * 16 + l15] = f2b(e2 * inv);
            sP[q][3 * 16 + l15] = f2b(e3 * inv);
        }
    }
    __syncthreads();
    // PV: all 4 waves; qt = wave>>1, d-tile pair = (wave&1)*2
    {
        int qt = wave >> 1, dp = (wave & 1) * 2;
        f32x4 o[2];
        o[0] = (f32x4){0.f, 0.f, 0.f, 0.f};
        o[1] = (f32x4){0.f, 0.f, 0.f, 0.f};
        #pragma unroll
        for (int k0 = 0; k0 < 2; k0++) {
            bf16x8 ap = *(const bf16x8*)&sP[qt * 16 + l15][k0 * 32 + quad * 8];
            #pragma unroll
            for (int j = 0; j < 2; j++) {
                bf16x8 bv = *(const bf16x8*)&sVT[(dp + j) * 16 + l15][k0 * 32 + quad * 8];
                o[j] = __builtin_amdgcn_mfma_f32_16x16x32_bf16(ap, bv, o[j], 0, 0, 0);
            }
        }
        #pragma unroll
        for (int j = 0; j < 2; j++) {
            int d = (dp + j) * 16 + l15;
            #pragma unroll
            for (int rr = 0; rr < 4; rr++) {
                int q = qt * 16 + quad * 4 + rr;
                ob[(size_t)(b * SEQ + lt * 32 + q) * AINNER + h * AD + d] = f2b(o[j][rr]);
            }
        }
    }
}

// ---------------- final: h = hidden2 + g*(Σ raw partials + bias); rmsnorm(h + r) --------
__global__ void k_final(const float* __restrict__ hidden2, const float* __restrict__ raw,
                        const float* __restrict__ bias, const float* __restrict__ aff,
                        const float* __restrict__ residual, const float* __restrict__ w,
                        float* __restrict__ out) {
    __shared__ float s4[4];
    const size_t PSTR = (size_t)ROWS * D_MODEL;
    int row = blockIdx.x;
    int b = row >> 9;
    const float* gm = aff + b * AFF + 3840;
    float v[3]; float ss = 0.f;
    #pragma unroll
    for (int j = 0; j < 3; j++) {
        int d = threadIdx.x + j * 256;
        size_t idx = (size_t)row * D_MODEL + d;
        float rawv = raw[idx] + raw[idx + PSTR];
        float x = hidden2[idx] + gm[d] * (rawv + bias[d]) + residual[idx];
        v[j] = x; ss += x * x;
    }
    ss = block_sum_256(ss, s4);
    float inv = rsqrtf(ss / (float)D_MODEL + 1e-5f);
    #pragma unroll
    for (int j = 0; j < 3; j++) {
        int d = threadIdx.x + j * 256;
        out[(size_t)row * D_MODEL + d] = v[j] * inv * w[d];
    }
}

// ---------------- host launch ----------------
extern "C" void kernel_launch(void* const* d_in, const int* in_sizes, int n_in,
                              void* d_out, int out_size, void* d_ws, size_t ws_size,
                              hipStream_t stream) {
    const float* hidden_states = (const float*)d_in[0];
    const float* ref_emb  = (const float*)d_in[1];
    const float* norm_w   = (const float*)d_in[2];
    const float* ada_w    = (const float*)d_in[3];
    const float* ada_b    = (const float*)d_in[4];
    const float* in_w     = (const float*)d_in[5];
    const float* conv_w   = (const float*)d_in[6];
    const float* conv_b   = (const float*)d_in[7];
    const float* dt_bias  = (const float*)d_in[8];
    const float* A_log    = (const float*)d_in[9];
    const float* D_ssm    = (const float*)d_in[10];
    const float* ssm_nw   = (const float*)d_in[11];
    const float* out_w    = (const float*)d_in[12];
    const float* out_b    = (const float*)d_in[13];
    const float* q_w      = (const float*)d_in[14];
    const float* k_w      = (const float*)d_in[15];
    const float* v_w      = (const float*)d_in[16];
    const float* o_w      = (const float*)d_in[17];
    const float* o_b      = (const float*)d_in[18];
    const float* norm_f_w = (const float*)d_in[19];
    float* out = (float*)d_out;

    char* p = (char*)d_ws;
    auto alloc = [&](size_t bytes) -> char* {
        char* r = p; p += (bytes + 255) & ~(size_t)255; return r;
    };
    float* residual = (float*)alloc((size_t)ROWS * D_MODEL * 4);
    float* hidden2  = (float*)alloc((size_t)ROWS * D_MODEL * 4);
    float* hidden_n = (float*)alloc((size_t)ROWS * D_MODEL * 4);
    float* tmpM     = (float*)alloc((size_t)4 * ROWS * D_MODEL * 4);  // out-proj partials
    float* tmpO     = (float*)alloc((size_t)2 * ROWS * D_MODEL * 4);  // o-proj partials
    float* zx       = (float*)alloc((size_t)2 * ROWS * D_IN_PROJ * 4); // in-proj partials
    float* dtb      = (float*)alloc((size_t)ROWS * NHEADS * 4);
    float* yscan    = (float*)alloc((size_t)ROWS * D_INNER * 4);
    float* aff_all  = (float*)alloc((size_t)N_LAYER * BSZ * AFF * 4);
    float* smc      = (float*)alloc((size_t)BSZ * D_MODEL * 4);
    float* Pbuf     = (float*)alloc((size_t)BSZ * NHEADS * NCHUNK * 4);
    unsigned short* xBC    = (unsigned short*)alloc((size_t)ROWS * CONV_DIM * 2);
    unsigned short* Sbuf   = (unsigned short*)alloc((size_t)BSZ * NHEADS * NCHUNK * 8192 * 2);
    unsigned short* u_bf   = (unsigned short*)alloc((size_t)ROWS * D_MODEL * 2);
    unsigned short* ynorm  = (unsigned short*)alloc((size_t)ROWS * D_INNER * 2);
    unsigned short* attnx  = (unsigned short*)alloc((size_t)ROWS * D_MODEL * 2);
    unsigned short* ob     = (unsigned short*)alloc((size_t)ROWS * AINNER * 2);
    unsigned short* ref_bf = (unsigned short*)alloc((size_t)BSZ * LC * D_MODEL * 2);
    unsigned short* kb_all  = (unsigned short*)alloc((size_t)N_LAYER * BSZ * LC * AINNER * 2);
    unsigned short* vb_all  = (unsigned short*)alloc((size_t)N_LAYER * BSZ * LC * AINNER * 2);
    unsigned short* in_wt_all  = (unsigned short*)alloc((size_t)N_LAYER * NP1 * D_MODEL * 2);
    unsigned short* out_wt_all = (unsigned short*)alloc((size_t)N_LAYER * D_MODEL * D_INNER * 2);
    unsigned short* q_wt_all   = (unsigned short*)alloc((size_t)N_LAYER * AINNER * D_MODEL * 2);
    unsigned short* o_wt_all   = (unsigned short*)alloc((size_t)N_LAYER * D_MODEL * AINNER * 2);
    unsigned short* kwt_all = (unsigned short*)alloc((size_t)N_LAYER * AINNER * D_MODEL * 2);
    unsigned short* vwt_all = (unsigned short*)alloc((size_t)N_LAYER * AINNER * D_MODEL * 2);

    k_prep<<<5670, 256, 0, stream>>>(ref_emb, ref_bf, smc, ada_b, aff_all,
                                     in_w, out_w, q_w, k_w, v_w, o_w,
                                     in_wt_all, out_wt_all, q_wt_all, kwt_all, vwt_all,
                                     o_wt_all);
    k_kvada<<<dim3(18, 1, 80), 256, 0, stream>>>(ref_bf, kwt_all, vwt_all, kb_all, vb_all,
                                                 smc, ada_w, aff_all);

    for (int layer = 0; layer < N_LAYER; layer++) {
        const float* L_norm_w  = norm_w  + layer * D_MODEL;
        const float* L_conv_w  = conv_w  + layer * CONV_DIM * 4;
        const float* L_conv_b  = conv_b  + layer * CONV_DIM;
        const float* L_dt_bias = dt_bias + layer * NHEADS;
        const float* L_A_log   = A_log   + layer * NHEADS;
        const float* L_D_ssm   = D_ssm   + layer * NHEADS;
        const float* L_ssm_nw  = ssm_nw  + layer * D_INNER;
        const float* L_out_b   = out_b   + layer * D_MODEL;
        const float* L_o_b_prev= o_b     + (layer - 1) * D_MODEL;
        const float* L_aff     = aff_all + (size_t)layer * BSZ * AFF;
        const float* L_aff_prev= aff_all + (size_t)(layer - 1) * BSZ * AFF;
        const unsigned short* in_wt  = in_wt_all  + (size_t)layer * NP1 * D_MODEL;
        const unsigned short* out_wt = out_wt_all + (size_t)layer * D_MODEL * D_INNER;
        const unsigned short* q_wt   = q_wt_all   + (size_t)layer * AINNER * D_MODEL;
        const unsigned short* o_wt   = o_wt_all   + (size_t)layer * D_MODEL * AINNER;

        k_addrmsmod<<<ROWS, 256, 0, stream>>>(
            layer == 0 ? hidden_states : hidden2, tmpO,
            layer == 0 ? o_b : L_o_b_prev,
            layer == 0 ? aff_all : L_aff_prev,
            residual, L_norm_w, L_aff, hidden_n, u_bf, layer == 0 ? 0 : 1);
        k_gemm_sk<<<dim3(NP1 / 128, ROWS / 128, 2), 256, 0, stream>>>(u_bf, in_wt, zx, ROWS, D_IN_PROJ, D_MODEL, 384);
        k_convdt<<<544, 256, 0, stream>>>(zx, L_conv_w, L_conv_b, L_dt_bias, xBC, dtb);
        k_ssm_par<<<dim3(NCHUNK, BSZ * NHEADS), 256, 0, stream>>>(xBC, dtb, L_A_log, L_D_ssm, yscan, Sbuf, Pbuf);
        k_ssm_fix<<<dim3(NCHUNK - 1, BSZ * NHEADS), 256, 0, stream>>>(xBC, dtb, L_A_log, Sbuf, Pbuf, yscan);
        k_gatednorm<<<ROWS, 256, 0, stream>>>(yscan, zx, L_ssm_nw, ynorm);
        k_gemm_sk<<<dim3(D_MODEL / 128, ROWS / 128, 4), 256, 0, stream>>>(ynorm, out_wt, tmpM, ROWS, D_MODEL, D_INNER, 384);
        k_fuse_ln<<<ROWS, 256, 0, stream>>>(hidden_n, tmpM, L_out_b, L_aff, hidden2, attnx);
        k_attn<<<BSZ * AH * 16, 256, 0, stream>>>(
            attnx, q_wt,
            kb_all + (size_t)layer * BSZ * LC * AINNER,
            vb_all + (size_t)layer * BSZ * LC * AINNER, ob);
        k_gemm_sk<<<dim3(D_MODEL / 128, ROWS / 128, 2), 256, 0, stream>>>(ob, o_wt, tmpO, ROWS, D_MODEL, AINNER, 256);
    }
    k_final<<<ROWS, 256, 0, stream>>>(hidden2, tmpO, o_b + (N_LAYER - 1) * D_MODEL,
                                      aff_all + (size_t)(N_LAYER - 1) * BSZ * AFF,
                                      residual, norm_f_w, out);
}

// Round 6
// 1034.064 us; speedup vs baseline: 1.7121x; 1.0139x over previous
//
#include <hip/hip_runtime.h>
#include <hip/hip_bf16.h>
#include <math.h>

// ---------------- constants ----------------
#define D_MODEL   768
#define N_LAYER   8
#define D_INNER   1536
#define D_STATE   128
#define HEADDIM   64
#define NHEADS    24
#define CONV_DIM  1792
#define D_IN_PROJ 3352
#define AH        8
#define AD        64
#define AINNER    512
#define BSZ       2
#define SEQ       512
#define LC        64
#define ROWS      (BSZ*SEQ)          // 1024
#define NCHUNK    8
#define CT        64                 // chunk length
#define NP1       3456               // 3352 padded to 27*128
#define AFF       4608

typedef __attribute__((ext_vector_type(8))) short bf16x8;
typedef __attribute__((ext_vector_type(4))) float f32x4;
typedef __attribute__((ext_vector_type(8))) unsigned short u16x8;

__device__ __forceinline__ float siluf(float x) { return x / (1.f + expf(-x)); }

__device__ __forceinline__ unsigned short f2b(float x) {
    __hip_bfloat16 h = __float2bfloat16(x);
    return __builtin_bit_cast(unsigned short, h);
}
__device__ __forceinline__ float b2f(unsigned short u) {
    unsigned v = ((unsigned)u) << 16;
    return __builtin_bit_cast(float, v);
}

// async global->LDS 16B copy (wave-uniform base + lane*16 contiguity honored by callers)
__device__ __forceinline__ void gload16(const void* g, void* l) {
    __builtin_amdgcn_global_load_lds(
        (const __attribute__((address_space(1))) unsigned int*)g,
        (__attribute__((address_space(3))) unsigned int*)l,
        16, 0, 0);
}

// block-wide sum, 256 threads (4 waves)
__device__ __forceinline__ float block_sum_256(float v, float* s4) {
    #pragma unroll
    for (int o = 32; o > 0; o >>= 1) v += __shfl_down(v, o, 64);
    __syncthreads();
    if ((threadIdx.x & 63) == 0) s4[threadIdx.x >> 6] = v;
    __syncthreads();
    return s4[0] + s4[1] + s4[2] + s4[3];
}

// ---------------- fused preamble: f2b + silumean + ada init + ALL weight transposes ----
// segments: [0,48) ref f2b x8; [48,54) silumean; [54,342) ada init;
// transposes (64x64 tiles, 4x float4 loads, 2x ushort8 stores):
// [342,5430) in_w; [5430,7734) out_w; [7734,10038) q/k/v; [10038,10806) o_w.
__global__ void k_prep(const float* __restrict__ ref_emb, unsigned short* __restrict__ ref_bf,
                       float* __restrict__ smc, const float* __restrict__ adab,
                       float* __restrict__ aff_all,
                       const float* __restrict__ in_w, const float* __restrict__ out_w,
                       const float* __restrict__ qw, const float* __restrict__ kw,
                       const float* __restrict__ vw, const float* __restrict__ ow,
                       unsigned short* __restrict__ in_wt, unsigned short* __restrict__ out_wt,
                       unsigned short* __restrict__ qwt, unsigned short* __restrict__ kwt,
                       unsigned short* __restrict__ vwt, unsigned short* __restrict__ owt) {
    int blk = blockIdx.x, t = threadIdx.x;
    if (blk < 48) {                               // ref f2b, vectorized x8
        int i8 = blk * 256 + t;
        float4 a = *(const float4*)&ref_emb[(size_t)i8 * 8];
        float4 b4 = *(const float4*)&ref_emb[(size_t)i8 * 8 + 4];
        u16x8 o;
        o[0] = f2b(a.x); o[1] = f2b(a.y); o[2] = f2b(a.z); o[3] = f2b(a.w);
        o[4] = f2b(b4.x); o[5] = f2b(b4.y); o[6] = f2b(b4.z); o[7] = f2b(b4.w);
        *(u16x8*)&ref_bf[(size_t)i8 * 8] = o;
        return;
    }
    if (blk < 54) {                               // silu(mean(cond,1))
        int i = (blk - 48) * 256 + t;
        if (i < BSZ * D_MODEL) {
            int b = i / D_MODEL, d = i % D_MODEL;
            const float* p = ref_emb + (size_t)b * LC * D_MODEL + d;
            float s = 0.f;
            #pragma unroll 4
            for (int l = 0; l < LC; l++) s += p[l * D_MODEL];
            smc[i] = siluf(s * (1.f / (float)LC));
        }
        return;
    }
    if (blk < 342) {                              // aff init with bias
        int i = (blk - 54) * 256 + t;
        int j = i % AFF; int l = (i / AFF) >> 1;
        aff_all[i] = adab[l * AFF + j];
        return;
    }
    const float* src; unsigned short* dst; int K, N, n0, k0;
    int u = blk - 342;
    if (u < 5088) {                               // in_w: K=768, N=3352 (pad 3456)
        int z = u / 636, rem = u % 636;
        k0 = (rem / 53) * 64; n0 = (rem % 53) * 64;
        src = in_w + (size_t)z * 768 * 3352; dst = in_wt + (size_t)z * 3456 * 768;
        K = 768; N = 3352;
    } else if (u < 7392) {                        // out_w: K=1536, N=768
        u -= 5088; int z = u / 288, rem = u % 288;
        k0 = (rem / 12) * 64; n0 = (rem % 12) * 64;
        src = out_w + (size_t)z * 1536 * 768; dst = out_wt + (size_t)z * 768 * 1536;
        K = 1536; N = 768;
    } else if (u < 9696) {                        // q/k/v: K=768, N=512
        u -= 7392; int z = u / 96, rem = u % 96;
        k0 = (rem / 8) * 64; n0 = (rem % 8) * 64;
        int which = z >> 3, layer = z & 7;
        src = (which == 0 ? qw : which == 1 ? kw : vw) + (size_t)layer * 768 * 512;
        dst = (which == 0 ? qwt : which == 1 ? kwt : vwt) + (size_t)layer * 512 * 768;
        K = 768; N = 512;
    } else {                                      // o_w: K=512, N=768
        u -= 9696; int z = u / 96, rem = u % 96;
        k0 = (rem / 12) * 64; n0 = (rem % 12) * 64;
        src = ow + (size_t)z * 512 * 768; dst = owt + (size_t)z * 768 * 512;
        K = 512; N = 768;
    }
    __shared__ float tile[64][65];
    // read: 64 rows x 64 cols, 4 independent float4 loads per thread
    #pragma unroll
    for (int p2 = 0; p2 < 4; p2++) {
        int idx = p2 * 256 + t;
        int k = idx >> 4, cg = idx & 15;
        int n = n0 + cg * 4;
        float4 v = (float4){0.f, 0.f, 0.f, 0.f};
        if (n < N) v = *(const float4*)&src[(size_t)(k0 + k) * N + n];  // N%4==0: no straddle
        tile[k][cg * 4 + 0] = v.x; tile[k][cg * 4 + 1] = v.y;
        tile[k][cg * 4 + 2] = v.z; tile[k][cg * 4 + 3] = v.w;
    }
    __syncthreads();
    // write: 64 n-rows x 64 k, ushort8 (16B) stores, 2 per thread
    #pragma unroll
    for (int p2 = 0; p2 < 2; p2++) {
        int idx = p2 * 256 + t;
        int n = idx >> 3, kk = (idx & 7) * 8;
        u16x8 o;
        #pragma unroll
        for (int e = 0; e < 8; e++) o[e] = f2b(tile[kk + e][n]);
        *(u16x8*)&dst[(size_t)(n0 + n) * K + k0 + kk] = o;
    }
}

// ---------------- merged K/V projection GEMM + ada split-K ----------------
// grid (18,1,80): z<16 -> kv gemm (x<4); z>=16 -> ada (l=(z-16)>>3, kc=(z-16)&7)
__global__ __launch_bounds__(256)
void k_kvada(const unsigned short* __restrict__ A, const unsigned short* __restrict__ Kwt,
             const unsigned short* __restrict__ Vwt, unsigned short* __restrict__ Kb,
             unsigned short* __restrict__ Vb,
             const float* __restrict__ smc, const float* __restrict__ adaw,
             float* __restrict__ aff_all) {
    int z = blockIdx.z;
    if (z >= 16) {
        int zz = z - 16; int l = zz >> 3, kc = zz & 7;
        int j = blockIdx.x * 256 + threadIdx.x;
        const float* w = adaw + (size_t)l * D_MODEL * AFF + j;
        const float* x0 = smc;
        const float* x1 = smc + D_MODEL;
        float s0 = 0.f, s1 = 0.f;
        int d0 = kc * 96;
        #pragma unroll 8
        for (int d = d0; d < d0 + 96; d++) {
            float wv = w[(size_t)d * AFF];
            s0 += x0[d] * wv; s1 += x1[d] * wv;
        }
        atomicAdd(&aff_all[(size_t)l * BSZ * AFF + j], s0);
        atomicAdd(&aff_all[(size_t)l * BSZ * AFF + AFF + j], s1);
        return;
    }
    if (blockIdx.x >= 4) return;
    int layer = z >> 1; int which = z & 1;
    const unsigned short* Bt = (which ? Vwt : Kwt) + (size_t)layer * AINNER * D_MODEL;
    unsigned short* C = (which ? Vb : Kb) + (size_t)layer * (BSZ * LC) * AINNER;
    __shared__ __align__(16) unsigned short As[128][32];
    __shared__ __align__(16) unsigned short Bs[128][32];
    int n0 = blockIdx.x * 128;
    int tid = threadIdx.x;
    int lane = tid & 63, wave = tid >> 6;
    int wm = (wave >> 1) * 64, wn = (wave & 1) * 64;
    int l15 = lane & 15, quad = lane >> 4;
    f32x4 acc[4][4];
    #pragma unroll
    for (int i = 0; i < 4; i++)
        #pragma unroll
        for (int j = 0; j < 4; j++) acc[i][j] = (f32x4){0.f, 0.f, 0.f, 0.f};
    int srow = tid >> 2, schunk = (tid & 3) * 8;
    for (int k0 = 0; k0 < D_MODEL; k0 += 32) {
        #pragma unroll
        for (int ps = 0; ps < 2; ps++) {
            int r = srow + ps * 64;
            gload16(&A[(size_t)r * D_MODEL + k0 + schunk], &As[r][schunk]);
            gload16(&Bt[(size_t)(n0 + r) * D_MODEL + k0 + schunk], &Bs[r][schunk]);
        }
        __syncthreads();
        bf16x8 af[4], bfr[4];
        #pragma unroll
        for (int i = 0; i < 4; i++) af[i]  = *(const bf16x8*)&As[wm + i * 16 + l15][quad * 8];
        #pragma unroll
        for (int j = 0; j < 4; j++) bfr[j] = *(const bf16x8*)&Bs[wn + j * 16 + l15][quad * 8];
        #pragma unroll
        for (int i = 0; i < 4; i++)
            #pragma unroll
            for (int j = 0; j < 4; j++)
                acc[i][j] = __builtin_amdgcn_mfma_f32_16x16x32_bf16(af[i], bfr[j], acc[i][j], 0, 0, 0);
        __syncthreads();
    }
    #pragma unroll
    for (int i = 0; i < 4; i++) {
        #pragma unroll
        for (int j = 0; j < 4; j++) {
            int col = n0 + wn + j * 16 + l15;
            #pragma unroll
            for (int r = 0; r < 4; r++) {
                int row = wm + i * 16 + quad * 4 + r;
                C[(size_t)row * AINNER + col] = f2b(acc[i][j][r]);
            }
        }
    }
}

// ---------------- split-K GEMM, double-buffered + counted vmcnt + XCD swizzle ----------
__global__ __launch_bounds__(256)
void k_gemm_sk(const unsigned short* __restrict__ A, const unsigned short* __restrict__ Bt,
               float* __restrict__ C, int M, int N, int K, int Kc) {
    // bijective XCD remap (m204): contiguous decoded ranges per XCD -> L2 panel reuse
    int gx = gridDim.x, gy = gridDim.y;
    int nwg = gx * gy * gridDim.z;
    int flat = (blockIdx.z * gy + blockIdx.y) * gx + blockIdx.x;
    int q = nwg >> 3, r8 = nwg & 7;
    int xcd = flat & 7, idx8 = flat >> 3;
    int swz = (xcd < r8 ? xcd * (q + 1) : r8 * (q + 1) + (xcd - r8) * q) + idx8;
    int bx = swz % gx; int t2 = swz / gx; int by = t2 % gy; int bz = t2 / gy;

    C += (size_t)bz * M * N;
    int kbeg = bz * Kc;
    int kend = kbeg + Kc; if (kend > K) kend = K;
    int nt = (kend - kbeg) >> 5;
    __shared__ __align__(16) unsigned short As[2][128][32];
    __shared__ __align__(16) unsigned short Bs[2][128][32];
    int m0 = by * 128, n0 = bx * 128;
    int tid = threadIdx.x;
    int lane = tid & 63, wave = tid >> 6;
    int wm = (wave >> 1) * 64, wn = (wave & 1) * 64;
    int l15 = lane & 15, quad = lane >> 4;
    f32x4 acc[4][4];
    #pragma unroll
    for (int i = 0; i < 4; i++)
        #pragma unroll
        for (int j = 0; j < 4; j++) acc[i][j] = (f32x4){0.f, 0.f, 0.f, 0.f};

    int srow = tid >> 2;
    int schunk = (tid & 3) * 8;

    #define STAGE_SK(buf, kk0)                                                        \
        do {                                                                          \
            _Pragma("unroll")                                                         \
            for (int ps = 0; ps < 2; ps++) {                                          \
                int r = srow + ps * 64;                                               \
                gload16(&A[(size_t)(m0 + r) * K + (kk0) + schunk], &As[buf][r][schunk]); \
                gload16(&Bt[(size_t)(n0 + r) * K + (kk0) + schunk], &Bs[buf][r][schunk]); \
            }                                                                         \
        } while (0)

    STAGE_SK(0, kbeg);
    int cur = 0;
    for (int it = 0; it < nt; ++it) {
        if (it + 1 < nt) {
            STAGE_SK(cur ^ 1, kbeg + (it + 1) * 32);
            asm volatile("s_waitcnt vmcnt(4)" ::: "memory");
        } else {
            asm volatile("s_waitcnt vmcnt(0)" ::: "memory");
        }
        __builtin_amdgcn_s_barrier();
        bf16x8 af[4], bfr[4];
        #pragma unroll
        for (int i = 0; i < 4; i++) af[i]  = *(const bf16x8*)&As[cur][wm + i * 16 + l15][quad * 8];
        #pragma unroll
        for (int j = 0; j < 4; j++) bfr[j] = *(const bf16x8*)&Bs[cur][wn + j * 16 + l15][quad * 8];
        #pragma unroll
        for (int i = 0; i < 4; i++)
            #pragma unroll
            for (int j = 0; j < 4; j++)
                acc[i][j] = __builtin_amdgcn_mfma_f32_16x16x32_bf16(af[i], bfr[j], acc[i][j], 0, 0, 0);
        __builtin_amdgcn_s_barrier();
        cur ^= 1;
    }
    #undef STAGE_SK
    #pragma unroll
    for (int i = 0; i < 4; i++) {
        #pragma unroll
        for (int j = 0; j < 4; j++) {
            int col = n0 + wn + j * 16 + l15;
            if (col < N) {
                #pragma unroll
                for (int r = 0; r < 4; r++) {
                    int row = m0 + wm + i * 16 + quad * 4 + r;
                    C[(size_t)row * N + col] = acc[i][j][r];
                }
            }
        }
    }
}

// ---------------- [fused prev-attn out (4 split-K partials)] + residual + rmsnorm + mod ----
__global__ void k_addrmsmod(const float* __restrict__ hin, const float* __restrict__ raw,
                            const float* __restrict__ bias, const float* __restrict__ affprev,
                            float* __restrict__ residual, const float* __restrict__ normw,
                            const float* __restrict__ affcur,
                            float* __restrict__ hidden_n, unsigned short* __restrict__ u,
                            int has_raw) {
    __shared__ float s4[4];
    const size_t PSTR = (size_t)ROWS * D_MODEL;
    int row = blockIdx.x;
    int b = row >> 9;
    const float* hp = hin + (size_t)row * D_MODEL;
    float* rp = residual + (size_t)row * D_MODEL;
    float v[3]; float ss = 0.f;
    #pragma unroll
    for (int j = 0; j < 3; j++) {
        int d = threadIdx.x + j * 256;
        float x = hp[d];
        if (has_raw) {
            float g = affprev[b * AFF + 3840 + d];
            size_t idx = (size_t)row * D_MODEL + d;
            float rawv = raw[idx] + raw[idx + PSTR] + raw[idx + 2 * PSTR] + raw[idx + 3 * PSTR];
            x += g * (rawv + bias[d]) + rp[d];
        }
        rp[d] = x; v[j] = x; ss += x * x;
    }
    ss = block_sum_256(ss, s4);
    float inv = rsqrtf(ss / (float)D_MODEL + 1e-5f);
    const float* sh = affcur + b * AFF;
    const float* sc = affcur + b * AFF + 768;
    #pragma unroll
    for (int j = 0; j < 3; j++) {
        int d = threadIdx.x + j * 256;
        float hn = v[j] * inv * normw[d];
        hidden_n[(size_t)row * D_MODEL + d] = hn;
        u[(size_t)row * D_MODEL + d] = f2b(hn * (1.f + sc[d]) + sh[d]);
    }
}

// ---------------- depthwise causal conv + silu -> bf16; softplus(dt) ----------------
__global__ void k_convdt(const float* __restrict__ zx, const float* __restrict__ convw,
                         const float* __restrict__ convb, const float* __restrict__ dtbias,
                         unsigned short* __restrict__ xBC, float* __restrict__ dtb) {
    const size_t PSTRZ = (size_t)ROWS * D_IN_PROJ;
    int blk = blockIdx.x, tid = threadIdx.x;
    if (blk >= 448) {                             // softplus(dt) segment, exact 24576
        int i = (blk - 448) * 256 + tid;
        int h = i % NHEADS; int row = i / NHEADS;
        size_t off = (size_t)row * D_IN_PROJ + D_INNER + CONV_DIM + h;
        float x = zx[off] + zx[off + PSTRZ] + dtbias[h];
        dtb[i] = (x > 20.f) ? x : log1pf(expf(x));
        return;
    }
    int g = blk * 256 + tid;                      // 114688 = 448ch-groups x 256row-groups
    int cg = g % 448, rg = g / 448;
    int c0 = cg * 4, row0 = rg * 4;
    int l0 = row0 & 511;
    size_t rowbase = (size_t)row0 * D_IN_PROJ + D_INNER + c0;
    float rr[7][4];
    #pragma unroll
    for (int k = 0; k < 7; k++) {
        int tpos = l0 - 3 + k;
        if (tpos >= 0) {
            size_t idx = rowbase + (size_t)(k - 3) * D_IN_PROJ;
            float4 a = *(const float4*)&zx[idx];
            float4 b4 = *(const float4*)&zx[idx + PSTRZ];
            rr[k][0] = a.x + b4.x; rr[k][1] = a.y + b4.y;
            rr[k][2] = a.z + b4.z; rr[k][3] = a.w + b4.w;
        } else {
            rr[k][0] = rr[k][1] = rr[k][2] = rr[k][3] = 0.f;
        }
    }
    float4 w0 = *(const float4*)&convw[(size_t)c0 * 4];
    float4 w1 = *(const float4*)&convw[(size_t)(c0 + 1) * 4];
    float4 w2 = *(const float4*)&convw[(size_t)(c0 + 2) * 4];
    float4 w3 = *(const float4*)&convw[(size_t)(c0 + 3) * 4];
    float4 bb = *(const float4*)&convb[c0];
    #pragma unroll
    for (int r = 0; r < 4; r++) {
        ushort4 o;
        float a0 = bb.x + w0.x * rr[r][0] + w0.y * rr[r + 1][0] + w0.z * rr[r + 2][0] + w0.w * rr[r + 3][0];
        float a1 = bb.y + w1.x * rr[r][1] + w1.y * rr[r + 1][1] + w1.z * rr[r + 2][1] + w1.w * rr[r + 3][1];
        float a2 = bb.z + w2.x * rr[r][2] + w2.y * rr[r + 1][2] + w2.z * rr[r + 2][2] + w2.w * rr[r + 3][2];
        float a3 = bb.w + w3.x * rr[r][3] + w3.y * rr[r + 1][3] + w3.z * rr[r + 2][3] + w3.w * rr[r + 3][3];
        o.x = f2b(siluf(a0)); o.y = f2b(siluf(a1));
        o.z = f2b(siluf(a2)); o.w = f2b(siluf(a3));
        *(ushort4*)&xBC[(size_t)(row0 + r) * CONV_DIM + c0] = o;
    }
}

// ---------------- SSM K1: chunk-parallel (grid = NCHUNK x B*H), xBC bf16 ----------------
__global__ __launch_bounds__(256)
void k_ssm_par(const unsigned short* __restrict__ xBC, const float* __restrict__ dtb,
               const float* __restrict__ Alog, const float* __restrict__ Dssm,
               float* __restrict__ y, unsigned short* __restrict__ Sbuf,
               float* __restrict__ Pbuf) {
    __shared__ unsigned short sB[64][136];    // [t][n]
    __shared__ unsigned short sC[64][136];    // [t][n]
    __shared__ unsigned short sXT[64][72];    // [p][t]
    __shared__ unsigned short sG[64][72];     // G[i][s]; reused as XwT [p][t]
    __shared__ unsigned short sBT[128][72];   // [n][t]
    __shared__ float sL[64], sDt[64];
    int c = blockIdx.x, bh = blockIdx.y;
    int h = bh % NHEADS, b = bh / NHEADS;
    int tid = threadIdx.x;
    int lane = tid & 63, wave = tid >> 6;
    int l15 = lane & 15, quad = lane >> 4;
    int r = tid >> 2, q4 = tid & 3;
    int base = b * SEQ + c * CT;
    float a_h = expf(Alog[h]);
    float Dh = Dssm[h];
    if (tid < 64) {
        float dt = dtb[(base + tid) * NHEADS + h];
        float v = -a_h * dt;
        #pragma unroll
        for (int off = 1; off < 64; off <<= 1) {
            float u2 = __shfl_up(v, off, 64);
            if (tid >= off) v += u2;
        }
        sL[tid] = v; sDt[tid] = dt;
    }
    const unsigned short* xrow = xBC + (size_t)(base + r) * CONV_DIM;
    #pragma unroll
    for (int j = 0; j < 4; j++) {
        int n0 = q4 * 32 + j * 8;
        uint4 v = *(const uint4*)&xrow[D_INNER + n0];
        *(uint4*)&sB[r][n0] = v;
        const unsigned short* hv = (const unsigned short*)&v;
        #pragma unroll
        for (int e = 0; e < 8; e++) sBT[n0 + e][r] = hv[e];
        uint4 w = *(const uint4*)&xrow[D_INNER + D_STATE + n0];
        *(uint4*)&sC[r][n0] = w;
    }
    #pragma unroll
    for (int j = 0; j < 2; j++) {
        int p0 = q4 * 16 + j * 8;
        uint4 v = *(const uint4*)&xrow[h * HEADDIM + p0];
        const unsigned short* hv = (const unsigned short*)&v;
        #pragma unroll
        for (int e = 0; e < 8; e++) sXT[p0 + e][r] = hv[e];
    }
    __syncthreads();
    if (tid == 0) Pbuf[bh * NCHUNK + c] = expf(sL[63]);

    // acc1 = C·B^T  (CB[t][s])
    f32x4 acc1[4];
    #pragma unroll
    for (int j = 0; j < 4; j++) acc1[j] = (f32x4){0.f, 0.f, 0.f, 0.f};
    #pragma unroll
    for (int k0 = 0; k0 < 4; k0++) {
        bf16x8 a = *(const bf16x8*)&sC[wave * 16 + l15][k0 * 32 + quad * 8];
        #pragma unroll
        for (int nt = 0; nt < 4; nt++) {
            bf16x8 bv = *(const bf16x8*)&sB[nt * 16 + l15][k0 * 32 + quad * 8];
            acc1[nt] = __builtin_amdgcn_mfma_f32_16x16x32_bf16(a, bv, acc1[nt], 0, 0, 0);
        }
    }
    // G[i][s] = causal mask * CB * exp(L_i - L_s) * dt_s
    #pragma unroll
    for (int nt = 0; nt < 4; nt++) {
        int s = nt * 16 + l15;
        float Ls = sL[s], dts = sDt[s];
        #pragma unroll
        for (int rr = 0; rr < 4; rr++) {
            int i = wave * 16 + quad * 4 + rr;
            float g = (s <= i) ? acc1[nt][rr] * expf(sL[i] - Ls) * dts : 0.f;
            sG[i][s] = f2b(g);
        }
    }
    __syncthreads();

    // acc2 = G·X^T ; y_partial write (+ D·x)
    f32x4 acc2[4];
    #pragma unroll
    for (int j = 0; j < 4; j++) acc2[j] = (f32x4){0.f, 0.f, 0.f, 0.f};
    #pragma unroll
    for (int k0 = 0; k0 < 2; k0++) {
        bf16x8 a = *(const bf16x8*)&sG[wave * 16 + l15][k0 * 32 + quad * 8];
        #pragma unroll
        for (int nt = 0; nt < 4; nt++) {
            bf16x8 bv = *(const bf16x8*)&sXT[nt * 16 + l15][k0 * 32 + quad * 8];
            acc2[nt] = __builtin_amdgcn_mfma_f32_16x16x32_bf16(a, bv, acc2[nt], 0, 0, 0);
        }
    }
    #pragma unroll
    for (int nt = 0; nt < 4; nt++) {
        int p = nt * 16 + l15;
        #pragma unroll
        for (int rr = 0; rr < 4; rr++) {
            int i = wave * 16 + quad * 4 + rr;
            float xv = b2f(sXT[p][i]);
            y[(size_t)(base + i) * D_INNER + h * HEADDIM + p] = acc2[nt][rr] + Dh * xv;
        }
    }
    __syncthreads();
    // XwT[p][t] = X[t][p] * exp(Lend - L_t) * dt_t  (reuse sG)
    {
        float wr2 = expf(sL[63] - sL[r]) * sDt[r];
        #pragma unroll
        for (int j = 0; j < 16; j++) {
            int pp = q4 * 16 + j;
            sG[pp][r] = f2b(b2f(sXT[pp][r]) * wr2);
        }
    }
    __syncthreads();
    // S[p][n] = Xw·B -> Sbuf bf16
    f32x4 accS[8];
    #pragma unroll
    for (int j = 0; j < 8; j++) accS[j] = (f32x4){0.f, 0.f, 0.f, 0.f};
    #pragma unroll
    for (int k0 = 0; k0 < 2; k0++) {
        bf16x8 a = *(const bf16x8*)&sG[wave * 16 + l15][k0 * 32 + quad * 8];
        #pragma unroll
        for (int nt = 0; nt < 8; nt++) {
            bf16x8 bv = *(const bf16x8*)&sBT[nt * 16 + l15][k0 * 32 + quad * 8];
            accS[nt] = __builtin_amdgcn_mfma_f32_16x16x32_bf16(a, bv, accS[nt], 0, 0, 0);
        }
    }
    unsigned short* sout = Sbuf + ((size_t)bh * NCHUNK + c) * 8192;
    #pragma unroll
    for (int nt = 0; nt < 8; nt++) {
        int n = nt * 16 + l15;
        #pragma unroll
        for (int rr = 0; rr < 4; rr++) {
            int p = wave * 16 + quad * 4 + rr;
            sout[p * 128 + n] = f2b(accS[nt][rr]);
        }
    }
}

// ---------------- SSM K2: h-contribution, chunk-parallel (grid = (NCHUNK-1) x B*H) ------
__global__ __launch_bounds__(256)
void k_ssm_fix(const unsigned short* __restrict__ xBC, const float* __restrict__ dtb,
               const float* __restrict__ Alog, const unsigned short* __restrict__ Sbuf,
               const float* __restrict__ Pbuf, float* __restrict__ y) {
    __shared__ unsigned short sC[64][136];    // C~ = C * exp(L_t)
    __shared__ unsigned short sHB[64][136];   // h_start bf16 [p][n]
    __shared__ float sL[64];
    int c = blockIdx.x + 1, bh = blockIdx.y;
    int h = bh % NHEADS, b = bh / NHEADS;
    int tid = threadIdx.x;
    int lane = tid & 63, wave = tid >> 6;
    int l15 = lane & 15, quad = lane >> 4;
    int r = tid >> 2, q4 = tid & 3;
    int base = b * SEQ + c * CT;
    if (tid < 64) {
        float dt = dtb[(base + tid) * NHEADS + h];
        float v = -expf(Alog[h]) * dt;
        #pragma unroll
        for (int off = 1; off < 64; off <<= 1) {
            float u2 = __shfl_up(v, off, 64);
            if (tid >= off) v += u2;
        }
        sL[tid] = v;
    }
    // h_start: thread owns row p=r, cols [q4*32, q4*32+32)
    float hacc[32];
    #pragma unroll
    for (int e = 0; e < 32; e++) hacc[e] = 0.f;
    {
        const unsigned short* sp = Sbuf + (size_t)bh * NCHUNK * 8192 + r * 128 + q4 * 32;
        float w = 1.f;
        for (int j = c - 1; j >= 0; j--) {
            const unsigned short* srow = sp + (size_t)j * 8192;
            #pragma unroll
            for (int q = 0; q < 4; q++) {
                bf16x8 vv = *(const bf16x8*)&srow[q * 8];
                #pragma unroll
                for (int e = 0; e < 8; e++)
                    hacc[q * 8 + e] += w * b2f((unsigned short)vv[e]);
            }
            w *= Pbuf[bh * NCHUNK + j];
        }
    }
    __syncthreads();
    #pragma unroll
    for (int e = 0; e < 32; e++) sHB[r][q4 * 32 + e] = f2b(hacc[e]);
    {
        float el = expf(sL[r]);
        const unsigned short* xrow = xBC + (size_t)(base + r) * CONV_DIM + D_INNER + D_STATE;
        #pragma unroll
        for (int j = 0; j < 4; j++) {
            int n0 = q4 * 32 + j * 8;
            uint4 v = *(const uint4*)&xrow[n0];
            const unsigned short* hv = (const unsigned short*)&v;
            #pragma unroll
            for (int e = 0; e < 8; e++) sC[r][n0 + e] = f2b(b2f(hv[e]) * el);
        }
    }
    __syncthreads();
    // y[t][p] += sum_n C~[t][n] h[p][n]
    f32x4 acc[4];
    #pragma unroll
    for (int j = 0; j < 4; j++) acc[j] = (f32x4){0.f, 0.f, 0.f, 0.f};
    #pragma unroll
    for (int k0 = 0; k0 < 4; k0++) {
        bf16x8 a = *(const bf16x8*)&sC[wave * 16 + l15][k0 * 32 + quad * 8];
        #pragma unroll
        for (int nt = 0; nt < 4; nt++) {
            bf16x8 bv = *(const bf16x8*)&sHB[nt * 16 + l15][k0 * 32 + quad * 8];
            acc[nt] = __builtin_amdgcn_mfma_f32_16x16x32_bf16(a, bv, acc[nt], 0, 0, 0);
        }
    }
    #pragma unroll
    for (int nt = 0; nt < 4; nt++) {
        int p = nt * 16 + l15;
        #pragma unroll
        for (int rr = 0; rr < 4; rr++) {
            int i = wave * 16 + quad * 4 + rr;
            size_t idx = (size_t)(base + i) * D_INNER + h * HEADDIM + p;
            y[idx] += acc[nt][rr];
        }
    }
}

// ---------------- gated rmsnorm (z from 2 zx partials) -> bf16 ----------------
__global__ void k_gatednorm(const float* __restrict__ yscan, const float* __restrict__ zx,
                            const float* __restrict__ nw, unsigned short* __restrict__ out) {
    __shared__ float s4[4];
    const size_t PSTRZ = (size_t)ROWS * D_IN_PROJ;
    int row = blockIdx.x;
    const float* yp = yscan + (size_t)row * D_INNER;
    const float* zp0 = zx + (size_t)row * D_IN_PROJ;
    const float* zp1 = zp0 + PSTRZ;
    float v[6]; float ss = 0.f;
    #pragma unroll
    for (int j = 0; j < 6; j++) {
        int d = threadIdx.x + j * 256;
        float val = yp[d] * siluf(zp0[d] + zp1[d]);
        v[j] = val; ss += val * val;
    }
    ss = block_sum_256(ss, s4);
    float inv = rsqrtf(ss / (float)D_INNER + 1e-5f);
    #pragma unroll
    for (int j = 0; j < 6; j++) {
        int d = threadIdx.x + j * 256;
        out[(size_t)row * D_INNER + d] = f2b(v[j] * inv * nw[d]);
    }
}

// ---------------- hidden2 = hidden_n + g_mba*(Σ tmp partials + out_b); ln + msa mod ----
__global__ void k_fuse_ln(const float* __restrict__ hidden_n, const float* __restrict__ tmp,
                          const float* __restrict__ outb, const float* __restrict__ aff,
                          float* __restrict__ hidden2, unsigned short* __restrict__ attnx) {
    __shared__ float s4[4];
    const size_t PSTR = (size_t)ROWS * D_MODEL;
    int row = blockIdx.x;
    int b = row >> 9;
    const float* gm = aff + b * AFF + 1536;
    float v[3]; float s = 0.f;
    #pragma unroll
    for (int j = 0; j < 3; j++) {
        int d = threadIdx.x + j * 256;
        size_t idx = (size_t)row * D_MODEL + d;
        float t = tmp[idx] + tmp[idx + PSTR] + tmp[idx + 2 * PSTR] + tmp[idx + 3 * PSTR];
        float x = hidden_n[idx] + gm[d] * (t + outb[d]);
        hidden2[idx] = x;
        v[j] = x; s += x;
    }
    float mean = block_sum_256(s, s4) / (float)D_MODEL;
    float ss = 0.f;
    #pragma unroll
    for (int j = 0; j < 3; j++) { float c = v[j] - mean; ss += c * c; }
    float var = block_sum_256(ss, s4) / (float)D_MODEL;
    float inv = rsqrtf(var + 1e-6f);
    const float* sh = aff + b * AFF + 2304;
    const float* sc = aff + b * AFF + 3072;
    #pragma unroll
    for (int j = 0; j < 3; j++) {
        int d = threadIdx.x + j * 256;
        float xh = (v[j] - mean) * inv;
        attnx[(size_t)row * D_MODEL + d] = f2b(xh * (1.f + sc[d]) + sh[d]);
    }
}

// ---------------- cross-attention: fused Q-proj + MFMA QK^T + softmax + MFMA PV ---------
__global__ __launch_bounds__(256)
void k_attn(const unsigned short* __restrict__ attnx, const unsigned short* __restrict__ qwt,
            const unsigned short* __restrict__ kb, const unsigned short* __restrict__ vb,
            unsigned short* __restrict__ ob) {
    int blk = blockIdx.x;
    int lt = blk & 15; int h = (blk >> 4) & 7; int b = blk >> 7;
    __shared__ unsigned short sK[64][72];     // K [m][d]
    __shared__ unsigned short sVT[64][72];    // V^T [d][m]
    __shared__ unsigned short sA[32][136];
    __shared__ unsigned short sW[64][136];
    __shared__ unsigned short sQb[32][72];    // Q bf16 (pre-scaled)
    __shared__ unsigned short sP[32][72];     // softmax probs bf16
    int tid = threadIdx.x;
    // stage K rows + V transposed
    {
        int r = tid >> 2, c0 = (tid & 3) * 16;
        const unsigned short* kp = kb + (size_t)(b * LC + r) * AINNER + h * AD + c0;
        const unsigned short* vp = vb + (size_t)(b * LC + r) * AINNER + h * AD + c0;
        #pragma unroll
        for (int j = 0; j < 4; j++) {
            *(ushort4*)&sK[r][c0 + j * 4] = *(const ushort4*)&kp[j * 4];
            ushort4 vv = *(const ushort4*)&vp[j * 4];
            const unsigned short* hv = (const unsigned short*)&vv;
            #pragma unroll
            for (int e = 0; e < 4; e++) sVT[c0 + j * 4 + e][r] = hv[e];
        }
    }
    int lane = tid & 63, wave = tid >> 6;
    int l15 = lane & 15, quad = lane >> 4;
    int rt = wave >> 1, cp = (wave & 1) * 2;
    f32x4 accq[2];
    accq[0] = (f32x4){0.f, 0.f, 0.f, 0.f};
    accq[1] = (f32x4){0.f, 0.f, 0.f, 0.f};
    const size_t arow_base = (size_t)(b * SEQ + lt * 32) * D_MODEL;
    for (int k0 = 0; k0 < D_MODEL; k0 += 128) {
        __syncthreads();
        #pragma unroll
        for (int j = 0; j < 2; j++) {
            int s = tid + j * 256; int row = s >> 4, c8 = (s & 15) * 8;
            *(uint4*)&sA[row][c8] =
                *(const uint4*)&attnx[arow_base + (size_t)row * D_MODEL + k0 + c8];
        }
        #pragma unroll
        for (int j = 0; j < 4; j++) {
            int s = tid + j * 256; int row = s >> 4, c8 = (s & 15) * 8;
            *(uint4*)&sW[row][c8] =
                *(const uint4*)&qwt[(size_t)(h * AD + row) * D_MODEL + k0 + c8];
        }
        __syncthreads();
        #pragma unroll
        for (int ks = 0; ks < 4; ks++) {
            bf16x8 af = *(const bf16x8*)&sA[rt * 16 + l15][ks * 32 + quad * 8];
            #pragma unroll
            for (int j = 0; j < 2; j++) {
                bf16x8 bf = *(const bf16x8*)&sW[(cp + j) * 16 + l15][ks * 32 + quad * 8];
                accq[j] = __builtin_amdgcn_mfma_f32_16x16x32_bf16(af, bf, accq[j], 0, 0, 0);
            }
        }
    }
    // Q -> LDS bf16, scaled by 1/sqrt(AD)
    #pragma unroll
    for (int j = 0; j < 2; j++)
        #pragma unroll
        for (int rr = 0; rr < 4; rr++)
            sQb[rt * 16 + quad * 4 + rr][(cp + j) * 16 + l15] = f2b(accq[j][rr] * 0.125f);
    __syncthreads();
    // QK^T + softmax on waves 0,1 (qt = wave)
    if (wave < 2) {
        int qt = wave;
        f32x4 s[4];
        #pragma unroll
        for (int mt = 0; mt < 4; mt++) s[mt] = (f32x4){0.f, 0.f, 0.f, 0.f};
        #pragma unroll
        for (int k0 = 0; k0 < 2; k0++) {
            bf16x8 aq = *(const bf16x8*)&sQb[qt * 16 + l15][k0 * 32 + quad * 8];
            #pragma unroll
            for (int mt = 0; mt < 4; mt++) {
                bf16x8 bk = *(const bf16x8*)&sK[mt * 16 + l15][k0 * 32 + quad * 8];
                s[mt] = __builtin_amdgcn_mfma_f32_16x16x32_bf16(aq, bk, s[mt], 0, 0, 0);
            }
        }
        #pragma unroll
        for (int rr = 0; rr < 4; rr++) {
            float mx = fmaxf(fmaxf(s[0][rr], s[1][rr]), fmaxf(s[2][rr], s[3][rr]));
            #pragma unroll
            for (int off = 8; off > 0; off >>= 1) mx = fmaxf(mx, __shfl_xor(mx, off, 64));
            float e0 = expf(s[0][rr] - mx), e1 = expf(s[1][rr] - mx);
            float e2 = expf(s[2][rr] - mx), e3 = expf(s[3][rr] - mx);
            float sum = e0 + e1 + e2 + e3;
            #pragma unroll
            for (int off = 8; off > 0; off >>= 1) sum += __shfl_xor(sum, off, 64);
            float inv = 1.f / sum;
            int q = qt * 16 + quad * 4 + rr;
            sP[q][0 * 16 + l15] = f2b(e0 * inv);
            sP[q][1 * 16 + l15] = f2b(e1 * inv);
            sP[q][2 * 16 + l15] = f2b(e2 * inv);
            sP[q][3 * 16 + l15] = f2b(e3 * inv);
        }
    }
    __syncthreads();
    // PV: all 4 waves; qt = wave>>1, d-tile pair = (wave&1)*2
    {
        int qt = wave >> 1, dp = (wave & 1) * 2;
        f32x4 o[2];
        o[0] = (f32x4){0.f, 0.f, 0.f, 0.f};
        o[1] = (f32x4){0.f, 0.f, 0.f, 0.f};
        #pragma unroll
        for (int k0 = 0; k0 < 2; k0++) {
            bf16x8 ap = *(const bf16x8*)&sP[qt * 16 + l15][k0 * 32 + quad * 8];
            #pragma unroll
            for (int j = 0; j < 2; j++) {
                bf16x8 bv = *(const bf16x8*)&sVT[(dp + j) * 16 + l15][k0 * 32 + quad * 8];
                o[j] = __builtin_amdgcn_mfma_f32_16x16x32_bf16(ap, bv, o[j], 0, 0, 0);
            }
        }
        #pragma unroll
        for (int j = 0; j < 2; j++) {
            int d = (dp + j) * 16 + l15;
            #pragma unroll
            for (int rr = 0; rr < 4; rr++) {
                int q = qt * 16 + quad * 4 + rr;
                ob[(size_t)(b * SEQ + lt * 32 + q) * AINNER + h * AD + d] = f2b(o[j][rr]);
            }
        }
    }
}

// ---------------- final: h = hidden2 + g*(Σ raw partials + bias); rmsnorm(h + r) --------
__global__ void k_final(const float* __restrict__ hidden2, const float* __restrict__ raw,
                        const float* __restrict__ bias, const float* __restrict__ aff,
                        const float* __restrict__ residual, const float* __restrict__ w,
                        float* __restrict__ out) {
    __shared__ float s4[4];
    const size_t PSTR = (size_t)ROWS * D_MODEL;
    int row = blockIdx.x;
    int b = row >> 9;
    const float* gm = aff + b * AFF + 3840;
    float v[3]; float ss = 0.f;
    #pragma unroll
    for (int j = 0; j < 3; j++) {
        int d = threadIdx.x + j * 256;
        size_t idx = (size_t)row * D_MODEL + d;
        float rawv = raw[idx] + raw[idx + PSTR] + raw[idx + 2 * PSTR] + raw[idx + 3 * PSTR];
        float x = hidden2[idx] + gm[d] * (rawv + bias[d]) + residual[idx];
        v[j] = x; ss += x * x;
    }
    ss = block_sum_256(ss, s4);
    float inv = rsqrtf(ss / (float)D_MODEL + 1e-5f);
    #pragma unroll
    for (int j = 0; j < 3; j++) {
        int d = threadIdx.x + j * 256;
        out[(size_t)row * D_MODEL + d] = v[j] * inv * w[d];
    }
}

// ---------------- host launch ----------------
extern "C" void kernel_launch(void* const* d_in, const int* in_sizes, int n_in,
                              void* d_out, int out_size, void* d_ws, size_t ws_size,
                              hipStream_t stream) {
    const float* hidden_states = (const float*)d_in[0];
    const float* ref_emb  = (const float*)d_in[1];
    const float* norm_w   = (const float*)d_in[2];
    const float* ada_w    = (const float*)d_in[3];
    const float* ada_b    = (const float*)d_in[4];
    const float* in_w     = (const float*)d_in[5];
    const float* conv_w   = (const float*)d_in[6];
    const float* conv_b   = (const float*)d_in[7];
    const float* dt_bias  = (const float*)d_in[8];
    const float* A_log    = (const float*)d_in[9];
    const float* D_ssm    = (const float*)d_in[10];
    const float* ssm_nw   = (const float*)d_in[11];
    const float* out_w    = (const float*)d_in[12];
    const float* out_b    = (const float*)d_in[13];
    const float* q_w      = (const float*)d_in[14];
    const float* k_w      = (const float*)d_in[15];
    const float* v_w      = (const float*)d_in[16];
    const float* o_w      = (const float*)d_in[17];
    const float* o_b      = (const float*)d_in[18];
    const float* norm_f_w = (const float*)d_in[19];
    float* out = (float*)d_out;

    char* p = (char*)d_ws;
    auto alloc = [&](size_t bytes) -> char* {
        char* r = p; p += (bytes + 255) & ~(size_t)255; return r;
    };
    float* residual = (float*)alloc((size_t)ROWS * D_MODEL * 4);
    float* hidden2  = (float*)alloc((size_t)ROWS * D_MODEL * 4);
    float* hidden_n = (float*)alloc((size_t)ROWS * D_MODEL * 4);
    float* tmpM     = (float*)alloc((size_t)4 * ROWS * D_MODEL * 4);  // out-proj partials
    float* tmpO     = (float*)alloc((size_t)4 * ROWS * D_MODEL * 4);  // o-proj partials (SK=4)
    float* zx       = (float*)alloc((size_t)2 * ROWS * D_IN_PROJ * 4); // in-proj partials
    float* dtb      = (float*)alloc((size_t)ROWS * NHEADS * 4);
    float* yscan    = (float*)alloc((size_t)ROWS * D_INNER * 4);
    float* aff_all  = (float*)alloc((size_t)N_LAYER * BSZ * AFF * 4);
    float* smc      = (float*)alloc((size_t)BSZ * D_MODEL * 4);
    float* Pbuf     = (float*)alloc((size_t)BSZ * NHEADS * NCHUNK * 4);
    unsigned short* xBC    = (unsigned short*)alloc((size_t)ROWS * CONV_DIM * 2);
    unsigned short* Sbuf   = (unsigned short*)alloc((size_t)BSZ * NHEADS * NCHUNK * 8192 * 2);
    unsigned short* u_bf   = (unsigned short*)alloc((size_t)ROWS * D_MODEL * 2);
    unsigned short* ynorm  = (unsigned short*)alloc((size_t)ROWS * D_INNER * 2);
    unsigned short* attnx  = (unsigned short*)alloc((size_t)ROWS * D_MODEL * 2);
    unsigned short* ob     = (unsigned short*)alloc((size_t)ROWS * AINNER * 2);
    unsigned short* ref_bf = (unsigned short*)alloc((size_t)BSZ * LC * D_MODEL * 2);
    unsigned short* kb_all  = (unsigned short*)alloc((size_t)N_LAYER * BSZ * LC * AINNER * 2);
    unsigned short* vb_all  = (unsigned short*)alloc((size_t)N_LAYER * BSZ * LC * AINNER * 2);
    unsigned short* in_wt_all  = (unsigned short*)alloc((size_t)N_LAYER * NP1 * D_MODEL * 2);
    unsigned short* out_wt_all = (unsigned short*)alloc((size_t)N_LAYER * D_MODEL * D_INNER * 2);
    unsigned short* q_wt_all   = (unsigned short*)alloc((size_t)N_LAYER * AINNER * D_MODEL * 2);
    unsigned short* o_wt_all   = (unsigned short*)alloc((size_t)N_LAYER * D_MODEL * AINNER * 2);
    unsigned short* kwt_all = (unsigned short*)alloc((size_t)N_LAYER * AINNER * D_MODEL * 2);
    unsigned short* vwt_all = (unsigned short*)alloc((size_t)N_LAYER * AINNER * D_MODEL * 2);

    k_prep<<<10806, 256, 0, stream>>>(ref_emb, ref_bf, smc, ada_b, aff_all,
                                      in_w, out_w, q_w, k_w, v_w, o_w,
                                      in_wt_all, out_wt_all, q_wt_all, kwt_all, vwt_all,
                                      o_wt_all);
    k_kvada<<<dim3(18, 1, 80), 256, 0, stream>>>(ref_bf, kwt_all, vwt_all, kb_all, vb_all,
                                                 smc, ada_w, aff_all);

    for (int layer = 0; layer < N_LAYER; layer++) {
        const float* L_norm_w  = norm_w  + layer * D_MODEL;
        const float* L_conv_w  = conv_w  + layer * CONV_DIM * 4;
        const float* L_conv_b  = conv_b  + layer * CONV_DIM;
        const float* L_dt_bias = dt_bias + layer * NHEADS;
        const float* L_A_log   = A_log   + layer * NHEADS;
        const float* L_D_ssm   = D_ssm   + layer * NHEADS;
        const float* L_ssm_nw  = ssm_nw  + layer * D_INNER;
        const float* L_out_b   = out_b   + layer * D_MODEL;
        const float* L_o_b_prev= o_b     + (layer - 1) * D_MODEL;
        const float* L_aff     = aff_all + (size_t)layer * BSZ * AFF;
        const float* L_aff_prev= aff_all + (size_t)(layer - 1) * BSZ * AFF;
        const unsigned short* in_wt  = in_wt_all  + (size_t)layer * NP1 * D_MODEL;
        const unsigned short* out_wt = out_wt_all + (size_t)layer * D_MODEL * D_INNER;
        const unsigned short* q_wt   = q_wt_all   + (size_t)layer * AINNER * D_MODEL;
        const unsigned short* o_wt   = o_wt_all   + (size_t)layer * D_MODEL * AINNER;

        k_addrmsmod<<<ROWS, 256, 0, stream>>>(
            layer == 0 ? hidden_states : hidden2, tmpO,
            layer == 0 ? o_b : L_o_b_prev,
            layer == 0 ? aff_all : L_aff_prev,
            residual, L_norm_w, L_aff, hidden_n, u_bf, layer == 0 ? 0 : 1);
        k_gemm_sk<<<dim3(NP1 / 128, ROWS / 128, 2), 256, 0, stream>>>(u_bf, in_wt, zx, ROWS, D_IN_PROJ, D_MODEL, 384);
        k_convdt<<<544, 256, 0, stream>>>(zx, L_conv_w, L_conv_b, L_dt_bias, xBC, dtb);
        k_ssm_par<<<dim3(NCHUNK, BSZ * NHEADS), 256, 0, stream>>>(xBC, dtb, L_A_log, L_D_ssm, yscan, Sbuf, Pbuf);
        k_ssm_fix<<<dim3(NCHUNK - 1, BSZ * NHEADS), 256, 0, stream>>>(xBC, dtb, L_A_log, Sbuf, Pbuf, yscan);
        k_gatednorm<<<ROWS, 256, 0, stream>>>(yscan, zx, L_ssm_nw, ynorm);
        k_gemm_sk<<<dim3(D_MODEL / 128, ROWS / 128, 4), 256, 0, stream>>>(ynorm, out_wt, tmpM, ROWS, D_MODEL, D_INNER, 384);
        k_fuse_ln<<<ROWS, 256, 0, stream>>>(hidden_n, tmpM, L_out_b, L_aff, hidden2, attnx);
        k_attn<<<BSZ * AH * 16, 256, 0, stream>>>(
            attnx, q_wt,
            kb_all + (size_t)layer * BSZ * LC * AINNER,
            vb_all + (size_t)layer * BSZ * LC * AINNER, ob);
        k_gemm_sk<<<dim3(D_MODEL / 128, ROWS / 128, 4), 256, 0, stream>>>(ob, o_wt, tmpO, ROWS, D_MODEL, AINNER, 128);
    }
    k_final<<<ROWS, 256, 0, stream>>>(hidden2, tmpO, o_b + (N_LAYER - 1) * D_MODEL,
                                      aff_all + (size_t)(N_LAYER - 1) * BSZ * AFF,
                                      residual, norm_f_w, out);
}